// Round 2
// baseline (891.078 us; speedup 1.0000x reference)
//
#include <hip/hip_runtime.h>
#include <hip/hip_fp8.h>
#include <math.h>

#define HDIM 32
#define NHEAD 8
#define DMODEL 256
#define NTYPE 4
#define ETYPE 3
#define NLAYER 3

typedef unsigned short u16;
typedef unsigned char u8;
typedef __bf16 bf16x8 __attribute__((ext_vector_type(8)));
typedef float f32x4 __attribute__((ext_vector_type(4)));

__device__ __forceinline__ u16 f2bf(float f) {
  union { float f; unsigned u; } v; v.f = f;
  unsigned r = v.u + 0x7FFF + ((v.u >> 16) & 1);
  return (u16)(r >> 16);
}
__device__ __forceinline__ float bf2f(u16 b) {
  union { unsigned u; float f; } v; v.u = (unsigned)b << 16; return v.f;
}
__device__ __forceinline__ u8 f2fp8(float v) {
  __hip_fp8_e4m3 t(v); return (u8)t.__x;
}
__device__ __forceinline__ float fp82f(unsigned b) {
  __hip_fp8_e4m3 t; t.__x = (__hip_fp8_storage_t)b; return (float)t;
}

// fast GELU (tanh form)
__device__ __forceinline__ float gelu_f(float v) {
  float u = 0.7978845608028654f * v * (1.f + 0.044715f * v * v);
  float e = __expf(-2.f * fabsf(u));
  float th = (1.f - e) / (1.f + e);
  th = copysignf(th, u);
  return 0.5f * v * (1.f + th);
}

#define GLDS16(g, l)                                              \
  __builtin_amdgcn_global_load_lds(                               \
      (const __attribute__((address_space(1))) void*)(g),         \
      (__attribute__((address_space(3))) void*)(l), 16, 0, 0)

// ---------------------------------------------------------------------------
// CSR build (dst-sorted edge VALUES in position order)
// ---------------------------------------------------------------------------
__global__ void count_deg_kernel(const int* __restrict__ dst, int* __restrict__ deg, int E) {
  int tid = blockIdx.x * 256 + threadIdx.x;
  if (tid < E) atomicAdd(&deg[dst[tid]], 1);
}

__global__ __launch_bounds__(1024) void scan_kernel(const int* __restrict__ deg,
                                                    int* __restrict__ off, int n) {
  __shared__ int part[1024];
  int t = threadIdx.x;
  int chunk = (n + 1023) >> 10;
  int base = t * chunk;
  int s = 0;
  for (int i = 0; i < chunk; ++i) {
    int idx = base + i;
    if (idx < n) s += deg[idx];
  }
  part[t] = s;
  __syncthreads();
  for (int o = 1; o < 1024; o <<= 1) {
    int v = (t >= o) ? part[t - o] : 0;
    __syncthreads();
    part[t] += v;
    __syncthreads();
  }
  int run = part[t] - s;
  for (int i = 0; i < chunk; ++i) {
    int idx = base + i;
    if (idx < n) { off[idx] = run; run += deg[idx]; }
  }
  if (t == 1023) off[n] = part[1023];
}

__global__ void scatter_kernel(const int* __restrict__ src, const int* __restrict__ dst,
                               const int* __restrict__ etype,
                               const int* __restrict__ off, int* __restrict__ cursor,
                               int* __restrict__ csr_src, int* __restrict__ csr_dst,
                               int* __restrict__ csr_et, int E) {
  int tid = blockIdx.x * 256 + threadIdx.x;
  if (tid < E) {
    int d = dst[tid];
    int p = atomicAdd(&cursor[d], 1);
    int pos = off[d] + p;
    csr_src[pos] = src[tid];
    csr_dst[pos] = d;
    csr_et[pos] = etype[tid];
  }
}

// ---------------------------------------------------------------------------
// Node-type buckets — hierarchical to avoid same-address atomic contention
// ---------------------------------------------------------------------------
__global__ void tcount_kernel(const int* __restrict__ nt, int* __restrict__ tcnt, int N) {
  __shared__ int h[NTYPE];
  int t = threadIdx.x;
  if (t < NTYPE) h[t] = 0;
  __syncthreads();
  int tid = blockIdx.x * 256 + t;
  if (tid < N) atomicAdd(&h[nt[tid]], 1);
  __syncthreads();
  if (t < NTYPE && h[t] > 0) atomicAdd(&tcnt[t], h[t]);
}

__global__ void tscan_kernel(const int* __restrict__ tcnt, int* __restrict__ toff,
                             int* __restrict__ tile_off) {
  if (threadIdx.x == 0 && blockIdx.x == 0) {
    int o = 0, to = 0;
    for (int t = 0; t < NTYPE; ++t) {
      toff[t] = o; tile_off[t] = to;
      o += tcnt[t]; to += (tcnt[t] + 63) >> 6;
    }
    toff[NTYPE] = o; tile_off[NTYPE] = to;
  }
}

__global__ void tscatter_kernel(const int* __restrict__ nt, const int* __restrict__ toff,
                                int* __restrict__ tcur, int* __restrict__ tidx, int N) {
  int tid = blockIdx.x * 256 + threadIdx.x;
  int lane = threadIdx.x & 63;
  int ty = (tid < N) ? nt[tid] : -1;
  unsigned long long lt_mask = (lane == 63) ? 0x7FFFFFFFFFFFFFFFull
                                            : ((1ull << lane) - 1);
#pragma unroll
  for (int t4 = 0; t4 < NTYPE; ++t4) {
    unsigned long long mask = __ballot(ty == t4);
    if (mask == 0) continue;
    int first = __builtin_ctzll(mask);
    int cnt = __popcll(mask);
    int base = 0;
    if (lane == first) base = atomicAdd(&tcur[t4], cnt);
    base = __shfl(base, first, 64);
    if (ty == t4) {
      int rank = __popcll(mask & lt_mask);
      tidx[toff[t4] + base + rank] = tid;
    }
  }
}

// ---------------------------------------------------------------------------
// x fp32 -> bf16 mirror
// ---------------------------------------------------------------------------
__global__ void xconv_kernel(const float* __restrict__ x, u16* __restrict__ xb, int n4) {
  int i = blockIdx.x * 256 + threadIdx.x;
  if (i < n4) {
    float4 v = ((const float4*)x)[i];
    ushort4 o = { f2bf(v.x), f2bf(v.y), f2bf(v.z), f2bf(v.w) };
    ((ushort4*)xb)[i] = o;
  }
}

// ---------------------------------------------------------------------------
// Weight prep, per (l,type,head): bf16 B-operand mats ([col][k], k contig):
//   mat0 = WK^T, mat1 = WV^T,
//   mat2..4 = WQE[et] with Qe = x @ (WQ @ WE[et]^T)
// ---------------------------------------------------------------------------
__global__ __launch_bounds__(256) void wprep_kernel(
    const float* __restrict__ W_Q, const float* __restrict__ W_K,
    const float* __restrict__ W_V, const float* __restrict__ W_E,
    u16* __restrict__ wqkvb) {
  int b = blockIdx.x;
  int h = b & 7, tt = (b >> 3) & 3, l = b >> 5;
  __shared__ float wq[1024];
  __shared__ float we[3][1024];
  int t = threadIdx.x;
  const float* WQp = W_Q + (((size_t)l * NTYPE + tt) * NHEAD + h) * 1024;
  for (int i = t; i < 1024; i += 256) wq[i] = WQp[i];
  for (int et = 0; et < ETYPE; ++et) {
    const float* WEp = W_E + (((size_t)l * ETYPE + et) * NHEAD + h) * 1024;
    for (int i = t; i < 1024; i += 256) we[et][i] = WEp[i];
  }
  __syncthreads();
  const float* WKp = W_K + (((size_t)l * NTYPE + tt) * NHEAD + h) * 1024;
  const float* WVp = W_V + (((size_t)l * NTYPE + tt) * NHEAD + h) * 1024;
  u16* out = wqkvb + (size_t)b * 5120;
  for (int i = t; i < 1024; i += 256) {
    int col = i >> 5, k = i & 31;
    out[i] = f2bf(WKp[k * 32 + col]);
    out[1024 + i] = f2bf(WVp[k * 32 + col]);
#pragma unroll
    for (int et = 0; et < ETYPE; ++et) {
      float a = 0.f;
#pragma unroll
      for (int j = 0; j < 32; ++j) a += wq[k * 32 + j] * we[et][col * 32 + j];
      out[(2 + et) * 1024 + i] = f2bf(a);
    }
  }
}

// ---------------------------------------------------------------------------
// QKV via MFMA over type buckets: K,V stored fp8 e4m3, Qe[3] bf16.
// LDS layout for MFMA operands is [k-slot][row] per 16-row chunk so the
// b128 fragment reads are bank-conflict-free.
// ---------------------------------------------------------------------------
__global__ __launch_bounds__(256) void qkv_mfma(
    const u16* __restrict__ xb, const int* __restrict__ tidx,
    const int* __restrict__ toff, const int* __restrict__ tile_off,
    const u16* __restrict__ wqkvb_l,
    u8* __restrict__ Kb8, u8* __restrict__ Vb8, u16* __restrict__ Qeb) {
  __shared__ u16 smem[10240];
  int bx = blockIdx.x, h = blockIdx.y;
  if (bx >= tile_off[NTYPE]) return;
  int ty = 0;
  while (bx >= tile_off[ty + 1]) ++ty;
  int lt = bx - tile_off[ty];
  int base = toff[ty] + lt * 64;
  int cnt = min(64, toff[ty + 1] - toff[ty] - lt * 64);
  int t = threadIdx.x;
  {
    // x tile 64 rows x 32 k, stored as [rgroup(4)][slot(4)][row16(16)] 16B units
    int row = ((t >> 6) << 4) | (t & 15);
    int q = (t >> 4) & 3;
    int node = tidx[base + min(row, cnt - 1)];
    *(uint4*)&smem[t * 8] =
        *(const uint4*)&xb[(size_t)node * 256 + h * 32 + q * 8];
  }
  // weights: 5 mats of 32 cols x 32 k; store as [mt][slot(4)][col(32)] 16B units
  // (permute SOURCE chunk index so LDS writes stay linear/conflict-free)
  const u16* wsrc = wqkvb_l + ((size_t)ty * NHEAD + h) * 5120;
  for (int dc = t; dc < 640; dc += 256) {
    int mt = dc >> 7, wi = dc & 127, slot = wi >> 5, colx = wi & 31;
    *(uint4*)&smem[2048 + dc * 8] = *(const uint4*)&wsrc[(mt * 128 + colx * 4 + slot) * 8];
  }
  __syncthreads();

  int lane = t & 63, w = t >> 6;
  int m = lane & 15, q = lane >> 4;
  bf16x8 af = *(const bf16x8*)&smem[w * 512 + q * 128 + m * 8];
  f32x4 acc[5][2];
#pragma unroll
  for (int mt = 0; mt < 5; ++mt)
#pragma unroll
    for (int c = 0; c < 2; ++c) {
      bf16x8 bf = *(const bf16x8*)&smem[2048 + mt * 1024 + q * 256 + (c * 16 + m) * 8];
      acc[mt][c] = __builtin_amdgcn_mfma_f32_16x16x32_bf16(af, bf, (f32x4){0.f, 0.f, 0.f, 0.f}, 0, 0, 0);
    }
  __syncthreads();
#pragma unroll
  for (int mt = 0; mt < 5; ++mt)
#pragma unroll
    for (int c = 0; c < 2; ++c)
#pragma unroll
      for (int r = 0; r < 4; ++r)
        smem[mt * 2048 + (w * 16 + q * 4 + r) * 32 + c * 16 + m] = f2bf(acc[mt][c][r]);
  __syncthreads();
  {
    int row = t >> 2, q4 = t & 3;
    if (row < cnt) {
      int node = tidx[base + row];
      {
        const u16* sp = &smem[row * 32 + q4 * 8];
        unsigned long long pk = 0;
#pragma unroll
        for (int j = 0; j < 8; ++j)
          pk |= (unsigned long long)f2fp8(bf2f(sp[j])) << (8 * j);
        *(unsigned long long*)&Kb8[(size_t)node * 256 + h * 32 + q4 * 8] = pk;
      }
      {
        const u16* sp = &smem[2048 + row * 32 + q4 * 8];
        unsigned long long pk = 0;
#pragma unroll
        for (int j = 0; j < 8; ++j)
          pk |= (unsigned long long)f2fp8(bf2f(sp[j])) << (8 * j);
        *(unsigned long long*)&Vb8[(size_t)node * 256 + h * 32 + q4 * 8] = pk;
      }
#pragma unroll
      for (int et = 0; et < ETYPE; ++et)
        *(uint4*)&Qeb[((size_t)node * ETYPE + et) * 256 + h * 32 + q4 * 8] =
            *(const uint4*)&smem[(2 + et) * 2048 + row * 32 + q4 * 8];
    }
  }
}

// ---------------------------------------------------------------------------
// Edge scores -> exp(score). fp8 K gather (5 MB working set)
// ---------------------------------------------------------------------------
__global__ __launch_bounds__(256) void score_kernel(
    const int* __restrict__ csr_src, const int* __restrict__ csr_dst,
    const int* __restrict__ csr_et, const u16* __restrict__ Qeb,
    const u8* __restrict__ Kb8, const float* __restrict__ mu,
    float* __restrict__ scores, int E) {
  int tid = blockIdx.x * 256 + threadIdx.x;
  if (tid >= E * NHEAD) return;
  int p = tid >> 3, h = tid & 7;
  int s = csr_src[p], d = csr_dst[p], t = csr_et[p];
  const bf16x8* q = (const bf16x8*)(Qeb + ((size_t)d * ETYPE + t) * 256 + h * 32);
  const uint2* k = (const uint2*)(Kb8 + (size_t)s * 256 + h * 32);
  float acc = 0.f;
#pragma unroll
  for (int g = 0; g < 4; ++g) {
    uint2 kd = k[g];
    bf16x8 qq = q[g];
#pragma unroll
    for (int b = 0; b < 4; ++b) {
      acc += fp82f((kd.x >> (8 * b)) & 0xffu) * (float)qq[b];
      acc += fp82f((kd.y >> (8 * b)) & 0xffu) * (float)qq[4 + b];
    }
  }
  scores[tid] = __expf(acc * 0.17677669529663687f * mu[h * ETYPE + t]);
}

// ---------------------------------------------------------------------------
// Segment softmax + V aggregation with 4-WAY EDGE PARALLELISM: 4 groups of
// 64 threads each walk every 4th edge (4 independent gather chains in flight).
// Thread covers 4 dims via one uint (4xfp8) load; cross-group reduce
// through LDS once at the end.
// ---------------------------------------------------------------------------
__global__ __launch_bounds__(256) void agg_kernel(
    const int* __restrict__ off, const int* __restrict__ csr_src,
    const float* __restrict__ scores, const u8* __restrict__ Vb8,
    u16* __restrict__ aggb) {
  __shared__ float sacc[4][256];
  __shared__ float sssum[4][8];
  int n = blockIdx.x;
  int t = threadIdx.x;
  int g = t >> 6;          // edge group 0..3
  int l = t & 63;          // lane in group
  int d0 = l * 4;          // dims [d0, d0+4)
  int h = l >> 3;          // head of these dims
  int s0 = off[n], s1 = off[n + 1];
  float a0 = 0.f, a1 = 0.f, a2 = 0.f, a3 = 0.f, ssum = 0.f;
  for (int k = s0 + g; k < s1; k += 4) {
    int sn = csr_src[k];
    float e = scores[(size_t)k * 8 + h];
    unsigned v4 = *(const unsigned*)(Vb8 + (size_t)sn * 256 + d0);
    a0 += e * fp82f(v4 & 0xffu);
    a1 += e * fp82f((v4 >> 8) & 0xffu);
    a2 += e * fp82f((v4 >> 16) & 0xffu);
    a3 += e * fp82f((v4 >> 24) & 0xffu);
    ssum += e;
  }
  *(float4*)&sacc[g][d0] = make_float4(a0, a1, a2, a3);
  if ((l & 7) == 0) sssum[g][h] = ssum;
  __syncthreads();
  int hh = t >> 5;
  float tot = sacc[0][t] + sacc[1][t] + sacc[2][t] + sacc[3][t];
  float st = sssum[0][hh] + sssum[1][hh] + sssum[2][hh] + sssum[3][hh];
  aggb[(size_t)n * 256 + t] = f2bf(tot / (st + 1e-10f));
}

// ---------------------------------------------------------------------------
// fp32 [K,Nc] -> bf16 transposed [Nc,K]
// ---------------------------------------------------------------------------
__global__ __launch_bounds__(256) void convT_kernel(const float* __restrict__ W,
                                                    u16* __restrict__ Wt, int K, int Nc) {
  __shared__ float tile[32][33];
  int bk = blockIdx.y * 32, bn = blockIdx.x * 32;
  const float* Wz = W + (size_t)blockIdx.z * K * Nc;
  u16* Wtz = Wt + (size_t)blockIdx.z * K * Nc;
  int tx = threadIdx.x & 31, ty = threadIdx.x >> 5;
  for (int r = ty; r < 32; r += 8)
    tile[r][tx] = Wz[(size_t)(bk + r) * Nc + bn + tx];
  __syncthreads();
  for (int r = ty; r < 32; r += 8)
    Wtz[(size_t)(bn + r) * K + bk + tx] = f2bf(tile[tx][r]);
}

// ---------------------------------------------------------------------------
// bf16 MFMA GEMM: C[M,Nc] = A[M,K] @ Bt[Nc,K]^T + bias -> bf16 out.
// BM=128, BN template. GELU=1 adds fast-GELU to the epilogue.
//
// PIPELINE (T3/T4 minimum 2-phase): LDS double-buffered; STAGE for tile
// t+1 is issued between the ds_reads and the MFMA cluster of tile t, so
// the vmcnt(0) drain at each __syncthreads waits for loads issued a full
// compute-phase earlier (was: issue->sync->compute, exposing full load
// latency on EVERY K-step; MfmaUtil 9%).
//
// LDS layout per 16-row chunk: [k-slot(4)][row(16)] in 16B units (via
// per-lane global SOURCE addresses; LDS dest linear) -> bank-conflict-free
// fragment reads (verified: SQ_LDS_BANK_CONFLICT 1.29M -> 0).
// ---------------------------------------------------------------------------
template <int GELU, int BN>
__global__ __launch_bounds__(256) void gemm_mfma(
    const u16* __restrict__ A, const u16* __restrict__ Bt,
    const float* __restrict__ bias, u16* __restrict__ Cb,
    int M, int K, int Nc) {
  constexpr int MJ = BN / 32;
  __shared__ u16 As[2][128 * 32];
  __shared__ u16 Bs[2][BN * 32];
  const int t = threadIdx.x;
  const int lane = t & 63;
  const int w = t >> 6;
  const int row0 = blockIdx.y * 128;
  const int col0 = blockIdx.x * BN;
  const int wm = (w >> 1) * 64, wn = (w & 1) * (BN / 2);

  f32x4 acc[4][MJ] = {};
  const int lr16 = lane & 15;   // row within a 16-row chunk
  const int sl = lane >> 4;     // k-slot (8 bf16 = 16B)

  auto STAGE = [&](int buf, int k0) {
#pragma unroll
    for (int c = 0; c < 2; ++c) {
      const int chunk = w * 2 + c;
      const int r = chunk * 16 + lr16;
      int ra = row0 + r; if (ra >= M) ra = M - 1;
      GLDS16(A + (size_t)ra * K + k0 + sl * 8, &As[buf][(chunk * 64 + lane) * 8]);
      if (BN == 128) {
        GLDS16(Bt + (size_t)(col0 + r) * K + k0 + sl * 8, &Bs[buf][(chunk * 64 + lane) * 8]);
      }
    }
    if (BN == 64) {
      const int r = w * 16 + lr16;
      GLDS16(Bt + (size_t)(col0 + r) * K + k0 + sl * 8, &Bs[buf][(w * 64 + lane) * 8]);
    }
  };

  auto COMPUTE = [&](int buf, int knext, int bufnext) {
    __syncthreads();  // drains vmcnt for buf's loads (issued one phase ago)
    bf16x8 af[4], bfr[MJ];
#pragma unroll
    for (int i = 0; i < 4; ++i)
      af[i] = *(const bf16x8*)&As[buf][((wm >> 4) + i) * 512 + sl * 128 + lr16 * 8];
#pragma unroll
    for (int j = 0; j < MJ; ++j)
      bfr[j] = *(const bf16x8*)&Bs[buf][((wn >> 4) + j) * 512 + sl * 128 + lr16 * 8];
    if (knext < K) STAGE(bufnext, knext);  // prefetch next tile (safe: bufnext's
                                           // readers all completed before the barrier)
#pragma unroll
    for (int i = 0; i < 4; ++i)
#pragma unroll
      for (int j = 0; j < MJ; ++j)
        acc[i][j] = __builtin_amdgcn_mfma_f32_16x16x32_bf16(af[i], bfr[j], acc[i][j], 0, 0, 0);
  };

  STAGE(0, 0);
  for (int k0 = 0; k0 < K; k0 += 64) {  // K is a multiple of 64 here
    COMPUTE(0, k0 + 32, 1);
    COMPUTE(1, k0 + 64, 0);
  }

  const int lc = lane & 15;
  const int lrow = (lane >> 4) * 4;
  float bv[MJ];
#pragma unroll
  for (int j = 0; j < MJ; ++j) bv[j] = bias[col0 + wn + j * 16 + lc];
#pragma unroll
  for (int i = 0; i < 4; ++i) {
#pragma unroll
    for (int r = 0; r < 4; ++r) {
      int gr = row0 + wm + i * 16 + lrow + r;
      if (gr >= M) continue;
#pragma unroll
      for (int j = 0; j < MJ; ++j) {
        int gc = col0 + wn + j * 16 + lc;
        float v = acc[i][j][r] + bv[j];
        if (GELU) v = gelu_f(v);
        Cb[(size_t)gr * Nc + gc] = f2bf(v);
      }
    }
  }
}

// ---------------------------------------------------------------------------
// LayerNorm rows of 256: out = LN(xin + res) * g + b; res is bf16 (or null).
// xbuf stays the fp32 residual master.
// ---------------------------------------------------------------------------
__global__ __launch_bounds__(256) void ln_kernel(
    const float* __restrict__ xin, const u16* __restrict__ res,
    const float* __restrict__ g, const float* __restrict__ b,
    float* __restrict__ out, u16* __restrict__ outb) {
  int n = blockIdx.x;
  int t = threadIdx.x;
  __shared__ float red[8];
  size_t idx = (size_t)n * 256 + t;
  float r = xin[idx] + (res ? bf2f(res[idx]) : 0.f);
  float s = r;
  for (int o = 32; o > 0; o >>= 1) s += __shfl_xor(s, o, 64);
  if ((t & 63) == 0) red[t >> 6] = s;
  __syncthreads();
  float m = (red[0] + red[1] + red[2] + red[3]) * (1.f / 256.f);
  float d = r - m;
  float s2 = d * d;
  for (int o = 32; o > 0; o >>= 1) s2 += __shfl_xor(s2, o, 64);
  if ((t & 63) == 0) red[4 + (t >> 6)] = s2;
  __syncthreads();
  float var = (red[4] + red[5] + red[6] + red[7]) * (1.f / 256.f);
  float o = d * rsqrtf(var + 1e-5f) * g[t] + b[t];
  out[idx] = o;
  if (outb) outb[idx] = f2bf(o);
}

// ---------------------------------------------------------------------------
extern "C" void kernel_launch(void* const* d_in, const int* in_sizes, int n_in,
                              void* d_out, int out_size, void* d_ws, size_t ws_size,
                              hipStream_t stream) {
  const float* x_in   = (const float*)d_in[0];
  const int*   ei     = (const int*)d_in[1];
  const int*   etype  = (const int*)d_in[2];
  const int*   ntype  = (const int*)d_in[3];
  const float* W_Q    = (const float*)d_in[4];
  const float* W_K    = (const float*)d_in[5];
  const float* W_V    = (const float*)d_in[6];
  const float* W_E    = (const float*)d_in[7];
  const float* mu     = (const float*)d_in[8];
  const float* Wo     = (const float*)d_in[9];
  const float* bo     = (const float*)d_in[10];
  const float* ln1g   = (const float*)d_in[11];
  const float* ln1b   = (const float*)d_in[12];
  const float* ln2g   = (const float*)d_in[13];
  const float* ln2b   = (const float*)d_in[14];
  const float* w1     = (const float*)d_in[15];
  const float* b1     = (const float*)d_in[16];
  const float* w2     = (const float*)d_in[17];
  const float* b2     = (const float*)d_in[18];
  const float* outg   = (const float*)d_in[19];
  const float* outb   = (const float*)d_in[20];

  const int N = in_sizes[0] / DMODEL;    // 20000
  const int E = in_sizes[1] / 2;         // 320000
  const int* src = ei;
  const int* dst = ei + E;

  const size_t NF = (size_t)N * DMODEL;
  const size_t EH = (size_t)E * NHEAD;

  // ---- workspace layout ----
  float* f      = (float*)d_ws;
  float* xbuf   = f;                     // NF fp32 (residual master)
  float* scores = f + NF;                // EH fp32 (holds exp(score))
  u16*   fout   = (u16*)(f + NF + EH);   // NF bf16 (GEMM outputs)
  u16*   xb     = fout + NF;             // NF bf16
  u16*   Qeb    = xb + NF;               // 3NF bf16  } h1b aliases Qeb
  u16*   h1b    = Qeb;                   // alias (2NF used, FFN phase only)
  u16*   aggb   = Qeb + 3 * NF;          // NF bf16
  u8*    Kb8    = (u8*)(aggb + NF);      // NF bytes fp8
  u8*    Vb8    = Kb8 + NF;              // NF bytes fp8
  u16*   wqkvb  = (u16*)(Vb8 + NF);      // 96 * 5120
  u16*   Wot    = wqkvb + (size_t)NLAYER * NTYPE * NHEAD * 5120;
  u16*   w1t    = Wot + 3 * 65536;
  u16*   w2t    = w1t + 3 * 262144;
  int*   ip     = (int*)(w2t + 3 * 262144);
  int*   off    = ip;                    // N+1
  int*   csr_src= off + (N + 1);         // E
  int*   csr_dst= csr_src + E;           // E
  int*   csr_et = csr_dst + E;           // E
  int*   cursor = csr_et + E;            // N
  int*   tidx   = cursor + N;            // N
  int*   toff   = tidx + N;              // NTYPE+1
  int*   tile_off = toff + (NTYPE + 1);  // NTYPE+1
  int*   tcnt   = tile_off + (NTYPE + 1);// NTYPE
  int*   tcur   = tcnt + NTYPE;          // NTYPE

  // ---- CSR + type buckets (once) ----
  hipMemsetAsync(cursor, 0, (size_t)N * sizeof(int), stream);
  hipMemsetAsync(tcnt, 0, 2 * NTYPE * sizeof(int), stream);
  count_deg_kernel<<<(E + 255) / 256, 256, 0, stream>>>(dst, cursor, E);
  scan_kernel<<<1, 1024, 0, stream>>>(cursor, off, N);
  hipMemsetAsync(cursor, 0, (size_t)N * sizeof(int), stream);
  scatter_kernel<<<(E + 255) / 256, 256, 0, stream>>>(
      src, dst, etype, off, cursor, csr_src, csr_dst, csr_et, E);
  tcount_kernel<<<(N + 255) / 256, 256, 0, stream>>>(ntype, tcnt, N);
  tscan_kernel<<<1, 64, 0, stream>>>(tcnt, toff, tile_off);
  tscatter_kernel<<<(N + 255) / 256, 256, 0, stream>>>(ntype, toff, tcur, tidx, N);

  // ---- weight prep (once) ----
  wprep_kernel<<<NLAYER * NTYPE * NHEAD, 256, 0, stream>>>(W_Q, W_K, W_V, W_E, wqkvb);
  convT_kernel<<<dim3(DMODEL / 32, DMODEL / 32, NLAYER), 256, 0, stream>>>(
      Wo, Wot, DMODEL, DMODEL);
  convT_kernel<<<dim3(4 * DMODEL / 32, DMODEL / 32, NLAYER), 256, 0, stream>>>(
      w1, w1t, DMODEL, 4 * DMODEL);
  convT_kernel<<<dim3(DMODEL / 32, 4 * DMODEL / 32, NLAYER), 256, 0, stream>>>(
      w2, w2t, 4 * DMODEL, DMODEL);

  // ---- x working copies ----
  hipMemcpyAsync(xbuf, x_in, NF * sizeof(float), hipMemcpyDeviceToDevice, stream);
  xconv_kernel<<<(int)((NF / 4 + 255) / 256), 256, 0, stream>>>(x_in, xb, (int)(NF / 4));

  const int gm = (N + 127) / 128;
  const int qtiles = (N + 63) / 64 + NTYPE;
  for (int l = 0; l < NLAYER; ++l) {
    qkv_mfma<<<dim3(qtiles, NHEAD), 256, 0, stream>>>(
        xb, tidx, toff, tile_off,
        wqkvb + (size_t)l * NTYPE * NHEAD * 5120, Kb8, Vb8, Qeb);
    score_kernel<<<(int)((EH + 255) / 256), 256, 0, stream>>>(
        csr_src, csr_dst, csr_et, Qeb, Kb8, mu + (size_t)l * NHEAD * ETYPE, scores, E);
    agg_kernel<<<N, 256, 0, stream>>>(off, csr_src, scores, Vb8, aggb);

    gemm_mfma<0, 64><<<dim3(DMODEL / 64, gm), 256, 0, stream>>>(
        aggb, Wot + (size_t)l * 65536, bo + (size_t)l * DMODEL,
        fout, N, DMODEL, DMODEL);
    ln_kernel<<<N, 256, 0, stream>>>(xbuf, fout,
        ln1g + (size_t)l * DMODEL, ln1b + (size_t)l * DMODEL, xbuf, xb);
    gemm_mfma<1, 128><<<dim3(4 * DMODEL / 128, gm), 256, 0, stream>>>(
        xb, w1t + (size_t)l * 262144, b1 + (size_t)l * 4 * DMODEL,
        h1b, N, DMODEL, 4 * DMODEL);
    gemm_mfma<0, 64><<<dim3(DMODEL / 64, gm), 256, 0, stream>>>(
        h1b, w2t + (size_t)l * 262144, b2 + (size_t)l * DMODEL,
        fout, N, 4 * DMODEL, DMODEL);
    ln_kernel<<<N, 256, 0, stream>>>(xbuf, fout,
        ln2g + (size_t)l * DMODEL, ln2b + (size_t)l * DMODEL, xbuf, xb);
  }

  ln_kernel<<<N, 256, 0, stream>>>(xbuf, nullptr, outg, outb, (float*)d_out, nullptr);
}

// Round 3
// 796.675 us; speedup vs baseline: 1.1185x; 1.1185x over previous
//
#include <hip/hip_runtime.h>
#include <hip/hip_fp8.h>
#include <math.h>

#define HDIM 32
#define NHEAD 8
#define DMODEL 256
#define NTYPE 4
#define ETYPE 3
#define NLAYER 3

typedef unsigned short u16;
typedef unsigned char u8;
typedef __bf16 bf16x8 __attribute__((ext_vector_type(8)));
typedef float f32x4 __attribute__((ext_vector_type(4)));

__device__ __forceinline__ u16 f2bf(float f) {
  union { float f; unsigned u; } v; v.f = f;
  unsigned r = v.u + 0x7FFF + ((v.u >> 16) & 1);
  return (u16)(r >> 16);
}
__device__ __forceinline__ float bf2f(u16 b) {
  union { unsigned u; float f; } v; v.u = (unsigned)b << 16; return v.f;
}
__device__ __forceinline__ u8 f2fp8(float v) {
  __hip_fp8_e4m3 t(v); return (u8)t.__x;
}
__device__ __forceinline__ float fp82f(unsigned b) {
  __hip_fp8_e4m3 t; t.__x = (__hip_fp8_storage_t)b; return (float)t;
}

// fast GELU (tanh form)
__device__ __forceinline__ float gelu_f(float v) {
  float u = 0.7978845608028654f * v * (1.f + 0.044715f * v * v);
  float e = __expf(-2.f * fabsf(u));
  float th = (1.f - e) / (1.f + e);
  th = copysignf(th, u);
  return 0.5f * v * (1.f + th);
}

#define GLDS16(g, l)                                              \
  __builtin_amdgcn_global_load_lds(                               \
      (const __attribute__((address_space(1))) void*)(g),         \
      (__attribute__((address_space(3))) void*)(l), 16, 0, 0)

// ---------------------------------------------------------------------------
// CSR build (dst-sorted edge VALUES in position order)
// ---------------------------------------------------------------------------
__global__ void count_deg_kernel(const int* __restrict__ dst, int* __restrict__ deg, int E) {
  int tid = blockIdx.x * 256 + threadIdx.x;
  if (tid < E) atomicAdd(&deg[dst[tid]], 1);
}

__global__ __launch_bounds__(1024) void scan_kernel(const int* __restrict__ deg,
                                                    int* __restrict__ off, int n) {
  __shared__ int part[1024];
  int t = threadIdx.x;
  int chunk = (n + 1023) >> 10;
  int base = t * chunk;
  int s = 0;
  for (int i = 0; i < chunk; ++i) {
    int idx = base + i;
    if (idx < n) s += deg[idx];
  }
  part[t] = s;
  __syncthreads();
  for (int o = 1; o < 1024; o <<= 1) {
    int v = (t >= o) ? part[t - o] : 0;
    __syncthreads();
    part[t] += v;
    __syncthreads();
  }
  int run = part[t] - s;
  for (int i = 0; i < chunk; ++i) {
    int idx = base + i;
    if (idx < n) { off[idx] = run; run += deg[idx]; }
  }
  if (t == 1023) off[n] = part[1023];
}

__global__ void scatter_kernel(const int* __restrict__ src, const int* __restrict__ dst,
                               const int* __restrict__ etype,
                               const int* __restrict__ off, int* __restrict__ cursor,
                               int* __restrict__ csr_src, int* __restrict__ csr_dst,
                               int* __restrict__ csr_et, int E) {
  int tid = blockIdx.x * 256 + threadIdx.x;
  if (tid < E) {
    int d = dst[tid];
    int p = atomicAdd(&cursor[d], 1);
    int pos = off[d] + p;
    csr_src[pos] = src[tid];
    csr_dst[pos] = d;
    csr_et[pos] = etype[tid];
  }
}

// ---------------------------------------------------------------------------
// Node-type buckets — hierarchical to avoid same-address atomic contention
// ---------------------------------------------------------------------------
__global__ void tcount_kernel(const int* __restrict__ nt, int* __restrict__ tcnt, int N) {
  __shared__ int h[NTYPE];
  int t = threadIdx.x;
  if (t < NTYPE) h[t] = 0;
  __syncthreads();
  int tid = blockIdx.x * 256 + t;
  if (tid < N) atomicAdd(&h[nt[tid]], 1);
  __syncthreads();
  if (t < NTYPE && h[t] > 0) atomicAdd(&tcnt[t], h[t]);
}

__global__ void tscan_kernel(const int* __restrict__ tcnt, int* __restrict__ toff,
                             int* __restrict__ tile_off) {
  if (threadIdx.x == 0 && blockIdx.x == 0) {
    int o = 0, to = 0;
    for (int t = 0; t < NTYPE; ++t) {
      toff[t] = o; tile_off[t] = to;
      o += tcnt[t]; to += (tcnt[t] + 63) >> 6;
    }
    toff[NTYPE] = o; tile_off[NTYPE] = to;
  }
}

__global__ void tscatter_kernel(const int* __restrict__ nt, const int* __restrict__ toff,
                                int* __restrict__ tcur, int* __restrict__ tidx, int N) {
  int tid = blockIdx.x * 256 + threadIdx.x;
  int lane = threadIdx.x & 63;
  int ty = (tid < N) ? nt[tid] : -1;
  unsigned long long lt_mask = (lane == 63) ? 0x7FFFFFFFFFFFFFFFull
                                            : ((1ull << lane) - 1);
#pragma unroll
  for (int t4 = 0; t4 < NTYPE; ++t4) {
    unsigned long long mask = __ballot(ty == t4);
    if (mask == 0) continue;
    int first = __builtin_ctzll(mask);
    int cnt = __popcll(mask);
    int base = 0;
    if (lane == first) base = atomicAdd(&tcur[t4], cnt);
    base = __shfl(base, first, 64);
    if (ty == t4) {
      int rank = __popcll(mask & lt_mask);
      tidx[toff[t4] + base + rank] = tid;
    }
  }
}

// ---------------------------------------------------------------------------
// x fp32 -> bf16 mirror
// ---------------------------------------------------------------------------
__global__ void xconv_kernel(const float* __restrict__ x, u16* __restrict__ xb, int n4) {
  int i = blockIdx.x * 256 + threadIdx.x;
  if (i < n4) {
    float4 v = ((const float4*)x)[i];
    ushort4 o = { f2bf(v.x), f2bf(v.y), f2bf(v.z), f2bf(v.w) };
    ((ushort4*)xb)[i] = o;
  }
}

// ---------------------------------------------------------------------------
// Weight prep, per (l,type,head): bf16 B-operand mats ([col][k], k contig):
//   mat0 = WK^T, mat1 = WV^T,
//   mat2..4 = WQE[et] with Qe = x @ (WQ @ WE[et]^T)
// ---------------------------------------------------------------------------
__global__ __launch_bounds__(256) void wprep_kernel(
    const float* __restrict__ W_Q, const float* __restrict__ W_K,
    const float* __restrict__ W_V, const float* __restrict__ W_E,
    u16* __restrict__ wqkvb) {
  int b = blockIdx.x;
  int h = b & 7, tt = (b >> 3) & 3, l = b >> 5;
  __shared__ float wq[1024];
  __shared__ float we[3][1024];
  int t = threadIdx.x;
  const float* WQp = W_Q + (((size_t)l * NTYPE + tt) * NHEAD + h) * 1024;
  for (int i = t; i < 1024; i += 256) wq[i] = WQp[i];
  for (int et = 0; et < ETYPE; ++et) {
    const float* WEp = W_E + (((size_t)l * ETYPE + et) * NHEAD + h) * 1024;
    for (int i = t; i < 1024; i += 256) we[et][i] = WEp[i];
  }
  __syncthreads();
  const float* WKp = W_K + (((size_t)l * NTYPE + tt) * NHEAD + h) * 1024;
  const float* WVp = W_V + (((size_t)l * NTYPE + tt) * NHEAD + h) * 1024;
  u16* out = wqkvb + (size_t)b * 5120;
  for (int i = t; i < 1024; i += 256) {
    int col = i >> 5, k = i & 31;
    out[i] = f2bf(WKp[k * 32 + col]);
    out[1024 + i] = f2bf(WVp[k * 32 + col]);
#pragma unroll
    for (int et = 0; et < ETYPE; ++et) {
      float a = 0.f;
#pragma unroll
      for (int j = 0; j < 32; ++j) a += wq[k * 32 + j] * we[et][col * 32 + j];
      out[(2 + et) * 1024 + i] = f2bf(a);
    }
  }
}

// ---------------------------------------------------------------------------
// QKV via MFMA over type buckets: K,V stored fp8 e4m3, Qe[3] bf16.
// LDS layout for MFMA operands is [k-slot][row] per 16-row chunk so the
// b128 fragment reads are bank-conflict-free (reg-staged ds_write, so the
// scatter layout is free here).
// ---------------------------------------------------------------------------
__global__ __launch_bounds__(256) void qkv_mfma(
    const u16* __restrict__ xb, const int* __restrict__ tidx,
    const int* __restrict__ toff, const int* __restrict__ tile_off,
    const u16* __restrict__ wqkvb_l,
    u8* __restrict__ Kb8, u8* __restrict__ Vb8, u16* __restrict__ Qeb) {
  __shared__ u16 smem[10240];
  int bx = blockIdx.x, h = blockIdx.y;
  if (bx >= tile_off[NTYPE]) return;
  int ty = 0;
  while (bx >= tile_off[ty + 1]) ++ty;
  int lt = bx - tile_off[ty];
  int base = toff[ty] + lt * 64;
  int cnt = min(64, toff[ty + 1] - toff[ty] - lt * 64);
  int t = threadIdx.x;
  {
    // x tile 64 rows x 32 k, stored as [rgroup(4)][slot(4)][row16(16)] 16B units
    int row = ((t >> 6) << 4) | (t & 15);
    int q = (t >> 4) & 3;
    int node = tidx[base + min(row, cnt - 1)];
    *(uint4*)&smem[t * 8] =
        *(const uint4*)&xb[(size_t)node * 256 + h * 32 + q * 8];
  }
  // weights: 5 mats of 32 cols x 32 k; store as [mt][slot(4)][col(32)] 16B units
  const u16* wsrc = wqkvb_l + ((size_t)ty * NHEAD + h) * 5120;
  for (int dc = t; dc < 640; dc += 256) {
    int mt = dc >> 7, wi = dc & 127, slot = wi >> 5, colx = wi & 31;
    *(uint4*)&smem[2048 + dc * 8] = *(const uint4*)&wsrc[(mt * 128 + colx * 4 + slot) * 8];
  }
  __syncthreads();

  int lane = t & 63, w = t >> 6;
  int m = lane & 15, q = lane >> 4;
  bf16x8 af = *(const bf16x8*)&smem[w * 512 + q * 128 + m * 8];
  f32x4 acc[5][2];
#pragma unroll
  for (int mt = 0; mt < 5; ++mt)
#pragma unroll
    for (int c = 0; c < 2; ++c) {
      bf16x8 bf = *(const bf16x8*)&smem[2048 + mt * 1024 + q * 256 + (c * 16 + m) * 8];
      acc[mt][c] = __builtin_amdgcn_mfma_f32_16x16x32_bf16(af, bf, (f32x4){0.f, 0.f, 0.f, 0.f}, 0, 0, 0);
    }
  __syncthreads();
#pragma unroll
  for (int mt = 0; mt < 5; ++mt)
#pragma unroll
    for (int c = 0; c < 2; ++c)
#pragma unroll
      for (int r = 0; r < 4; ++r)
        smem[mt * 2048 + (w * 16 + q * 4 + r) * 32 + c * 16 + m] = f2bf(acc[mt][c][r]);
  __syncthreads();
  {
    int row = t >> 2, q4 = t & 3;
    if (row < cnt) {
      int node = tidx[base + row];
      {
        const u16* sp = &smem[row * 32 + q4 * 8];
        unsigned long long pk = 0;
#pragma unroll
        for (int j = 0; j < 8; ++j)
          pk |= (unsigned long long)f2fp8(bf2f(sp[j])) << (8 * j);
        *(unsigned long long*)&Kb8[(size_t)node * 256 + h * 32 + q4 * 8] = pk;
      }
      {
        const u16* sp = &smem[2048 + row * 32 + q4 * 8];
        unsigned long long pk = 0;
#pragma unroll
        for (int j = 0; j < 8; ++j)
          pk |= (unsigned long long)f2fp8(bf2f(sp[j])) << (8 * j);
        *(unsigned long long*)&Vb8[(size_t)node * 256 + h * 32 + q4 * 8] = pk;
      }
#pragma unroll
      for (int et = 0; et < ETYPE; ++et)
        *(uint4*)&Qeb[((size_t)node * ETYPE + et) * 256 + h * 32 + q4 * 8] =
            *(const uint4*)&smem[(2 + et) * 2048 + row * 32 + q4 * 8];
    }
  }
}

// ---------------------------------------------------------------------------
// Edge scores -> exp(score). fp8 K gather (5 MB working set)
// ---------------------------------------------------------------------------
__global__ __launch_bounds__(256) void score_kernel(
    const int* __restrict__ csr_src, const int* __restrict__ csr_dst,
    const int* __restrict__ csr_et, const u16* __restrict__ Qeb,
    const u8* __restrict__ Kb8, const float* __restrict__ mu,
    float* __restrict__ scores, int E) {
  int tid = blockIdx.x * 256 + threadIdx.x;
  if (tid >= E * NHEAD) return;
  int p = tid >> 3, h = tid & 7;
  int s = csr_src[p], d = csr_dst[p], t = csr_et[p];
  const bf16x8* q = (const bf16x8*)(Qeb + ((size_t)d * ETYPE + t) * 256 + h * 32);
  const uint2* k = (const uint2*)(Kb8 + (size_t)s * 256 + h * 32);
  float acc = 0.f;
#pragma unroll
  for (int g = 0; g < 4; ++g) {
    uint2 kd = k[g];
    bf16x8 qq = q[g];
#pragma unroll
    for (int b = 0; b < 4; ++b) {
      acc += fp82f((kd.x >> (8 * b)) & 0xffu) * (float)qq[b];
      acc += fp82f((kd.y >> (8 * b)) & 0xffu) * (float)qq[4 + b];
    }
  }
  scores[tid] = __expf(acc * 0.17677669529663687f * mu[h * ETYPE + t]);
}

// ---------------------------------------------------------------------------
// Segment softmax + V aggregation with 4-WAY EDGE PARALLELISM: 4 groups of
// 64 threads each walk every 4th edge (4 independent gather chains in flight).
// Thread covers 4 dims via one uint (4xfp8) load; cross-group reduce
// through LDS once at the end.
// ---------------------------------------------------------------------------
__global__ __launch_bounds__(256) void agg_kernel(
    const int* __restrict__ off, const int* __restrict__ csr_src,
    const float* __restrict__ scores, const u8* __restrict__ Vb8,
    u16* __restrict__ aggb) {
  __shared__ float sacc[4][256];
  __shared__ float sssum[4][8];
  int n = blockIdx.x;
  int t = threadIdx.x;
  int g = t >> 6;          // edge group 0..3
  int l = t & 63;          // lane in group
  int d0 = l * 4;          // dims [d0, d0+4)
  int h = l >> 3;          // head of these dims
  int s0 = off[n], s1 = off[n + 1];
  float a0 = 0.f, a1 = 0.f, a2 = 0.f, a3 = 0.f, ssum = 0.f;
  for (int k = s0 + g; k < s1; k += 4) {
    int sn = csr_src[k];
    float e = scores[(size_t)k * 8 + h];
    unsigned v4 = *(const unsigned*)(Vb8 + (size_t)sn * 256 + d0);
    a0 += e * fp82f(v4 & 0xffu);
    a1 += e * fp82f((v4 >> 8) & 0xffu);
    a2 += e * fp82f((v4 >> 16) & 0xffu);
    a3 += e * fp82f((v4 >> 24) & 0xffu);
    ssum += e;
  }
  *(float4*)&sacc[g][d0] = make_float4(a0, a1, a2, a3);
  if ((l & 7) == 0) sssum[g][h] = ssum;
  __syncthreads();
  int hh = t >> 5;
  float tot = sacc[0][t] + sacc[1][t] + sacc[2][t] + sacc[3][t];
  float st = sssum[0][hh] + sssum[1][hh] + sssum[2][hh] + sssum[3][hh];
  aggb[(size_t)n * 256 + t] = f2bf(tot / (st + 1e-10f));
}

// ---------------------------------------------------------------------------
// fp32 [K,Nc] -> bf16 transposed [Nc,K]
// ---------------------------------------------------------------------------
__global__ __launch_bounds__(256) void convT_kernel(const float* __restrict__ W,
                                                    u16* __restrict__ Wt, int K, int Nc) {
  __shared__ float tile[32][33];
  int bk = blockIdx.y * 32, bn = blockIdx.x * 32;
  const float* Wz = W + (size_t)blockIdx.z * K * Nc;
  u16* Wtz = Wt + (size_t)blockIdx.z * K * Nc;
  int tx = threadIdx.x & 31, ty = threadIdx.x >> 5;
  for (int r = ty; r < 32; r += 8)
    tile[r][tx] = Wz[(size_t)(bk + r) * Nc + bn + tx];
  __syncthreads();
  for (int r = ty; r < 32; r += 8)
    Wtz[(size_t)(bn + r) * K + bk + tx] = f2bf(tile[tx][r]);
}

// ---------------------------------------------------------------------------
// bf16 MFMA GEMM: C[M,Nc] = A[M,K] @ Bt[Nc,K]^T + bias -> bf16 out.
// BM=128, BN template. GELU=1 adds fast-GELU to the epilogue.
//
// R0 loop structure (single buffer, 2 barriers/K-step — dbuf measured WORSE:
// 73µs vs 41µs, compiler can't disambiguate LDS buffers).
//
// XOR slot-swizzle, coalescing-preserving (rule #21, both sides):
//   stage:  lane l = (row sr=l>>2, dest-slot sk0=l&3) fetches SOURCE slot
//           sk0 ^ ((sr>>1)&3) of its 64B row segment -> same cache line per
//           4-lane group (coalescing == R0), LDS dest linear.
//   read:   (row lr, slot ks) lives at unit lr*4 + (ks ^ ((lr>>1)&3));
//           bank = (16*lr + 4*slot') %32 -> lane bits {0},{1,2} span all 8
//           bank-groups, 2 lanes/bank = free (m136). Was 8-way in R0.
// ---------------------------------------------------------------------------
template <int GELU, int BN>
__global__ __launch_bounds__(256) void gemm_mfma(
    const u16* __restrict__ A, const u16* __restrict__ Bt,
    const float* __restrict__ bias, u16* __restrict__ Cb,
    int M, int K, int Nc) {
  constexpr int MJ = BN / 32;
  __shared__ u16 As[128 * 32];
  __shared__ u16 Bs[BN * 32];
  const int t = threadIdx.x;
  const int lane = t & 63;
  const int w = t >> 6;
  const int row0 = blockIdx.y * 128;
  const int col0 = blockIdx.x * BN;
  const int wm = (w >> 1) * 64, wn = (w & 1) * (BN / 2);

  f32x4 acc[4][MJ] = {};
  const int sr = lane >> 2;                  // stage row-in-chunk
  const int sk0 = lane & 3;                  // stage dest slot
  const int sks = sk0 ^ ((sr >> 1) & 3);     // stage source slot (XOR swizzle)

  for (int k0 = 0; k0 < K; k0 += 32) {
#pragma unroll
    for (int c = 0; c < 2; ++c) {
      const int chunk = w * 2 + c;
      const int r = chunk * 16 + sr;
      int ra = row0 + r; if (ra >= M) ra = M - 1;
      GLDS16(A + (size_t)ra * K + k0 + sks * 8, &As[(chunk * 64 + lane) * 8]);
      if (BN == 128) {
        GLDS16(Bt + (size_t)(col0 + r) * K + k0 + sks * 8, &Bs[(chunk * 64 + lane) * 8]);
      }
    }
    if (BN == 64) {
      const int r = w * 16 + sr;
      GLDS16(Bt + (size_t)(col0 + r) * K + k0 + sks * 8, &Bs[(w * 64 + lane) * 8]);
    }
    __syncthreads();
    bf16x8 af[4], bfr[MJ];
    const int ks = lane >> 4;    // k-slot of this lane's fragment
    const int lr = lane & 15;    // row within 16-row chunk
    const int rsl = ks ^ ((lr >> 1) & 3);  // swizzled slot (same involution)
#pragma unroll
    for (int i = 0; i < 4; ++i)
      af[i] = *(const bf16x8*)&As[(((wm >> 4) + i) * 64 + lr * 4 + rsl) * 8];
#pragma unroll
    for (int j = 0; j < MJ; ++j)
      bfr[j] = *(const bf16x8*)&Bs[(((wn >> 4) + j) * 64 + lr * 4 + rsl) * 8];
#pragma unroll
    for (int i = 0; i < 4; ++i)
#pragma unroll
      for (int j = 0; j < MJ; ++j)
        acc[i][j] = __builtin_amdgcn_mfma_f32_16x16x32_bf16(af[i], bfr[j], acc[i][j], 0, 0, 0);
    __syncthreads();
  }

  const int lc = lane & 15;
  const int lrow = (lane >> 4) * 4;
  float bv[MJ];
#pragma unroll
  for (int j = 0; j < MJ; ++j) bv[j] = bias[col0 + wn + j * 16 + lc];
#pragma unroll
  for (int i = 0; i < 4; ++i) {
#pragma unroll
    for (int r = 0; r < 4; ++r) {
      int gr = row0 + wm + i * 16 + lrow + r;
      if (gr >= M) continue;
#pragma unroll
      for (int j = 0; j < MJ; ++j) {
        int gc = col0 + wn + j * 16 + lc;
        float v = acc[i][j][r] + bv[j];
        if (GELU) v = gelu_f(v);
        Cb[(size_t)gr * Nc + gc] = f2bf(v);
      }
    }
  }
}

// ---------------------------------------------------------------------------
// LayerNorm rows of 256: out = LN(xin + res) * g + b; res is bf16 (or null).
// Wave-per-row: lane holds float4 (64 lanes x 4 = 256), pure shfl_xor
// reductions — no LDS, no barriers. 4 rows/block, vectorized loads/stores.
// ---------------------------------------------------------------------------
__global__ __launch_bounds__(256) void ln_kernel(
    const float* __restrict__ xin, const u16* __restrict__ res,
    const float* __restrict__ g, const float* __restrict__ b,
    float* __restrict__ out, u16* __restrict__ outb, int N) {
  int row = blockIdx.x * 4 + (threadIdx.x >> 6);
  if (row >= N) return;
  int l = threadIdx.x & 63;
  size_t base = (size_t)row * 256 + l * 4;
  float4 r4 = *(const float4*)&xin[base];
  if (res) {
    ushort4 rb = *(const ushort4*)&res[base];
    r4.x += bf2f(rb.x); r4.y += bf2f(rb.y);
    r4.z += bf2f(rb.z); r4.w += bf2f(rb.w);
  }
  float s = r4.x + r4.y + r4.z + r4.w;
  for (int o = 32; o > 0; o >>= 1) s += __shfl_xor(s, o, 64);
  float m = s * (1.f / 256.f);
  float dx = r4.x - m, dy = r4.y - m, dz = r4.z - m, dw = r4.w - m;
  float s2 = dx * dx + dy * dy + dz * dz + dw * dw;
  for (int o = 32; o > 0; o >>= 1) s2 += __shfl_xor(s2, o, 64);
  float inv = rsqrtf(s2 * (1.f / 256.f) + 1e-5f);
  float4 g4 = *(const float4*)&g[l * 4];
  float4 b4 = *(const float4*)&b[l * 4];
  float4 o4 = { dx * inv * g4.x + b4.x, dy * inv * g4.y + b4.y,
                dz * inv * g4.z + b4.z, dw * inv * g4.w + b4.w };
  *(float4*)&out[base] = o4;
  if (outb) {
    ushort4 ob = { f2bf(o4.x), f2bf(o4.y), f2bf(o4.z), f2bf(o4.w) };
    *(ushort4*)&outb[base] = ob;
  }
}

// ---------------------------------------------------------------------------
extern "C" void kernel_launch(void* const* d_in, const int* in_sizes, int n_in,
                              void* d_out, int out_size, void* d_ws, size_t ws_size,
                              hipStream_t stream) {
  const float* x_in   = (const float*)d_in[0];
  const int*   ei     = (const int*)d_in[1];
  const int*   etype  = (const int*)d_in[2];
  const int*   ntype  = (const int*)d_in[3];
  const float* W_Q    = (const float*)d_in[4];
  const float* W_K    = (const float*)d_in[5];
  const float* W_V    = (const float*)d_in[6];
  const float* W_E    = (const float*)d_in[7];
  const float* mu     = (const float*)d_in[8];
  const float* Wo     = (const float*)d_in[9];
  const float* bo     = (const float*)d_in[10];
  const float* ln1g   = (const float*)d_in[11];
  const float* ln1b   = (const float*)d_in[12];
  const float* ln2g   = (const float*)d_in[13];
  const float* ln2b   = (const float*)d_in[14];
  const float* w1     = (const float*)d_in[15];
  const float* b1     = (const float*)d_in[16];
  const float* w2     = (const float*)d_in[17];
  const float* b2     = (const float*)d_in[18];
  const float* outg   = (const float*)d_in[19];
  const float* outb   = (const float*)d_in[20];

  const int N = in_sizes[0] / DMODEL;    // 20000
  const int E = in_sizes[1] / 2;         // 320000
  const int* src = ei;
  const int* dst = ei + E;

  const size_t NF = (size_t)N * DMODEL;
  const size_t EH = (size_t)E * NHEAD;

  // ---- workspace layout ----
  float* f      = (float*)d_ws;
  float* xbuf   = f;                     // NF fp32 (residual master)
  float* scores = f + NF;                // EH fp32 (holds exp(score))
  u16*   fout   = (u16*)(f + NF + EH);   // NF bf16 (GEMM outputs)
  u16*   xb     = fout + NF;             // NF bf16
  u16*   Qeb    = xb + NF;               // 3NF bf16  } h1b aliases Qeb
  u16*   h1b    = Qeb;                   // alias (2NF used, FFN phase only)
  u16*   aggb   = Qeb + 3 * NF;          // NF bf16
  u8*    Kb8    = (u8*)(aggb + NF);      // NF bytes fp8
  u8*    Vb8    = Kb8 + NF;              // NF bytes fp8
  u16*   wqkvb  = (u16*)(Vb8 + NF);      // 96 * 5120
  u16*   Wot    = wqkvb + (size_t)NLAYER * NTYPE * NHEAD * 5120;
  u16*   w1t    = Wot + 3 * 65536;
  u16*   w2t    = w1t + 3 * 262144;
  int*   ip     = (int*)(w2t + 3 * 262144);
  int*   off    = ip;                    // N+1
  int*   csr_src= off + (N + 1);         // E
  int*   csr_dst= csr_src + E;           // E
  int*   csr_et = csr_dst + E;           // E
  int*   cursor = csr_et + E;            // N
  int*   tidx   = cursor + N;            // N
  int*   toff   = tidx + N;              // NTYPE+1
  int*   tile_off = toff + (NTYPE + 1);  // NTYPE+1
  int*   tcnt   = tile_off + (NTYPE + 1);// NTYPE
  int*   tcur   = tcnt + NTYPE;          // NTYPE

  // ---- CSR + type buckets (once) ----
  hipMemsetAsync(cursor, 0, (size_t)N * sizeof(int), stream);
  hipMemsetAsync(tcnt, 0, 2 * NTYPE * sizeof(int), stream);
  count_deg_kernel<<<(E + 255) / 256, 256, 0, stream>>>(dst, cursor, E);
  scan_kernel<<<1, 1024, 0, stream>>>(cursor, off, N);
  hipMemsetAsync(cursor, 0, (size_t)N * sizeof(int), stream);
  scatter_kernel<<<(E + 255) / 256, 256, 0, stream>>>(
      src, dst, etype, off, cursor, csr_src, csr_dst, csr_et, E);
  tcount_kernel<<<(N + 255) / 256, 256, 0, stream>>>(ntype, tcnt, N);
  tscan_kernel<<<1, 64, 0, stream>>>(tcnt, toff, tile_off);
  tscatter_kernel<<<(N + 255) / 256, 256, 0, stream>>>(ntype, toff, tcur, tidx, N);

  // ---- weight prep (once) ----
  wprep_kernel<<<NLAYER * NTYPE * NHEAD, 256, 0, stream>>>(W_Q, W_K, W_V, W_E, wqkvb);
  convT_kernel<<<dim3(DMODEL / 32, DMODEL / 32, NLAYER), 256, 0, stream>>>(
      Wo, Wot, DMODEL, DMODEL);
  convT_kernel<<<dim3(4 * DMODEL / 32, DMODEL / 32, NLAYER), 256, 0, stream>>>(
      w1, w1t, DMODEL, 4 * DMODEL);
  convT_kernel<<<dim3(DMODEL / 32, 4 * DMODEL / 32, NLAYER), 256, 0, stream>>>(
      w2, w2t, 4 * DMODEL, DMODEL);

  // ---- x working copies ----
  hipMemcpyAsync(xbuf, x_in, NF * sizeof(float), hipMemcpyDeviceToDevice, stream);
  xconv_kernel<<<(int)((NF / 4 + 255) / 256), 256, 0, stream>>>(x_in, xb, (int)(NF / 4));

  const int gm = (N + 127) / 128;
  const int lng = (N + 3) / 4;
  const int qtiles = (N + 63) / 64 + NTYPE;
  for (int l = 0; l < NLAYER; ++l) {
    qkv_mfma<<<dim3(qtiles, NHEAD), 256, 0, stream>>>(
        xb, tidx, toff, tile_off,
        wqkvb + (size_t)l * NTYPE * NHEAD * 5120, Kb8, Vb8, Qeb);
    score_kernel<<<(int)((EH + 255) / 256), 256, 0, stream>>>(
        csr_src, csr_dst, csr_et, Qeb, Kb8, mu + (size_t)l * NHEAD * ETYPE, scores, E);
    agg_kernel<<<N, 256, 0, stream>>>(off, csr_src, scores, Vb8, aggb);

    gemm_mfma<0, 64><<<dim3(DMODEL / 64, gm), 256, 0, stream>>>(
        aggb, Wot + (size_t)l * 65536, bo + (size_t)l * DMODEL,
        fout, N, DMODEL, DMODEL);
    ln_kernel<<<lng, 256, 0, stream>>>(xbuf, fout,
        ln1g + (size_t)l * DMODEL, ln1b + (size_t)l * DMODEL, xbuf, xb, N);
    gemm_mfma<1, 128><<<dim3(4 * DMODEL / 128, gm), 256, 0, stream>>>(
        xb, w1t + (size_t)l * 262144, b1 + (size_t)l * 4 * DMODEL,
        h1b, N, DMODEL, 4 * DMODEL);
    gemm_mfma<0, 64><<<dim3(DMODEL / 64, gm), 256, 0, stream>>>(
        h1b, w2t + (size_t)l * 262144, b2 + (size_t)l * DMODEL,
        fout, N, 4 * DMODEL, DMODEL);
    ln_kernel<<<lng, 256, 0, stream>>>(xbuf, fout,
        ln2g + (size_t)l * DMODEL, ln2b + (size_t)l * DMODEL, xbuf, xb, N);
  }

  ln_kernel<<<lng, 256, 0, stream>>>(xbuf, nullptr, outg, outb, (float*)d_out, nullptr, N);
}

// Round 4
// 756.046 us; speedup vs baseline: 1.1786x; 1.0537x over previous
//
#include <hip/hip_runtime.h>
#include <hip/hip_fp8.h>
#include <math.h>

#define HDIM 32
#define NHEAD 8
#define DMODEL 256
#define NTYPE 4
#define ETYPE 3
#define NLAYER 3

typedef unsigned short u16;
typedef unsigned char u8;
typedef __bf16 bf16x8 __attribute__((ext_vector_type(8)));
typedef float f32x4 __attribute__((ext_vector_type(4)));

__device__ __forceinline__ u16 f2bf(float f) {
  union { float f; unsigned u; } v; v.f = f;
  unsigned r = v.u + 0x7FFF + ((v.u >> 16) & 1);
  return (u16)(r >> 16);
}
__device__ __forceinline__ float bf2f(u16 b) {
  union { unsigned u; float f; } v; v.u = (unsigned)b << 16; return v.f;
}
__device__ __forceinline__ u8 f2fp8(float v) {
  __hip_fp8_e4m3 t(v); return (u8)t.__x;
}
__device__ __forceinline__ float fp82f(unsigned b) {
  __hip_fp8_e4m3 t; t.__x = (__hip_fp8_storage_t)b; return (float)t;
}

// fast GELU (tanh form)
__device__ __forceinline__ float gelu_f(float v) {
  float u = 0.7978845608028654f * v * (1.f + 0.044715f * v * v);
  float e = __expf(-2.f * fabsf(u));
  float th = (1.f - e) / (1.f + e);
  th = copysignf(th, u);
  return 0.5f * v * (1.f + th);
}

#define GLDS16(g, l)                                              \
  __builtin_amdgcn_global_load_lds(                               \
      (const __attribute__((address_space(1))) void*)(g),         \
      (__attribute__((address_space(3))) void*)(l), 16, 0, 0)

// ---------------------------------------------------------------------------
// CSR build (dst-sorted edge VALUES in position order)
// ---------------------------------------------------------------------------
__global__ void count_deg_kernel(const int* __restrict__ dst, int* __restrict__ deg, int E) {
  int tid = blockIdx.x * 256 + threadIdx.x;
  if (tid < E) atomicAdd(&deg[dst[tid]], 1);
}

__global__ __launch_bounds__(1024) void scan_kernel(const int* __restrict__ deg,
                                                    int* __restrict__ off, int n) {
  __shared__ int part[1024];
  int t = threadIdx.x;
  int chunk = (n + 1023) >> 10;
  int base = t * chunk;
  int s = 0;
  for (int i = 0; i < chunk; ++i) {
    int idx = base + i;
    if (idx < n) s += deg[idx];
  }
  part[t] = s;
  __syncthreads();
  for (int o = 1; o < 1024; o <<= 1) {
    int v = (t >= o) ? part[t - o] : 0;
    __syncthreads();
    part[t] += v;
    __syncthreads();
  }
  int run = part[t] - s;
  for (int i = 0; i < chunk; ++i) {
    int idx = base + i;
    if (idx < n) { off[idx] = run; run += deg[idx]; }
  }
  if (t == 1023) off[n] = part[1023];
}

__global__ void scatter_kernel(const int* __restrict__ src, const int* __restrict__ dst,
                               const int* __restrict__ etype,
                               const int* __restrict__ off, int* __restrict__ cursor,
                               int* __restrict__ csr_src, int* __restrict__ csr_dst,
                               int* __restrict__ csr_et, int E) {
  int tid = blockIdx.x * 256 + threadIdx.x;
  if (tid < E) {
    int d = dst[tid];
    int p = atomicAdd(&cursor[d], 1);
    int pos = off[d] + p;
    csr_src[pos] = src[tid];
    csr_dst[pos] = d;
    csr_et[pos] = etype[tid];
  }
}

// ---------------------------------------------------------------------------
// Node-type buckets — hierarchical to avoid same-address atomic contention
// ---------------------------------------------------------------------------
__global__ void tcount_kernel(const int* __restrict__ nt, int* __restrict__ tcnt, int N) {
  __shared__ int h[NTYPE];
  int t = threadIdx.x;
  if (t < NTYPE) h[t] = 0;
  __syncthreads();
  int tid = blockIdx.x * 256 + t;
  if (tid < N) atomicAdd(&h[nt[tid]], 1);
  __syncthreads();
  if (t < NTYPE && h[t] > 0) atomicAdd(&tcnt[t], h[t]);
}

__global__ void tscan_kernel(const int* __restrict__ tcnt, int* __restrict__ toff,
                             int* __restrict__ tile_off) {
  if (threadIdx.x == 0 && blockIdx.x == 0) {
    int o = 0, to = 0;
    for (int t = 0; t < NTYPE; ++t) {
      toff[t] = o; tile_off[t] = to;
      o += tcnt[t]; to += (tcnt[t] + 63) >> 6;
    }
    toff[NTYPE] = o; tile_off[NTYPE] = to;
  }
}

__global__ void tscatter_kernel(const int* __restrict__ nt, const int* __restrict__ toff,
                                int* __restrict__ tcur, int* __restrict__ tidx, int N) {
  int tid = blockIdx.x * 256 + threadIdx.x;
  int lane = threadIdx.x & 63;
  int ty = (tid < N) ? nt[tid] : -1;
  unsigned long long lt_mask = (lane == 63) ? 0x7FFFFFFFFFFFFFFFull
                                            : ((1ull << lane) - 1);
#pragma unroll
  for (int t4 = 0; t4 < NTYPE; ++t4) {
    unsigned long long mask = __ballot(ty == t4);
    if (mask == 0) continue;
    int first = __builtin_ctzll(mask);
    int cnt = __popcll(mask);
    int base = 0;
    if (lane == first) base = atomicAdd(&tcur[t4], cnt);
    base = __shfl(base, first, 64);
    if (ty == t4) {
      int rank = __popcll(mask & lt_mask);
      tidx[toff[t4] + base + rank] = tid;
    }
  }
}

// ---------------------------------------------------------------------------
// x fp32 -> bf16 mirror
// ---------------------------------------------------------------------------
__global__ void xconv_kernel(const float* __restrict__ x, u16* __restrict__ xb, int n4) {
  int i = blockIdx.x * 256 + threadIdx.x;
  if (i < n4) {
    float4 v = ((const float4*)x)[i];
    ushort4 o = { f2bf(v.x), f2bf(v.y), f2bf(v.z), f2bf(v.w) };
    ((ushort4*)xb)[i] = o;
  }
}

// ---------------------------------------------------------------------------
// Weight prep, per (l,type,head): bf16 B-operand mats ([col][k], k contig):
//   mat0 = WK^T, mat1 = WV^T,
//   mat2..4 = WQE[et] with Qe = x @ (WQ @ WE[et]^T)
// ---------------------------------------------------------------------------
__global__ __launch_bounds__(256) void wprep_kernel(
    const float* __restrict__ W_Q, const float* __restrict__ W_K,
    const float* __restrict__ W_V, const float* __restrict__ W_E,
    u16* __restrict__ wqkvb) {
  int b = blockIdx.x;
  int h = b & 7, tt = (b >> 3) & 3, l = b >> 5;
  __shared__ float wq[1024];
  __shared__ float we[3][1024];
  int t = threadIdx.x;
  const float* WQp = W_Q + (((size_t)l * NTYPE + tt) * NHEAD + h) * 1024;
  for (int i = t; i < 1024; i += 256) wq[i] = WQp[i];
  for (int et = 0; et < ETYPE; ++et) {
    const float* WEp = W_E + (((size_t)l * ETYPE + et) * NHEAD + h) * 1024;
    for (int i = t; i < 1024; i += 256) we[et][i] = WEp[i];
  }
  __syncthreads();
  const float* WKp = W_K + (((size_t)l * NTYPE + tt) * NHEAD + h) * 1024;
  const float* WVp = W_V + (((size_t)l * NTYPE + tt) * NHEAD + h) * 1024;
  u16* out = wqkvb + (size_t)b * 5120;
  for (int i = t; i < 1024; i += 256) {
    int col = i >> 5, k = i & 31;
    out[i] = f2bf(WKp[k * 32 + col]);
    out[1024 + i] = f2bf(WVp[k * 32 + col]);
#pragma unroll
    for (int et = 0; et < ETYPE; ++et) {
      float a = 0.f;
#pragma unroll
      for (int j = 0; j < 32; ++j) a += wq[k * 32 + j] * we[et][col * 32 + j];
      out[(2 + et) * 1024 + i] = f2bf(a);
    }
  }
}

// ---------------------------------------------------------------------------
// QKV via MFMA over type buckets: K,V stored fp8 e4m3, Qe[3] bf16.
// LDS layout for MFMA operands is [k-slot][row] per 16-row chunk so the
// b128 fragment reads are bank-conflict-free (reg-staged ds_write, so the
// scatter layout is free here).
// ---------------------------------------------------------------------------
__global__ __launch_bounds__(256) void qkv_mfma(
    const u16* __restrict__ xb, const int* __restrict__ tidx,
    const int* __restrict__ toff, const int* __restrict__ tile_off,
    const u16* __restrict__ wqkvb_l,
    u8* __restrict__ Kb8, u8* __restrict__ Vb8, u16* __restrict__ Qeb) {
  __shared__ u16 smem[10240];
  int bx = blockIdx.x, h = blockIdx.y;
  if (bx >= tile_off[NTYPE]) return;
  int ty = 0;
  while (bx >= tile_off[ty + 1]) ++ty;
  int lt = bx - tile_off[ty];
  int base = toff[ty] + lt * 64;
  int cnt = min(64, toff[ty + 1] - toff[ty] - lt * 64);
  int t = threadIdx.x;
  {
    // x tile 64 rows x 32 k, stored as [rgroup(4)][slot(4)][row16(16)] 16B units
    int row = ((t >> 6) << 4) | (t & 15);
    int q = (t >> 4) & 3;
    int node = tidx[base + min(row, cnt - 1)];
    *(uint4*)&smem[t * 8] =
        *(const uint4*)&xb[(size_t)node * 256 + h * 32 + q * 8];
  }
  // weights: 5 mats of 32 cols x 32 k; store as [mt][slot(4)][col(32)] 16B units
  const u16* wsrc = wqkvb_l + ((size_t)ty * NHEAD + h) * 5120;
  for (int dc = t; dc < 640; dc += 256) {
    int mt = dc >> 7, wi = dc & 127, slot = wi >> 5, colx = wi & 31;
    *(uint4*)&smem[2048 + dc * 8] = *(const uint4*)&wsrc[(mt * 128 + colx * 4 + slot) * 8];
  }
  __syncthreads();

  int lane = t & 63, w = t >> 6;
  int m = lane & 15, q = lane >> 4;
  bf16x8 af = *(const bf16x8*)&smem[w * 512 + q * 128 + m * 8];
  f32x4 acc[5][2];
#pragma unroll
  for (int mt = 0; mt < 5; ++mt)
#pragma unroll
    for (int c = 0; c < 2; ++c) {
      bf16x8 bf = *(const bf16x8*)&smem[2048 + mt * 1024 + q * 256 + (c * 16 + m) * 8];
      acc[mt][c] = __builtin_amdgcn_mfma_f32_16x16x32_bf16(af, bf, (f32x4){0.f, 0.f, 0.f, 0.f}, 0, 0, 0);
    }
  __syncthreads();
#pragma unroll
  for (int mt = 0; mt < 5; ++mt)
#pragma unroll
    for (int c = 0; c < 2; ++c)
#pragma unroll
      for (int r = 0; r < 4; ++r)
        smem[mt * 2048 + (w * 16 + q * 4 + r) * 32 + c * 16 + m] = f2bf(acc[mt][c][r]);
  __syncthreads();
  {
    int row = t >> 2, q4 = t & 3;
    if (row < cnt) {
      int node = tidx[base + row];
      {
        const u16* sp = &smem[row * 32 + q4 * 8];
        unsigned long long pk = 0;
#pragma unroll
        for (int j = 0; j < 8; ++j)
          pk |= (unsigned long long)f2fp8(bf2f(sp[j])) << (8 * j);
        *(unsigned long long*)&Kb8[(size_t)node * 256 + h * 32 + q4 * 8] = pk;
      }
      {
        const u16* sp = &smem[2048 + row * 32 + q4 * 8];
        unsigned long long pk = 0;
#pragma unroll
        for (int j = 0; j < 8; ++j)
          pk |= (unsigned long long)f2fp8(bf2f(sp[j])) << (8 * j);
        *(unsigned long long*)&Vb8[(size_t)node * 256 + h * 32 + q4 * 8] = pk;
      }
#pragma unroll
      for (int et = 0; et < ETYPE; ++et)
        *(uint4*)&Qeb[((size_t)node * ETYPE + et) * 256 + h * 32 + q4 * 8] =
            *(const uint4*)&smem[(2 + et) * 2048 + row * 32 + q4 * 8];
    }
  }
}

// ---------------------------------------------------------------------------
// Edge scores -> exp(score). fp8 K gather (5 MB working set)
// ---------------------------------------------------------------------------
__global__ __launch_bounds__(256) void score_kernel(
    const int* __restrict__ csr_src, const int* __restrict__ csr_dst,
    const int* __restrict__ csr_et, const u16* __restrict__ Qeb,
    const u8* __restrict__ Kb8, const float* __restrict__ mu,
    float* __restrict__ scores, int E) {
  int tid = blockIdx.x * 256 + threadIdx.x;
  if (tid >= E * NHEAD) return;
  int p = tid >> 3, h = tid & 7;
  int s = csr_src[p], d = csr_dst[p], t = csr_et[p];
  const bf16x8* q = (const bf16x8*)(Qeb + ((size_t)d * ETYPE + t) * 256 + h * 32);
  const uint2* k = (const uint2*)(Kb8 + (size_t)s * 256 + h * 32);
  float acc = 0.f;
#pragma unroll
  for (int g = 0; g < 4; ++g) {
    uint2 kd = k[g];
    bf16x8 qq = q[g];
#pragma unroll
    for (int b = 0; b < 4; ++b) {
      acc += fp82f((kd.x >> (8 * b)) & 0xffu) * (float)qq[b];
      acc += fp82f((kd.y >> (8 * b)) & 0xffu) * (float)qq[4 + b];
    }
  }
  scores[tid] = __expf(acc * 0.17677669529663687f * mu[h * ETYPE + t]);
}

// ---------------------------------------------------------------------------
// Segment softmax + V aggregation with 4-WAY EDGE PARALLELISM: 4 groups of
// 64 threads each walk every 4th edge (4 independent gather chains in flight).
// Thread covers 4 dims via one uint (4xfp8) load; cross-group reduce
// through LDS once at the end.
// ---------------------------------------------------------------------------
__global__ __launch_bounds__(256) void agg_kernel(
    const int* __restrict__ off, const int* __restrict__ csr_src,
    const float* __restrict__ scores, const u8* __restrict__ Vb8,
    u16* __restrict__ aggb) {
  __shared__ float sacc[4][256];
  __shared__ float sssum[4][8];
  int n = blockIdx.x;
  int t = threadIdx.x;
  int g = t >> 6;          // edge group 0..3
  int l = t & 63;          // lane in group
  int d0 = l * 4;          // dims [d0, d0+4)
  int h = l >> 3;          // head of these dims
  int s0 = off[n], s1 = off[n + 1];
  float a0 = 0.f, a1 = 0.f, a2 = 0.f, a3 = 0.f, ssum = 0.f;
  for (int k = s0 + g; k < s1; k += 4) {
    int sn = csr_src[k];
    float e = scores[(size_t)k * 8 + h];
    unsigned v4 = *(const unsigned*)(Vb8 + (size_t)sn * 256 + d0);
    a0 += e * fp82f(v4 & 0xffu);
    a1 += e * fp82f((v4 >> 8) & 0xffu);
    a2 += e * fp82f((v4 >> 16) & 0xffu);
    a3 += e * fp82f((v4 >> 24) & 0xffu);
    ssum += e;
  }
  *(float4*)&sacc[g][d0] = make_float4(a0, a1, a2, a3);
  if ((l & 7) == 0) sssum[g][h] = ssum;
  __syncthreads();
  int hh = t >> 5;
  float tot = sacc[0][t] + sacc[1][t] + sacc[2][t] + sacc[3][t];
  float st = sssum[0][hh] + sssum[1][hh] + sssum[2][hh] + sssum[3][hh];
  aggb[(size_t)n * 256 + t] = f2bf(tot / (st + 1e-10f));
}

// ---------------------------------------------------------------------------
// fp32 [K,Nc] -> bf16 transposed [Nc,K]
// ---------------------------------------------------------------------------
__global__ __launch_bounds__(256) void convT_kernel(const float* __restrict__ W,
                                                    u16* __restrict__ Wt, int K, int Nc) {
  __shared__ float tile[32][33];
  int bk = blockIdx.y * 32, bn = blockIdx.x * 32;
  const float* Wz = W + (size_t)blockIdx.z * K * Nc;
  u16* Wtz = Wt + (size_t)blockIdx.z * K * Nc;
  int tx = threadIdx.x & 31, ty = threadIdx.x >> 5;
  for (int r = ty; r < 32; r += 8)
    tile[r][tx] = Wz[(size_t)(bk + r) * Nc + bn + tx];
  __syncthreads();
  for (int r = ty; r < 32; r += 8)
    Wtz[(size_t)(bn + r) * K + bk + tx] = f2bf(tile[tx][r]);
}

// ---------------------------------------------------------------------------
// bf16 MFMA GEMM: C[M,Nc] = A[M,K] @ Bt[Nc,K]^T + bias -> bf16 out.
// BM=128, BN template. GELU=1 adds fast-GELU to the epilogue.
//
// Structure: R0's proven single-buffer / lane-linear staging (both
// conflict-"fix" remaps measured SLOWER: global-issue pattern dominates,
// LDS 8-way conflict is off the critical path in this regime), plus:
//  - BK=64: two 32-k halves per barrier pair -> half the vmcnt(0) drains.
//  - Bijective XCD swizzle (m204): each XCD gets contiguous row-panels so
//    A-panel re-reads across col-blocks hit the XCD-private L2.
// ---------------------------------------------------------------------------
template <int GELU, int BN>
__global__ __launch_bounds__(256) void gemm_mfma(
    const u16* __restrict__ A, const u16* __restrict__ Bt,
    const float* __restrict__ bias, u16* __restrict__ Cb,
    int M, int K, int Nc) {
  constexpr int MJ = BN / 32;
  __shared__ u16 As[128 * 64];       // 2 halves x 8 chunks x 64 lanes x 8 u16
  __shared__ u16 Bs[BN * 64];
  const int t = threadIdx.x;
  const int lane = t & 63;
  const int w = t >> 6;

  // bijective XCD-aware remap (8 XCDs, round-robin dispatch by linear id)
  const int nwg = gridDim.x * gridDim.y;
  const int lin = blockIdx.y * gridDim.x + blockIdx.x;
  const int qq = nwg >> 3, rr = nwg & 7;
  const int xcd = lin & 7, pos = lin >> 3;
  const int nl = (xcd < rr ? xcd * (qq + 1) : rr * (qq + 1) + (xcd - rr) * qq) + pos;
  const int row0 = (nl / gridDim.x) * 128;
  const int col0 = (nl % gridDim.x) * BN;

  const int wm = (w >> 1) * 64, wn = (w & 1) * (BN / 2);

  f32x4 acc[4][MJ] = {};
  const int sr = lane >> 2;        // stage row within 16-row chunk
  const int sk = (lane & 3) * 8;   // stage k-slot (lane-linear: coalesced)

  for (int k0 = 0; k0 < K; k0 += 64) {
#pragma unroll
    for (int half = 0; half < 2; ++half) {
#pragma unroll
      for (int c = 0; c < 2; ++c) {
        const int chunk = w * 2 + c;
        const int r = chunk * 16 + sr;
        int ra = row0 + r; if (ra >= M) ra = M - 1;
        GLDS16(A + (size_t)ra * K + k0 + half * 32 + sk,
               &As[((half * 8 + chunk) * 64 + lane) * 8]);
        if (BN == 128) {
          GLDS16(Bt + (size_t)(col0 + r) * K + k0 + half * 32 + sk,
                 &Bs[((half * 8 + chunk) * 64 + lane) * 8]);
        }
      }
      if (BN == 64) {
        const int r = w * 16 + sr;
        GLDS16(Bt + (size_t)(col0 + r) * K + k0 + half * 32 + sk,
               &Bs[((half * 4 + w) * 64 + lane) * 8]);
      }
    }
    __syncthreads();
    const int ko = (lane >> 4) * 8;
    const int lr = lane & 15;
#pragma unroll
    for (int half = 0; half < 2; ++half) {
      bf16x8 af[4], bfr[MJ];
      const int ab = half * 8 * 512;                       // A half offset (u16)
      const int bb = half * (BN == 128 ? 8 : 4) * 512;     // B half offset (u16)
#pragma unroll
      for (int i = 0; i < 4; ++i)
        af[i] = *(const bf16x8*)&As[ab + ((wm >> 4) + i) * 512 + lr * 32 + ko];
#pragma unroll
      for (int j = 0; j < MJ; ++j)
        bfr[j] = *(const bf16x8*)&Bs[bb + ((wn >> 4) + j) * 512 + lr * 32 + ko];
#pragma unroll
      for (int i = 0; i < 4; ++i)
#pragma unroll
        for (int j = 0; j < MJ; ++j)
          acc[i][j] = __builtin_amdgcn_mfma_f32_16x16x32_bf16(af[i], bfr[j], acc[i][j], 0, 0, 0);
    }
    __syncthreads();
  }

  const int lc = lane & 15;
  const int lrow = (lane >> 4) * 4;
  float bv[MJ];
#pragma unroll
  for (int j = 0; j < MJ; ++j) bv[j] = bias[col0 + wn + j * 16 + lc];
#pragma unroll
  for (int i = 0; i < 4; ++i) {
#pragma unroll
    for (int r = 0; r < 4; ++r) {
      int gr = row0 + wm + i * 16 + lrow + r;
      if (gr >= M) continue;
#pragma unroll
      for (int j = 0; j < MJ; ++j) {
        int gc = col0 + wn + j * 16 + lc;
        float v = acc[i][j][r] + bv[j];
        if (GELU) v = gelu_f(v);
        Cb[(size_t)gr * Nc + gc] = f2bf(v);
      }
    }
  }
}

// ---------------------------------------------------------------------------
// LayerNorm rows of 256: out = LN(xin + res) * g + b; res is bf16 (or null).
// Wave-per-row: lane holds float4 (64 lanes x 4 = 256), pure shfl_xor
// reductions — no LDS, no barriers. 4 rows/block, vectorized loads/stores.
// ---------------------------------------------------------------------------
__global__ __launch_bounds__(256) void ln_kernel(
    const float* __restrict__ xin, const u16* __restrict__ res,
    const float* __restrict__ g, const float* __restrict__ b,
    float* __restrict__ out, u16* __restrict__ outb, int N) {
  int row = blockIdx.x * 4 + (threadIdx.x >> 6);
  if (row >= N) return;
  int l = threadIdx.x & 63;
  size_t base = (size_t)row * 256 + l * 4;
  float4 r4 = *(const float4*)&xin[base];
  if (res) {
    ushort4 rb = *(const ushort4*)&res[base];
    r4.x += bf2f(rb.x); r4.y += bf2f(rb.y);
    r4.z += bf2f(rb.z); r4.w += bf2f(rb.w);
  }
  float s = r4.x + r4.y + r4.z + r4.w;
  for (int o = 32; o > 0; o >>= 1) s += __shfl_xor(s, o, 64);
  float m = s * (1.f / 256.f);
  float dx = r4.x - m, dy = r4.y - m, dz = r4.z - m, dw = r4.w - m;
  float s2 = dx * dx + dy * dy + dz * dz + dw * dw;
  for (int o = 32; o > 0; o >>= 1) s2 += __shfl_xor(s2, o, 64);
  float inv = rsqrtf(s2 * (1.f / 256.f) + 1e-5f);
  float4 g4 = *(const float4*)&g[l * 4];
  float4 b4 = *(const float4*)&b[l * 4];
  float4 o4 = { dx * inv * g4.x + b4.x, dy * inv * g4.y + b4.y,
                dz * inv * g4.z + b4.z, dw * inv * g4.w + b4.w };
  *(float4*)&out[base] = o4;
  if (outb) {
    ushort4 ob = { f2bf(o4.x), f2bf(o4.y), f2bf(o4.z), f2bf(o4.w) };
    *(ushort4*)&outb[base] = ob;
  }
}

// ---------------------------------------------------------------------------
extern "C" void kernel_launch(void* const* d_in, const int* in_sizes, int n_in,
                              void* d_out, int out_size, void* d_ws, size_t ws_size,
                              hipStream_t stream) {
  const float* x_in   = (const float*)d_in[0];
  const int*   ei     = (const int*)d_in[1];
  const int*   etype  = (const int*)d_in[2];
  const int*   ntype  = (const int*)d_in[3];
  const float* W_Q    = (const float*)d_in[4];
  const float* W_K    = (const float*)d_in[5];
  const float* W_V    = (const float*)d_in[6];
  const float* W_E    = (const float*)d_in[7];
  const float* mu     = (const float*)d_in[8];
  const float* Wo     = (const float*)d_in[9];
  const float* bo     = (const float*)d_in[10];
  const float* ln1g   = (const float*)d_in[11];
  const float* ln1b   = (const float*)d_in[12];
  const float* ln2g   = (const float*)d_in[13];
  const float* ln2b   = (const float*)d_in[14];
  const float* w1     = (const float*)d_in[15];
  const float* b1     = (const float*)d_in[16];
  const float* w2     = (const float*)d_in[17];
  const float* b2     = (const float*)d_in[18];
  const float* outg   = (const float*)d_in[19];
  const float* outb   = (const float*)d_in[20];

  const int N = in_sizes[0] / DMODEL;    // 20000
  const int E = in_sizes[1] / 2;         // 320000
  const int* src = ei;
  const int* dst = ei + E;

  const size_t NF = (size_t)N * DMODEL;
  const size_t EH = (size_t)E * NHEAD;

  // ---- workspace layout ----
  float* f      = (float*)d_ws;
  float* xbuf   = f;                     // NF fp32 (residual master)
  float* scores = f + NF;                // EH fp32 (holds exp(score))
  u16*   fout   = (u16*)(f + NF + EH);   // NF bf16 (GEMM outputs)
  u16*   xb     = fout + NF;             // NF bf16
  u16*   Qeb    = xb + NF;               // 3NF bf16  } h1b aliases Qeb
  u16*   h1b    = Qeb;                   // alias (2NF used, FFN phase only)
  u16*   aggb   = Qeb + 3 * NF;          // NF bf16
  u8*    Kb8    = (u8*)(aggb + NF);      // NF bytes fp8
  u8*    Vb8    = Kb8 + NF;              // NF bytes fp8
  u16*   wqkvb  = (u16*)(Vb8 + NF);      // 96 * 5120
  u16*   Wot    = wqkvb + (size_t)NLAYER * NTYPE * NHEAD * 5120;
  u16*   w1t    = Wot + 3 * 65536;
  u16*   w2t    = w1t + 3 * 262144;
  int*   ip     = (int*)(w2t + 3 * 262144);
  int*   off    = ip;                    // N+1
  int*   csr_src= off + (N + 1);         // E
  int*   csr_dst= csr_src + E;           // E
  int*   csr_et = csr_dst + E;           // E
  int*   cursor = csr_et + E;            // N
  int*   tidx   = cursor + N;            // N
  int*   toff   = tidx + N;              // NTYPE+1
  int*   tile_off = toff + (NTYPE + 1);  // NTYPE+1
  int*   tcnt   = tile_off + (NTYPE + 1);// NTYPE
  int*   tcur   = tcnt + NTYPE;          // NTYPE

  // ---- CSR + type buckets (once) ----
  hipMemsetAsync(cursor, 0, (size_t)N * sizeof(int), stream);
  hipMemsetAsync(tcnt, 0, 2 * NTYPE * sizeof(int), stream);
  count_deg_kernel<<<(E + 255) / 256, 256, 0, stream>>>(dst, cursor, E);
  scan_kernel<<<1, 1024, 0, stream>>>(cursor, off, N);
  hipMemsetAsync(cursor, 0, (size_t)N * sizeof(int), stream);
  scatter_kernel<<<(E + 255) / 256, 256, 0, stream>>>(
      src, dst, etype, off, cursor, csr_src, csr_dst, csr_et, E);
  tcount_kernel<<<(N + 255) / 256, 256, 0, stream>>>(ntype, tcnt, N);
  tscan_kernel<<<1, 64, 0, stream>>>(tcnt, toff, tile_off);
  tscatter_kernel<<<(N + 255) / 256, 256, 0, stream>>>(ntype, toff, tcur, tidx, N);

  // ---- weight prep (once) ----
  wprep_kernel<<<NLAYER * NTYPE * NHEAD, 256, 0, stream>>>(W_Q, W_K, W_V, W_E, wqkvb);
  convT_kernel<<<dim3(DMODEL / 32, DMODEL / 32, NLAYER), 256, 0, stream>>>(
      Wo, Wot, DMODEL, DMODEL);
  convT_kernel<<<dim3(4 * DMODEL / 32, DMODEL / 32, NLAYER), 256, 0, stream>>>(
      w1, w1t, DMODEL, 4 * DMODEL);
  convT_kernel<<<dim3(DMODEL / 32, 4 * DMODEL / 32, NLAYER), 256, 0, stream>>>(
      w2, w2t, 4 * DMODEL, DMODEL);

  // ---- x working copies ----
  hipMemcpyAsync(xbuf, x_in, NF * sizeof(float), hipMemcpyDeviceToDevice, stream);
  xconv_kernel<<<(int)((NF / 4 + 255) / 256), 256, 0, stream>>>(x_in, xb, (int)(NF / 4));

  const int gm = (N + 127) / 128;
  const int lng = (N + 3) / 4;
  const int qtiles = (N + 63) / 64 + NTYPE;
  for (int l = 0; l < NLAYER; ++l) {
    qkv_mfma<<<dim3(qtiles, NHEAD), 256, 0, stream>>>(
        xb, tidx, toff, tile_off,
        wqkvb + (size_t)l * NTYPE * NHEAD * 5120, Kb8, Vb8, Qeb);
    score_kernel<<<(int)((EH + 255) / 256), 256, 0, stream>>>(
        csr_src, csr_dst, csr_et, Qeb, Kb8, mu + (size_t)l * NHEAD * ETYPE, scores, E);
    agg_kernel<<<N, 256, 0, stream>>>(off, csr_src, scores, Vb8, aggb);

    gemm_mfma<0, 64><<<dim3(DMODEL / 64, gm), 256, 0, stream>>>(
        aggb, Wot + (size_t)l * 65536, bo + (size_t)l * DMODEL,
        fout, N, DMODEL, DMODEL);
    ln_kernel<<<lng, 256, 0, stream>>>(xbuf, fout,
        ln1g + (size_t)l * DMODEL, ln1b + (size_t)l * DMODEL, xbuf, xb, N);
    gemm_mfma<1, 128><<<dim3(4 * DMODEL / 128, gm), 256, 0, stream>>>(
        xb, w1t + (size_t)l * 262144, b1 + (size_t)l * 4 * DMODEL,
        h1b, N, DMODEL, 4 * DMODEL);
    gemm_mfma<0, 64><<<dim3(DMODEL / 64, gm), 256, 0, stream>>>(
        h1b, w2t + (size_t)l * 262144, b2 + (size_t)l * DMODEL,
        fout, N, 4 * DMODEL, DMODEL);
    ln_kernel<<<lng, 256, 0, stream>>>(xbuf, fout,
        ln2g + (size_t)l * DMODEL, ln2b + (size_t)l * DMODEL, xbuf, xb, N);
  }

  ln_kernel<<<lng, 256, 0, stream>>>(xbuf, nullptr, outg, outb, (float*)d_out, nullptr, N);
}

// Round 5
// 729.601 us; speedup vs baseline: 1.2213x; 1.0362x over previous
//
#include <hip/hip_runtime.h>
#include <hip/hip_fp8.h>
#include <math.h>

#define HDIM 32
#define NHEAD 8
#define DMODEL 256
#define NTYPE 4
#define ETYPE 3
#define NLAYER 3

typedef unsigned short u16;
typedef unsigned char u8;
typedef __bf16 bf16x8 __attribute__((ext_vector_type(8)));
typedef float f32x4 __attribute__((ext_vector_type(4)));

__device__ __forceinline__ u16 f2bf(float f) {
  union { float f; unsigned u; } v; v.f = f;
  unsigned r = v.u + 0x7FFF + ((v.u >> 16) & 1);
  return (u16)(r >> 16);
}
__device__ __forceinline__ float bf2f(u16 b) {
  union { unsigned u; float f; } v; v.u = (unsigned)b << 16; return v.f;
}
__device__ __forceinline__ u8 f2fp8(float v) {
  __hip_fp8_e4m3 t(v); return (u8)t.__x;
}
__device__ __forceinline__ float fp82f(unsigned b) {
  __hip_fp8_e4m3 t; t.__x = (__hip_fp8_storage_t)b; return (float)t;
}

// fast GELU (tanh form)
__device__ __forceinline__ float gelu_f(float v) {
  float u = 0.7978845608028654f * v * (1.f + 0.044715f * v * v);
  float e = __expf(-2.f * fabsf(u));
  float th = (1.f - e) / (1.f + e);
  th = copysignf(th, u);
  return 0.5f * v * (1.f + th);
}

#define GLDS16(g, l)                                              \
  __builtin_amdgcn_global_load_lds(                               \
      (const __attribute__((address_space(1))) void*)(g),         \
      (__attribute__((address_space(3))) void*)(l), 16, 0, 0)

// ---------------------------------------------------------------------------
// CSR build (dst-sorted edge VALUES in position order)
// ---------------------------------------------------------------------------
__global__ void count_deg_kernel(const int* __restrict__ dst, int* __restrict__ deg, int E) {
  int tid = blockIdx.x * 256 + threadIdx.x;
  if (tid < E) atomicAdd(&deg[dst[tid]], 1);
}

__global__ __launch_bounds__(1024) void scan_kernel(const int* __restrict__ deg,
                                                    int* __restrict__ off, int n) {
  __shared__ int part[1024];
  int t = threadIdx.x;
  int chunk = (n + 1023) >> 10;
  int base = t * chunk;
  int s = 0;
  for (int i = 0; i < chunk; ++i) {
    int idx = base + i;
    if (idx < n) s += deg[idx];
  }
  part[t] = s;
  __syncthreads();
  for (int o = 1; o < 1024; o <<= 1) {
    int v = (t >= o) ? part[t - o] : 0;
    __syncthreads();
    part[t] += v;
    __syncthreads();
  }
  int run = part[t] - s;
  for (int i = 0; i < chunk; ++i) {
    int idx = base + i;
    if (idx < n) { off[idx] = run; run += deg[idx]; }
  }
  if (t == 1023) off[n] = part[1023];
}

__global__ void scatter_kernel(const int* __restrict__ src, const int* __restrict__ dst,
                               const int* __restrict__ etype,
                               const int* __restrict__ off, int* __restrict__ cursor,
                               int* __restrict__ csr_src, int* __restrict__ csr_dst,
                               int* __restrict__ csr_et, int E) {
  int tid = blockIdx.x * 256 + threadIdx.x;
  if (tid < E) {
    int d = dst[tid];
    int p = atomicAdd(&cursor[d], 1);
    int pos = off[d] + p;
    csr_src[pos] = src[tid];
    csr_dst[pos] = d;
    csr_et[pos] = etype[tid];
  }
}

// ---------------------------------------------------------------------------
// Node-type buckets — hierarchical to avoid same-address atomic contention
// ---------------------------------------------------------------------------
__global__ void tcount_kernel(const int* __restrict__ nt, int* __restrict__ tcnt, int N) {
  __shared__ int h[NTYPE];
  int t = threadIdx.x;
  if (t < NTYPE) h[t] = 0;
  __syncthreads();
  int tid = blockIdx.x * 256 + t;
  if (tid < N) atomicAdd(&h[nt[tid]], 1);
  __syncthreads();
  if (t < NTYPE && h[t] > 0) atomicAdd(&tcnt[t], h[t]);
}

__global__ void tscan_kernel(const int* __restrict__ tcnt, int* __restrict__ toff,
                             int* __restrict__ tile_off) {
  if (threadIdx.x == 0 && blockIdx.x == 0) {
    int o = 0, to = 0;
    for (int t = 0; t < NTYPE; ++t) {
      toff[t] = o; tile_off[t] = to;
      o += tcnt[t]; to += (tcnt[t] + 63) >> 6;
    }
    toff[NTYPE] = o; tile_off[NTYPE] = to;
  }
}

__global__ void tscatter_kernel(const int* __restrict__ nt, const int* __restrict__ toff,
                                int* __restrict__ tcur, int* __restrict__ tidx, int N) {
  int tid = blockIdx.x * 256 + threadIdx.x;
  int lane = threadIdx.x & 63;
  int ty = (tid < N) ? nt[tid] : -1;
  unsigned long long lt_mask = (lane == 63) ? 0x7FFFFFFFFFFFFFFFull
                                            : ((1ull << lane) - 1);
#pragma unroll
  for (int t4 = 0; t4 < NTYPE; ++t4) {
    unsigned long long mask = __ballot(ty == t4);
    if (mask == 0) continue;
    int first = __builtin_ctzll(mask);
    int cnt = __popcll(mask);
    int base = 0;
    if (lane == first) base = atomicAdd(&tcur[t4], cnt);
    base = __shfl(base, first, 64);
    if (ty == t4) {
      int rank = __popcll(mask & lt_mask);
      tidx[toff[t4] + base + rank] = tid;
    }
  }
}

// ---------------------------------------------------------------------------
// x fp32 -> bf16 mirror
// ---------------------------------------------------------------------------
__global__ void xconv_kernel(const float* __restrict__ x, u16* __restrict__ xb, int n4) {
  int i = blockIdx.x * 256 + threadIdx.x;
  if (i < n4) {
    float4 v = ((const float4*)x)[i];
    ushort4 o = { f2bf(v.x), f2bf(v.y), f2bf(v.z), f2bf(v.w) };
    ((ushort4*)xb)[i] = o;
  }
}

// ---------------------------------------------------------------------------
// Weight prep, per (l,type,head): bf16 B-operand mats ([col][k], k contig):
//   mat0 = WK^T, mat1 = WV^T,
//   mat2..4 = WQE[et] with Qe = x @ (WQ @ WE[et]^T)
// wq stored PADDED [32][33]: read wq[k*33+j] -> bank (k+j)&31, conflict-free
// (was wq[k*32+j]: all k in bank j&31 = 32-way conflict, 6.8M counted, 40.7µs
// for a 96-block once-only kernel).
// ---------------------------------------------------------------------------
__global__ __launch_bounds__(256) void wprep_kernel(
    const float* __restrict__ W_Q, const float* __restrict__ W_K,
    const float* __restrict__ W_V, const float* __restrict__ W_E,
    u16* __restrict__ wqkvb) {
  int b = blockIdx.x;
  int h = b & 7, tt = (b >> 3) & 3, l = b >> 5;
  __shared__ float wq[1056];         // 32 x 33 padded
  __shared__ float we[3][1024];
  int t = threadIdx.x;
  const float* WQp = W_Q + (((size_t)l * NTYPE + tt) * NHEAD + h) * 1024;
  for (int i = t; i < 1024; i += 256) wq[(i >> 5) * 33 + (i & 31)] = WQp[i];
  for (int et = 0; et < ETYPE; ++et) {
    const float* WEp = W_E + (((size_t)l * ETYPE + et) * NHEAD + h) * 1024;
    for (int i = t; i < 1024; i += 256) we[et][i] = WEp[i];
  }
  __syncthreads();
  const float* WKp = W_K + (((size_t)l * NTYPE + tt) * NHEAD + h) * 1024;
  const float* WVp = W_V + (((size_t)l * NTYPE + tt) * NHEAD + h) * 1024;
  u16* out = wqkvb + (size_t)b * 5120;
  for (int i = t; i < 1024; i += 256) {
    int col = i >> 5, k = i & 31;
    out[i] = f2bf(WKp[k * 32 + col]);
    out[1024 + i] = f2bf(WVp[k * 32 + col]);
#pragma unroll
    for (int et = 0; et < ETYPE; ++et) {
      float a = 0.f;
#pragma unroll
      for (int j = 0; j < 32; ++j) a += wq[k * 33 + j] * we[et][col * 32 + j];
      out[(2 + et) * 1024 + i] = f2bf(a);
    }
  }
}

// ---------------------------------------------------------------------------
// QKV via MFMA over type buckets: K,V stored fp8 e4m3, Qe[3] bf16.
// LDS layout for MFMA operands is [k-slot][row] per 16-row chunk so the
// b128 fragment reads are bank-conflict-free (reg-staged ds_write, so the
// scatter layout is free here).
// ---------------------------------------------------------------------------
__global__ __launch_bounds__(256) void qkv_mfma(
    const u16* __restrict__ xb, const int* __restrict__ tidx,
    const int* __restrict__ toff, const int* __restrict__ tile_off,
    const u16* __restrict__ wqkvb_l,
    u8* __restrict__ Kb8, u8* __restrict__ Vb8, u16* __restrict__ Qeb) {
  __shared__ u16 smem[10240];
  int bx = blockIdx.x, h = blockIdx.y;
  if (bx >= tile_off[NTYPE]) return;
  int ty = 0;
  while (bx >= tile_off[ty + 1]) ++ty;
  int lt = bx - tile_off[ty];
  int base = toff[ty] + lt * 64;
  int cnt = min(64, toff[ty + 1] - toff[ty] - lt * 64);
  int t = threadIdx.x;
  {
    // x tile 64 rows x 32 k, stored as [rgroup(4)][slot(4)][row16(16)] 16B units
    int row = ((t >> 6) << 4) | (t & 15);
    int q = (t >> 4) & 3;
    int node = tidx[base + min(row, cnt - 1)];
    *(uint4*)&smem[t * 8] =
        *(const uint4*)&xb[(size_t)node * 256 + h * 32 + q * 8];
  }
  // weights: 5 mats of 32 cols x 32 k; store as [mt][slot(4)][col(32)] 16B units
  const u16* wsrc = wqkvb_l + ((size_t)ty * NHEAD + h) * 5120;
  for (int dc = t; dc < 640; dc += 256) {
    int mt = dc >> 7, wi = dc & 127, slot = wi >> 5, colx = wi & 31;
    *(uint4*)&smem[2048 + dc * 8] = *(const uint4*)&wsrc[(mt * 128 + colx * 4 + slot) * 8];
  }
  __syncthreads();

  int lane = t & 63, w = t >> 6;
  int m = lane & 15, q = lane >> 4;
  bf16x8 af = *(const bf16x8*)&smem[w * 512 + q * 128 + m * 8];
  f32x4 acc[5][2];
#pragma unroll
  for (int mt = 0; mt < 5; ++mt)
#pragma unroll
    for (int c = 0; c < 2; ++c) {
      bf16x8 bf = *(const bf16x8*)&smem[2048 + mt * 1024 + q * 256 + (c * 16 + m) * 8];
      acc[mt][c] = __builtin_amdgcn_mfma_f32_16x16x32_bf16(af, bf, (f32x4){0.f, 0.f, 0.f, 0.f}, 0, 0, 0);
    }
  __syncthreads();
#pragma unroll
  for (int mt = 0; mt < 5; ++mt)
#pragma unroll
    for (int c = 0; c < 2; ++c)
#pragma unroll
      for (int r = 0; r < 4; ++r)
        smem[mt * 2048 + (w * 16 + q * 4 + r) * 32 + c * 16 + m] = f2bf(acc[mt][c][r]);
  __syncthreads();
  {
    int row = t >> 2, q4 = t & 3;
    if (row < cnt) {
      int node = tidx[base + row];
      {
        const u16* sp = &smem[row * 32 + q4 * 8];
        unsigned long long pk = 0;
#pragma unroll
        for (int j = 0; j < 8; ++j)
          pk |= (unsigned long long)f2fp8(bf2f(sp[j])) << (8 * j);
        *(unsigned long long*)&Kb8[(size_t)node * 256 + h * 32 + q4 * 8] = pk;
      }
      {
        const u16* sp = &smem[2048 + row * 32 + q4 * 8];
        unsigned long long pk = 0;
#pragma unroll
        for (int j = 0; j < 8; ++j)
          pk |= (unsigned long long)f2fp8(bf2f(sp[j])) << (8 * j);
        *(unsigned long long*)&Vb8[(size_t)node * 256 + h * 32 + q4 * 8] = pk;
      }
#pragma unroll
      for (int et = 0; et < ETYPE; ++et)
        *(uint4*)&Qeb[((size_t)node * ETYPE + et) * 256 + h * 32 + q4 * 8] =
            *(const uint4*)&smem[(2 + et) * 2048 + row * 32 + q4 * 8];
    }
  }
}

// ---------------------------------------------------------------------------
// Edge scores -> exp(score). fp8 K gather (5 MB working set)
// ---------------------------------------------------------------------------
__global__ __launch_bounds__(256) void score_kernel(
    const int* __restrict__ csr_src, const int* __restrict__ csr_dst,
    const int* __restrict__ csr_et, const u16* __restrict__ Qeb,
    const u8* __restrict__ Kb8, const float* __restrict__ mu,
    float* __restrict__ scores, int E) {
  int tid = blockIdx.x * 256 + threadIdx.x;
  if (tid >= E * NHEAD) return;
  int p = tid >> 3, h = tid & 7;
  int s = csr_src[p], d = csr_dst[p], t = csr_et[p];
  const bf16x8* q = (const bf16x8*)(Qeb + ((size_t)d * ETYPE + t) * 256 + h * 32);
  const uint2* k = (const uint2*)(Kb8 + (size_t)s * 256 + h * 32);
  float acc = 0.f;
#pragma unroll
  for (int g = 0; g < 4; ++g) {
    uint2 kd = k[g];
    bf16x8 qq = q[g];
#pragma unroll
    for (int b = 0; b < 4; ++b) {
      acc += fp82f((kd.x >> (8 * b)) & 0xffu) * (float)qq[b];
      acc += fp82f((kd.y >> (8 * b)) & 0xffu) * (float)qq[4 + b];
    }
  }
  scores[tid] = __expf(acc * 0.17677669529663687f * mu[h * ETYPE + t]);
}

// ---------------------------------------------------------------------------
// Segment softmax + V aggregation with 4-WAY EDGE PARALLELISM: 4 groups of
// 64 threads each walk every 4th edge (4 independent gather chains in flight).
// Thread covers 4 dims via one uint (4xfp8) load; cross-group reduce
// through LDS once at the end.
// ---------------------------------------------------------------------------
__global__ __launch_bounds__(256) void agg_kernel(
    const int* __restrict__ off, const int* __restrict__ csr_src,
    const float* __restrict__ scores, const u8* __restrict__ Vb8,
    u16* __restrict__ aggb) {
  __shared__ float sacc[4][256];
  __shared__ float sssum[4][8];
  int n = blockIdx.x;
  int t = threadIdx.x;
  int g = t >> 6;          // edge group 0..3
  int l = t & 63;          // lane in group
  int d0 = l * 4;          // dims [d0, d0+4)
  int h = l >> 3;          // head of these dims
  int s0 = off[n], s1 = off[n + 1];
  float a0 = 0.f, a1 = 0.f, a2 = 0.f, a3 = 0.f, ssum = 0.f;
  for (int k = s0 + g; k < s1; k += 4) {
    int sn = csr_src[k];
    float e = scores[(size_t)k * 8 + h];
    unsigned v4 = *(const unsigned*)(Vb8 + (size_t)sn * 256 + d0);
    a0 += e * fp82f(v4 & 0xffu);
    a1 += e * fp82f((v4 >> 8) & 0xffu);
    a2 += e * fp82f((v4 >> 16) & 0xffu);
    a3 += e * fp82f((v4 >> 24) & 0xffu);
    ssum += e;
  }
  *(float4*)&sacc[g][d0] = make_float4(a0, a1, a2, a3);
  if ((l & 7) == 0) sssum[g][h] = ssum;
  __syncthreads();
  int hh = t >> 5;
  float tot = sacc[0][t] + sacc[1][t] + sacc[2][t] + sacc[3][t];
  float st = sssum[0][hh] + sssum[1][hh] + sssum[2][hh] + sssum[3][hh];
  aggb[(size_t)n * 256 + t] = f2bf(tot / (st + 1e-10f));
}

// ---------------------------------------------------------------------------
// fp32 [K,Nc] -> bf16 transposed [Nc,K]
// ---------------------------------------------------------------------------
__global__ __launch_bounds__(256) void convT_kernel(const float* __restrict__ W,
                                                    u16* __restrict__ Wt, int K, int Nc) {
  __shared__ float tile[32][33];
  int bk = blockIdx.y * 32, bn = blockIdx.x * 32;
  const float* Wz = W + (size_t)blockIdx.z * K * Nc;
  u16* Wtz = Wt + (size_t)blockIdx.z * K * Nc;
  int tx = threadIdx.x & 31, ty = threadIdx.x >> 5;
  for (int r = ty; r < 32; r += 8)
    tile[r][tx] = Wz[(size_t)(bk + r) * Nc + bn + tx];
  __syncthreads();
  for (int r = ty; r < 32; r += 8)
    Wtz[(size_t)(bn + r) * K + bk + tx] = f2bf(tile[tx][r]);
}

// ---------------------------------------------------------------------------
// bf16 MFMA GEMM: C[M,Nc] = A[M,K] @ Bt[Nc,K]^T + bias -> bf16 out.
// BM=128, BN=128 for ALL gemms now (A-refetch scales with gridX; halving
// gridX for Nc=256 halves A traffic and doubles MFMA per wave).
// GELU=1 adds fast-GELU to the epilogue.
//
// Structure: R0's proven single-buffer / lane-linear staging (both
// conflict-"fix" remaps measured SLOWER: global-issue pattern dominates,
// LDS 8-way conflict is off the critical path in this regime), plus:
//  - BK=64: two 32-k halves per barrier pair -> half the vmcnt(0) drains.
//  - Bijective XCD swizzle (m204): each XCD gets contiguous row-panels so
//    A/B-panel re-reads across blocks hit the XCD-private L2.
// ---------------------------------------------------------------------------
template <int GELU, int BN>
__global__ __launch_bounds__(256) void gemm_mfma(
    const u16* __restrict__ A, const u16* __restrict__ Bt,
    const float* __restrict__ bias, u16* __restrict__ Cb,
    int M, int K, int Nc) {
  constexpr int MJ = BN / 32;
  __shared__ u16 As[128 * 64];       // 2 halves x 8 chunks x 64 lanes x 8 u16
  __shared__ u16 Bs[BN * 64];
  const int t = threadIdx.x;
  const int lane = t & 63;
  const int w = t >> 6;

  // bijective XCD-aware remap (8 XCDs, round-robin dispatch by linear id)
  const int nwg = gridDim.x * gridDim.y;
  const int lin = blockIdx.y * gridDim.x + blockIdx.x;
  const int qq = nwg >> 3, rr = nwg & 7;
  const int xcd = lin & 7, pos = lin >> 3;
  const int nl = (xcd < rr ? xcd * (qq + 1) : rr * (qq + 1) + (xcd - rr) * qq) + pos;
  const int row0 = (nl / gridDim.x) * 128;
  const int col0 = (nl % gridDim.x) * BN;

  const int wm = (w >> 1) * 64, wn = (w & 1) * (BN / 2);

  f32x4 acc[4][MJ] = {};
  const int sr = lane >> 2;        // stage row within 16-row chunk
  const int sk = (lane & 3) * 8;   // stage k-slot (lane-linear: coalesced)

  for (int k0 = 0; k0 < K; k0 += 64) {
#pragma unroll
    for (int half = 0; half < 2; ++half) {
#pragma unroll
      for (int c = 0; c < 2; ++c) {
        const int chunk = w * 2 + c;
        const int r = chunk * 16 + sr;
        int ra = row0 + r; if (ra >= M) ra = M - 1;
        GLDS16(A + (size_t)ra * K + k0 + half * 32 + sk,
               &As[((half * 8 + chunk) * 64 + lane) * 8]);
        if (BN == 128) {
          GLDS16(Bt + (size_t)(col0 + r) * K + k0 + half * 32 + sk,
                 &Bs[((half * 8 + chunk) * 64 + lane) * 8]);
        }
      }
      if (BN == 64) {
        const int r = w * 16 + sr;
        GLDS16(Bt + (size_t)(col0 + r) * K + k0 + half * 32 + sk,
               &Bs[((half * 4 + w) * 64 + lane) * 8]);
      }
    }
    __syncthreads();
    const int ko = (lane >> 4) * 8;
    const int lr = lane & 15;
#pragma unroll
    for (int half = 0; half < 2; ++half) {
      bf16x8 af[4], bfr[MJ];
      const int ab = half * 8 * 512;                       // A half offset (u16)
      const int bb = half * (BN == 128 ? 8 : 4) * 512;     // B half offset (u16)
#pragma unroll
      for (int i = 0; i < 4; ++i)
        af[i] = *(const bf16x8*)&As[ab + ((wm >> 4) + i) * 512 + lr * 32 + ko];
#pragma unroll
      for (int j = 0; j < MJ; ++j)
        bfr[j] = *(const bf16x8*)&Bs[bb + ((wn >> 4) + j) * 512 + lr * 32 + ko];
#pragma unroll
      for (int i = 0; i < 4; ++i)
#pragma unroll
        for (int j = 0; j < MJ; ++j)
          acc[i][j] = __builtin_amdgcn_mfma_f32_16x16x32_bf16(af[i], bfr[j], acc[i][j], 0, 0, 0);
    }
    __syncthreads();
  }

  const int lc = lane & 15;
  const int lrow = (lane >> 4) * 4;
  float bv[MJ];
#pragma unroll
  for (int j = 0; j < MJ; ++j) bv[j] = bias[col0 + wn + j * 16 + lc];
#pragma unroll
  for (int i = 0; i < 4; ++i) {
#pragma unroll
    for (int r = 0; r < 4; ++r) {
      int gr = row0 + wm + i * 16 + lrow + r;
      if (gr >= M) continue;
#pragma unroll
      for (int j = 0; j < MJ; ++j) {
        int gc = col0 + wn + j * 16 + lc;
        float v = acc[i][j][r] + bv[j];
        if (GELU) v = gelu_f(v);
        Cb[(size_t)gr * Nc + gc] = f2bf(v);
      }
    }
  }
}

// ---------------------------------------------------------------------------
// LayerNorm rows of 256: out = LN(xin + res) * g + b; res is bf16 (or null).
// Wave-per-row: lane holds float4 (64 lanes x 4 = 256), pure shfl_xor
// reductions — no LDS, no barriers. 4 rows/block, vectorized loads/stores.
// ---------------------------------------------------------------------------
__global__ __launch_bounds__(256) void ln_kernel(
    const float* __restrict__ xin, const u16* __restrict__ res,
    const float* __restrict__ g, const float* __restrict__ b,
    float* __restrict__ out, u16* __restrict__ outb, int N) {
  int row = blockIdx.x * 4 + (threadIdx.x >> 6);
  if (row >= N) return;
  int l = threadIdx.x & 63;
  size_t base = (size_t)row * 256 + l * 4;
  float4 r4 = *(const float4*)&xin[base];
  if (res) {
    ushort4 rb = *(const ushort4*)&res[base];
    r4.x += bf2f(rb.x); r4.y += bf2f(rb.y);
    r4.z += bf2f(rb.z); r4.w += bf2f(rb.w);
  }
  float s = r4.x + r4.y + r4.z + r4.w;
  for (int o = 32; o > 0; o >>= 1) s += __shfl_xor(s, o, 64);
  float m = s * (1.f / 256.f);
  float dx = r4.x - m, dy = r4.y - m, dz = r4.z - m, dw = r4.w - m;
  float s2 = dx * dx + dy * dy + dz * dz + dw * dw;
  for (int o = 32; o > 0; o >>= 1) s2 += __shfl_xor(s2, o, 64);
  float inv = rsqrtf(s2 * (1.f / 256.f) + 1e-5f);
  float4 g4 = *(const float4*)&g[l * 4];
  float4 b4 = *(const float4*)&b[l * 4];
  float4 o4 = { dx * inv * g4.x + b4.x, dy * inv * g4.y + b4.y,
                dz * inv * g4.z + b4.z, dw * inv * g4.w + b4.w };
  *(float4*)&out[base] = o4;
  if (outb) {
    ushort4 ob = { f2bf(o4.x), f2bf(o4.y), f2bf(o4.z), f2bf(o4.w) };
    *(ushort4*)&outb[base] = ob;
  }
}

// ---------------------------------------------------------------------------
extern "C" void kernel_launch(void* const* d_in, const int* in_sizes, int n_in,
                              void* d_out, int out_size, void* d_ws, size_t ws_size,
                              hipStream_t stream) {
  const float* x_in   = (const float*)d_in[0];
  const int*   ei     = (const int*)d_in[1];
  const int*   etype  = (const int*)d_in[2];
  const int*   ntype  = (const int*)d_in[3];
  const float* W_Q    = (const float*)d_in[4];
  const float* W_K    = (const float*)d_in[5];
  const float* W_V    = (const float*)d_in[6];
  const float* W_E    = (const float*)d_in[7];
  const float* mu     = (const float*)d_in[8];
  const float* Wo     = (const float*)d_in[9];
  const float* bo     = (const float*)d_in[10];
  const float* ln1g   = (const float*)d_in[11];
  const float* ln1b   = (const float*)d_in[12];
  const float* ln2g   = (const float*)d_in[13];
  const float* ln2b   = (const float*)d_in[14];
  const float* w1     = (const float*)d_in[15];
  const float* b1     = (const float*)d_in[16];
  const float* w2     = (const float*)d_in[17];
  const float* b2     = (const float*)d_in[18];
  const float* outg   = (const float*)d_in[19];
  const float* outb   = (const float*)d_in[20];

  const int N = in_sizes[0] / DMODEL;    // 20000
  const int E = in_sizes[1] / 2;         // 320000
  const int* src = ei;
  const int* dst = ei + E;

  const size_t NF = (size_t)N * DMODEL;
  const size_t EH = (size_t)E * NHEAD;

  // ---- workspace layout ----
  float* f      = (float*)d_ws;
  float* xbuf   = f;                     // NF fp32 (residual master)
  float* scores = f + NF;                // EH fp32 (holds exp(score))
  u16*   fout   = (u16*)(f + NF + EH);   // NF bf16 (GEMM outputs)
  u16*   xb     = fout + NF;             // NF bf16
  u16*   Qeb    = xb + NF;               // 3NF bf16  } h1b aliases Qeb
  u16*   h1b    = Qeb;                   // alias (2NF used, FFN phase only)
  u16*   aggb   = Qeb + 3 * NF;          // NF bf16
  u8*    Kb8    = (u8*)(aggb + NF);      // NF bytes fp8
  u8*    Vb8    = Kb8 + NF;              // NF bytes fp8
  u16*   wqkvb  = (u16*)(Vb8 + NF);      // 96 * 5120
  u16*   Wot    = wqkvb + (size_t)NLAYER * NTYPE * NHEAD * 5120;
  u16*   w1t    = Wot + 3 * 65536;
  u16*   w2t    = w1t + 3 * 262144;
  int*   ip     = (int*)(w2t + 3 * 262144);
  int*   off    = ip;                    // N+1
  int*   csr_src= off + (N + 1);         // E
  int*   csr_dst= csr_src + E;           // E
  int*   csr_et = csr_dst + E;           // E
  int*   cursor = csr_et + E;            // N
  int*   tidx   = cursor + N;            // N
  int*   toff   = tidx + N;              // NTYPE+1
  int*   tile_off = toff + (NTYPE + 1);  // NTYPE+1
  int*   tcnt   = tile_off + (NTYPE + 1);// NTYPE
  int*   tcur   = tcnt + NTYPE;          // NTYPE

  // ---- CSR + type buckets (once) ----
  hipMemsetAsync(cursor, 0, (size_t)N * sizeof(int), stream);
  hipMemsetAsync(tcnt, 0, 2 * NTYPE * sizeof(int), stream);
  count_deg_kernel<<<(E + 255) / 256, 256, 0, stream>>>(dst, cursor, E);
  scan_kernel<<<1, 1024, 0, stream>>>(cursor, off, N);
  hipMemsetAsync(cursor, 0, (size_t)N * sizeof(int), stream);
  scatter_kernel<<<(E + 255) / 256, 256, 0, stream>>>(
      src, dst, etype, off, cursor, csr_src, csr_dst, csr_et, E);
  tcount_kernel<<<(N + 255) / 256, 256, 0, stream>>>(ntype, tcnt, N);
  tscan_kernel<<<1, 64, 0, stream>>>(tcnt, toff, tile_off);
  tscatter_kernel<<<(N + 255) / 256, 256, 0, stream>>>(ntype, toff, tcur, tidx, N);

  // ---- weight prep (once) ----
  wprep_kernel<<<NLAYER * NTYPE * NHEAD, 256, 0, stream>>>(W_Q, W_K, W_V, W_E, wqkvb);
  convT_kernel<<<dim3(DMODEL / 32, DMODEL / 32, NLAYER), 256, 0, stream>>>(
      Wo, Wot, DMODEL, DMODEL);
  convT_kernel<<<dim3(4 * DMODEL / 32, DMODEL / 32, NLAYER), 256, 0, stream>>>(
      w1, w1t, DMODEL, 4 * DMODEL);
  convT_kernel<<<dim3(DMODEL / 32, 4 * DMODEL / 32, NLAYER), 256, 0, stream>>>(
      w2, w2t, 4 * DMODEL, DMODEL);

  // ---- x working copies ----
  hipMemcpyAsync(xbuf, x_in, NF * sizeof(float), hipMemcpyDeviceToDevice, stream);
  xconv_kernel<<<(int)((NF / 4 + 255) / 256), 256, 0, stream>>>(x_in, xb, (int)(NF / 4));

  const int gm = (N + 127) / 128;
  const int lng = (N + 3) / 4;
  const int qtiles = (N + 63) / 64 + NTYPE;
  for (int l = 0; l < NLAYER; ++l) {
    qkv_mfma<<<dim3(qtiles, NHEAD), 256, 0, stream>>>(
        xb, tidx, toff, tile_off,
        wqkvb + (size_t)l * NTYPE * NHEAD * 5120, Kb8, Vb8, Qeb);
    score_kernel<<<(int)((EH + 255) / 256), 256, 0, stream>>>(
        csr_src, csr_dst, csr_et, Qeb, Kb8, mu + (size_t)l * NHEAD * ETYPE, scores, E);
    agg_kernel<<<N, 256, 0, stream>>>(off, csr_src, scores, Vb8, aggb);

    gemm_mfma<0, 128><<<dim3(DMODEL / 128, gm), 256, 0, stream>>>(
        aggb, Wot + (size_t)l * 65536, bo + (size_t)l * DMODEL,
        fout, N, DMODEL, DMODEL);
    ln_kernel<<<lng, 256, 0, stream>>>(xbuf, fout,
        ln1g + (size_t)l * DMODEL, ln1b + (size_t)l * DMODEL, xbuf, xb, N);
    gemm_mfma<1, 128><<<dim3(4 * DMODEL / 128, gm), 256, 0, stream>>>(
        xb, w1t + (size_t)l * 262144, b1 + (size_t)l * 4 * DMODEL,
        h1b, N, DMODEL, 4 * DMODEL);
    gemm_mfma<0, 128><<<dim3(DMODEL / 128, gm), 256, 0, stream>>>(
        h1b, w2t + (size_t)l * 262144, b2 + (size_t)l * DMODEL,
        fout, N, 4 * DMODEL, DMODEL);
    ln_kernel<<<lng, 256, 0, stream>>>(xbuf, fout,
        ln2g + (size_t)l * DMODEL, ln2b + (size_t)l * DMODEL, xbuf, xb, N);
  }

  ln_kernel<<<lng, 256, 0, stream>>>(xbuf, nullptr, outg, outb, (float*)d_out, nullptr, N);
}

// Round 6
// 706.376 us; speedup vs baseline: 1.2615x; 1.0329x over previous
//
#include <hip/hip_runtime.h>
#include <hip/hip_fp8.h>
#include <math.h>

#define HDIM 32
#define NHEAD 8
#define DMODEL 256
#define NTYPE 4
#define ETYPE 3
#define NLAYER 3

typedef unsigned short u16;
typedef unsigned char u8;
typedef __bf16 bf16x8 __attribute__((ext_vector_type(8)));
typedef float f32x4 __attribute__((ext_vector_type(4)));

__device__ __forceinline__ u16 f2bf(float f) {
  union { float f; unsigned u; } v; v.f = f;
  unsigned r = v.u + 0x7FFF + ((v.u >> 16) & 1);
  return (u16)(r >> 16);
}
__device__ __forceinline__ float bf2f(u16 b) {
  union { unsigned u; float f; } v; v.u = (unsigned)b << 16; return v.f;
}
__device__ __forceinline__ u8 f2fp8(float v) {
  __hip_fp8_e4m3 t(v); return (u8)t.__x;
}
__device__ __forceinline__ float fp82f(unsigned b) {
  __hip_fp8_e4m3 t; t.__x = (__hip_fp8_storage_t)b; return (float)t;
}

// fast GELU (tanh form)
__device__ __forceinline__ float gelu_f(float v) {
  float u = 0.7978845608028654f * v * (1.f + 0.044715f * v * v);
  float e = __expf(-2.f * fabsf(u));
  float th = (1.f - e) / (1.f + e);
  th = copysignf(th, u);
  return 0.5f * v * (1.f + th);
}

#define GLDS16(g, l)                                              \
  __builtin_amdgcn_global_load_lds(                               \
      (const __attribute__((address_space(1))) void*)(g),         \
      (__attribute__((address_space(3))) void*)(l), 16, 0, 0)

// ---------------------------------------------------------------------------
// CSR build (dst-sorted edge VALUES in position order)
// ---------------------------------------------------------------------------
__global__ void count_deg_kernel(const int* __restrict__ dst, int* __restrict__ deg, int E) {
  int tid = blockIdx.x * 256 + threadIdx.x;
  if (tid < E) atomicAdd(&deg[dst[tid]], 1);
}

__global__ __launch_bounds__(1024) void scan_kernel(const int* __restrict__ deg,
                                                    int* __restrict__ off, int n) {
  __shared__ int part[1024];
  int t = threadIdx.x;
  int chunk = (n + 1023) >> 10;
  int base = t * chunk;
  int s = 0;
  for (int i = 0; i < chunk; ++i) {
    int idx = base + i;
    if (idx < n) s += deg[idx];
  }
  part[t] = s;
  __syncthreads();
  for (int o = 1; o < 1024; o <<= 1) {
    int v = (t >= o) ? part[t - o] : 0;
    __syncthreads();
    part[t] += v;
    __syncthreads();
  }
  int run = part[t] - s;
  for (int i = 0; i < chunk; ++i) {
    int idx = base + i;
    if (idx < n) { off[idx] = run; run += deg[idx]; }
  }
  if (t == 1023) off[n] = part[1023];
}

__global__ void scatter_kernel(const int* __restrict__ src, const int* __restrict__ dst,
                               const int* __restrict__ etype,
                               const int* __restrict__ off, int* __restrict__ cursor,
                               int* __restrict__ csr_src,
                               int* __restrict__ csr_et, int E) {
  int tid = blockIdx.x * 256 + threadIdx.x;
  if (tid < E) {
    int d = dst[tid];
    int p = atomicAdd(&cursor[d], 1);
    int pos = off[d] + p;
    csr_src[pos] = src[tid];
    csr_et[pos] = etype[tid];
  }
}

// ---------------------------------------------------------------------------
// Node-type buckets — hierarchical to avoid same-address atomic contention
// ---------------------------------------------------------------------------
__global__ void tcount_kernel(const int* __restrict__ nt, int* __restrict__ tcnt, int N) {
  __shared__ int h[NTYPE];
  int t = threadIdx.x;
  if (t < NTYPE) h[t] = 0;
  __syncthreads();
  int tid = blockIdx.x * 256 + t;
  if (tid < N) atomicAdd(&h[nt[tid]], 1);
  __syncthreads();
  if (t < NTYPE && h[t] > 0) atomicAdd(&tcnt[t], h[t]);
}

__global__ void tscan_kernel(const int* __restrict__ tcnt, int* __restrict__ toff,
                             int* __restrict__ tile_off) {
  if (threadIdx.x == 0 && blockIdx.x == 0) {
    int o = 0, to = 0;
    for (int t = 0; t < NTYPE; ++t) {
      toff[t] = o; tile_off[t] = to;
      o += tcnt[t]; to += (tcnt[t] + 63) >> 6;
    }
    toff[NTYPE] = o; tile_off[NTYPE] = to;
  }
}

__global__ void tscatter_kernel(const int* __restrict__ nt, const int* __restrict__ toff,
                                int* __restrict__ tcur, int* __restrict__ tidx, int N) {
  int tid = blockIdx.x * 256 + threadIdx.x;
  int lane = threadIdx.x & 63;
  int ty = (tid < N) ? nt[tid] : -1;
  unsigned long long lt_mask = (lane == 63) ? 0x7FFFFFFFFFFFFFFFull
                                            : ((1ull << lane) - 1);
#pragma unroll
  for (int t4 = 0; t4 < NTYPE; ++t4) {
    unsigned long long mask = __ballot(ty == t4);
    if (mask == 0) continue;
    int first = __builtin_ctzll(mask);
    int cnt = __popcll(mask);
    int base = 0;
    if (lane == first) base = atomicAdd(&tcur[t4], cnt);
    base = __shfl(base, first, 64);
    if (ty == t4) {
      int rank = __popcll(mask & lt_mask);
      tidx[toff[t4] + base + rank] = tid;
    }
  }
}

// ---------------------------------------------------------------------------
// x fp32 -> {fp32 residual master copy, bf16 mirror} in one pass
// ---------------------------------------------------------------------------
__global__ void xconv_kernel(const float* __restrict__ x, float* __restrict__ xbuf,
                             u16* __restrict__ xb, int n4) {
  int i = blockIdx.x * 256 + threadIdx.x;
  if (i < n4) {
    float4 v = ((const float4*)x)[i];
    ((float4*)xbuf)[i] = v;
    ushort4 o = { f2bf(v.x), f2bf(v.y), f2bf(v.z), f2bf(v.w) };
    ((ushort4*)xb)[i] = o;
  }
}

// ---------------------------------------------------------------------------
// Weight prep, per (l,type,head): bf16 B-operand mats ([col][k], k contig):
//   mat0 = WK^T, mat1 = WV^T,
//   mat2..4 = WQE[et] with Qe = x @ (WQ @ WE[et]^T)
// wq stored PADDED [32][33]: read wq[k*33+j] -> bank (k+j)&31, conflict-free
// (was 32-way conflict, 6.8M counted, 40.7µs once-only kernel -> fixed R5).
// ---------------------------------------------------------------------------
__global__ __launch_bounds__(256) void wprep_kernel(
    const float* __restrict__ W_Q, const float* __restrict__ W_K,
    const float* __restrict__ W_V, const float* __restrict__ W_E,
    u16* __restrict__ wqkvb) {
  int b = blockIdx.x;
  int h = b & 7, tt = (b >> 3) & 3, l = b >> 5;
  __shared__ float wq[1056];         // 32 x 33 padded
  __shared__ float we[3][1024];
  int t = threadIdx.x;
  const float* WQp = W_Q + (((size_t)l * NTYPE + tt) * NHEAD + h) * 1024;
  for (int i = t; i < 1024; i += 256) wq[(i >> 5) * 33 + (i & 31)] = WQp[i];
  for (int et = 0; et < ETYPE; ++et) {
    const float* WEp = W_E + (((size_t)l * ETYPE + et) * NHEAD + h) * 1024;
    for (int i = t; i < 1024; i += 256) we[et][i] = WEp[i];
  }
  __syncthreads();
  const float* WKp = W_K + (((size_t)l * NTYPE + tt) * NHEAD + h) * 1024;
  const float* WVp = W_V + (((size_t)l * NTYPE + tt) * NHEAD + h) * 1024;
  u16* out = wqkvb + (size_t)b * 5120;
  for (int i = t; i < 1024; i += 256) {
    int col = i >> 5, k = i & 31;
    out[i] = f2bf(WKp[k * 32 + col]);
    out[1024 + i] = f2bf(WVp[k * 32 + col]);
#pragma unroll
    for (int et = 0; et < ETYPE; ++et) {
      float a = 0.f;
#pragma unroll
      for (int j = 0; j < 32; ++j) a += wq[k * 33 + j] * we[et][col * 32 + j];
      out[(2 + et) * 1024 + i] = f2bf(a);
    }
  }
}

// ---------------------------------------------------------------------------
// QKV via MFMA over type buckets: K,V stored fp8 e4m3, Qe[3] bf16.
// LDS layout for MFMA operands is [k-slot][row] per 16-row chunk so the
// b128 fragment reads are bank-conflict-free (reg-staged ds_write, so the
// scatter layout is free here).
// ---------------------------------------------------------------------------
__global__ __launch_bounds__(256) void qkv_mfma(
    const u16* __restrict__ xb, const int* __restrict__ tidx,
    const int* __restrict__ toff, const int* __restrict__ tile_off,
    const u16* __restrict__ wqkvb_l,
    u8* __restrict__ Kb8, u8* __restrict__ Vb8, u16* __restrict__ Qeb) {
  __shared__ u16 smem[10240];
  int bx = blockIdx.x, h = blockIdx.y;
  if (bx >= tile_off[NTYPE]) return;
  int ty = 0;
  while (bx >= tile_off[ty + 1]) ++ty;
  int lt = bx - tile_off[ty];
  int base = toff[ty] + lt * 64;
  int cnt = min(64, toff[ty + 1] - toff[ty] - lt * 64);
  int t = threadIdx.x;
  {
    // x tile 64 rows x 32 k, stored as [rgroup(4)][slot(4)][row16(16)] 16B units
    int row = ((t >> 6) << 4) | (t & 15);
    int q = (t >> 4) & 3;
    int node = tidx[base + min(row, cnt - 1)];
    *(uint4*)&smem[t * 8] =
        *(const uint4*)&xb[(size_t)node * 256 + h * 32 + q * 8];
  }
  // weights: 5 mats of 32 cols x 32 k; store as [mt][slot(4)][col(32)] 16B units
  const u16* wsrc = wqkvb_l + ((size_t)ty * NHEAD + h) * 5120;
  for (int dc = t; dc < 640; dc += 256) {
    int mt = dc >> 7, wi = dc & 127, slot = wi >> 5, colx = wi & 31;
    *(uint4*)&smem[2048 + dc * 8] = *(const uint4*)&wsrc[(mt * 128 + colx * 4 + slot) * 8];
  }
  __syncthreads();

  int lane = t & 63, w = t >> 6;
  int m = lane & 15, q = lane >> 4;
  bf16x8 af = *(const bf16x8*)&smem[w * 512 + q * 128 + m * 8];
  f32x4 acc[5][2];
#pragma unroll
  for (int mt = 0; mt < 5; ++mt)
#pragma unroll
    for (int c = 0; c < 2; ++c) {
      bf16x8 bf = *(const bf16x8*)&smem[2048 + mt * 1024 + q * 256 + (c * 16 + m) * 8];
      acc[mt][c] = __builtin_amdgcn_mfma_f32_16x16x32_bf16(af, bf, (f32x4){0.f, 0.f, 0.f, 0.f}, 0, 0, 0);
    }
  __syncthreads();
#pragma unroll
  for (int mt = 0; mt < 5; ++mt)
#pragma unroll
    for (int c = 0; c < 2; ++c)
#pragma unroll
      for (int r = 0; r < 4; ++r)
        smem[mt * 2048 + (w * 16 + q * 4 + r) * 32 + c * 16 + m] = f2bf(acc[mt][c][r]);
  __syncthreads();
  {
    int row = t >> 2, q4 = t & 3;
    if (row < cnt) {
      int node = tidx[base + row];
      {
        const u16* sp = &smem[row * 32 + q4 * 8];
        unsigned long long pk = 0;
#pragma unroll
        for (int j = 0; j < 8; ++j)
          pk |= (unsigned long long)f2fp8(bf2f(sp[j])) << (8 * j);
        *(unsigned long long*)&Kb8[(size_t)node * 256 + h * 32 + q4 * 8] = pk;
      }
      {
        const u16* sp = &smem[2048 + row * 32 + q4 * 8];
        unsigned long long pk = 0;
#pragma unroll
        for (int j = 0; j < 8; ++j)
          pk |= (unsigned long long)f2fp8(bf2f(sp[j])) << (8 * j);
        *(unsigned long long*)&Vb8[(size_t)node * 256 + h * 32 + q4 * 8] = pk;
      }
#pragma unroll
      for (int et = 0; et < ETYPE; ++et)
        *(uint4*)&Qeb[((size_t)node * ETYPE + et) * 256 + h * 32 + q4 * 8] =
            *(const uint4*)&smem[(2 + et) * 2048 + row * 32 + q4 * 8];
    }
  }
}

// ---------------------------------------------------------------------------
// FUSED score+softmax+aggregate. Key insight: within a block the dst node is
// FIXED, so Q[dst] for all 3 edge types is 3 rows -> preloaded to registers
// (was: score_kernel gathered 512B of Q PER EDGE = ~164MB/layer). Per edge:
// gather K row (4B/lane), 4-FMA partial dot, 3x shfl_xor reduce within the
// 8-lane head group (each 64-lane group = one wave; et is wave-uniform so
// the q0/q1/q2 select is divergence-free), exp, then V accumulate as before.
// 4-way edge parallelism (4 waves walk every 4th edge).
// ---------------------------------------------------------------------------
__global__ __launch_bounds__(256) void agg_kernel(
    const int* __restrict__ off, const int* __restrict__ csr_src,
    const int* __restrict__ csr_et, const u16* __restrict__ Qeb,
    const u8* __restrict__ Kb8, const float* __restrict__ mu,
    const u8* __restrict__ Vb8, u16* __restrict__ aggb) {
  __shared__ float sacc[4][256];
  __shared__ float sssum[4][8];
  int n = blockIdx.x;
  int t = threadIdx.x;
  int g = t >> 6;          // edge group 0..3 (one wave each)
  int l = t & 63;          // lane in group
  int d0 = l * 4;          // dims [d0, d0+4)
  int h = l >> 3;          // head of these dims

  // preload Q[dst=n] rows for the 3 edge types (bf16 -> f32), + scaled mu
  float4 q0, q1, q2;
  {
    const u16* qp = Qeb + (size_t)n * ETYPE * 256 + d0;
    ushort4 a = *(const ushort4*)(qp);
    ushort4 b = *(const ushort4*)(qp + 256);
    ushort4 c = *(const ushort4*)(qp + 512);
    q0 = make_float4(bf2f(a.x), bf2f(a.y), bf2f(a.z), bf2f(a.w));
    q1 = make_float4(bf2f(b.x), bf2f(b.y), bf2f(b.z), bf2f(b.w));
    q2 = make_float4(bf2f(c.x), bf2f(c.y), bf2f(c.z), bf2f(c.w));
  }
  const float sc = 0.17677669529663687f;
  float mu0 = sc * mu[h * ETYPE + 0];
  float mu1 = sc * mu[h * ETYPE + 1];
  float mu2 = sc * mu[h * ETYPE + 2];

  int s0 = off[n], s1 = off[n + 1];
  float a0 = 0.f, a1 = 0.f, a2 = 0.f, a3 = 0.f, ssum = 0.f;
  for (int k = s0 + g; k < s1; k += 4) {
    int sn = csr_src[k];
    int et = csr_et[k];
    unsigned k4 = *(const unsigned*)(Kb8 + (size_t)sn * 256 + d0);
    float4 qe = (et == 0) ? q0 : (et == 1) ? q1 : q2;
    float mue = (et == 0) ? mu0 : (et == 1) ? mu1 : mu2;
    float p = fp82f(k4 & 0xffu) * qe.x + fp82f((k4 >> 8) & 0xffu) * qe.y
            + fp82f((k4 >> 16) & 0xffu) * qe.z + fp82f((k4 >> 24) & 0xffu) * qe.w;
    p += __shfl_xor(p, 1, 64);
    p += __shfl_xor(p, 2, 64);
    p += __shfl_xor(p, 4, 64);   // full 32-dim dot, replicated in the 8 head lanes
    float e = __expf(p * mue);
    unsigned v4 = *(const unsigned*)(Vb8 + (size_t)sn * 256 + d0);
    a0 += e * fp82f(v4 & 0xffu);
    a1 += e * fp82f((v4 >> 8) & 0xffu);
    a2 += e * fp82f((v4 >> 16) & 0xffu);
    a3 += e * fp82f((v4 >> 24) & 0xffu);
    ssum += e;
  }
  *(float4*)&sacc[g][d0] = make_float4(a0, a1, a2, a3);
  if ((l & 7) == 0) sssum[g][h] = ssum;
  __syncthreads();
  int hh = t >> 5;
  float tot = sacc[0][t] + sacc[1][t] + sacc[2][t] + sacc[3][t];
  float st = sssum[0][hh] + sssum[1][hh] + sssum[2][hh] + sssum[3][hh];
  aggb[(size_t)n * 256 + t] = f2bf(tot / (st + 1e-10f));
}

// ---------------------------------------------------------------------------
// fp32 [K,Nc] -> bf16 transposed [Nc,K]
// ---------------------------------------------------------------------------
__global__ __launch_bounds__(256) void convT_kernel(const float* __restrict__ W,
                                                    u16* __restrict__ Wt, int K, int Nc) {
  __shared__ float tile[32][33];
  int bk = blockIdx.y * 32, bn = blockIdx.x * 32;
  const float* Wz = W + (size_t)blockIdx.z * K * Nc;
  u16* Wtz = Wt + (size_t)blockIdx.z * K * Nc;
  int tx = threadIdx.x & 31, ty = threadIdx.x >> 5;
  for (int r = ty; r < 32; r += 8)
    tile[r][tx] = Wz[(size_t)(bk + r) * Nc + bn + tx];
  __syncthreads();
  for (int r = ty; r < 32; r += 8)
    Wtz[(size_t)(bn + r) * K + bk + tx] = f2bf(tile[tx][r]);
}

// ---------------------------------------------------------------------------
// bf16 MFMA GEMM: C[M,Nc] = A[M,K] @ Bt[Nc,K]^T + bias -> bf16 out.
// BM=128, BN=128 for all gemms. GELU=1 adds fast-GELU to the epilogue.
// Proven structure (R0-R5): single-buffer lane-linear staging (both
// conflict-fix remaps measured slower; stage coalescing dominates), BK=64
// (half the vmcnt(0) drains), bijective XCD swizzle (L2 panel reuse).
// ---------------------------------------------------------------------------
template <int GELU, int BN>
__global__ __launch_bounds__(256) void gemm_mfma(
    const u16* __restrict__ A, const u16* __restrict__ Bt,
    const float* __restrict__ bias, u16* __restrict__ Cb,
    int M, int K, int Nc) {
  constexpr int MJ = BN / 32;
  __shared__ u16 As[128 * 64];       // 2 halves x 8 chunks x 64 lanes x 8 u16
  __shared__ u16 Bs[BN * 64];
  const int t = threadIdx.x;
  const int lane = t & 63;
  const int w = t >> 6;

  // bijective XCD-aware remap (8 XCDs, round-robin dispatch by linear id)
  const int nwg = gridDim.x * gridDim.y;
  const int lin = blockIdx.y * gridDim.x + blockIdx.x;
  const int qq = nwg >> 3, rr = nwg & 7;
  const int xcd = lin & 7, pos = lin >> 3;
  const int nl = (xcd < rr ? xcd * (qq + 1) : rr * (qq + 1) + (xcd - rr) * qq) + pos;
  const int row0 = (nl / gridDim.x) * 128;
  const int col0 = (nl % gridDim.x) * BN;

  const int wm = (w >> 1) * 64, wn = (w & 1) * (BN / 2);

  f32x4 acc[4][MJ] = {};
  const int sr = lane >> 2;        // stage row within 16-row chunk
  const int sk = (lane & 3) * 8;   // stage k-slot (lane-linear: coalesced)

  for (int k0 = 0; k0 < K; k0 += 64) {
#pragma unroll
    for (int half = 0; half < 2; ++half) {
#pragma unroll
      for (int c = 0; c < 2; ++c) {
        const int chunk = w * 2 + c;
        const int r = chunk * 16 + sr;
        int ra = row0 + r; if (ra >= M) ra = M - 1;
        GLDS16(A + (size_t)ra * K + k0 + half * 32 + sk,
               &As[((half * 8 + chunk) * 64 + lane) * 8]);
        if (BN == 128) {
          GLDS16(Bt + (size_t)(col0 + r) * K + k0 + half * 32 + sk,
                 &Bs[((half * 8 + chunk) * 64 + lane) * 8]);
        }
      }
      if (BN == 64) {
        const int r = w * 16 + sr;
        GLDS16(Bt + (size_t)(col0 + r) * K + k0 + half * 32 + sk,
               &Bs[((half * 4 + w) * 64 + lane) * 8]);
      }
    }
    __syncthreads();
    const int ko = (lane >> 4) * 8;
    const int lr = lane & 15;
#pragma unroll
    for (int half = 0; half < 2; ++half) {
      bf16x8 af[4], bfr[MJ];
      const int ab = half * 8 * 512;                       // A half offset (u16)
      const int bb = half * (BN == 128 ? 8 : 4) * 512;     // B half offset (u16)
#pragma unroll
      for (int i = 0; i < 4; ++i)
        af[i] = *(const bf16x8*)&As[ab + ((wm >> 4) + i) * 512 + lr * 32 + ko];
#pragma unroll
      for (int j = 0; j < MJ; ++j)
        bfr[j] = *(const bf16x8*)&Bs[bb + ((wn >> 4) + j) * 512 + lr * 32 + ko];
#pragma unroll
      for (int i = 0; i < 4; ++i)
#pragma unroll
        for (int j = 0; j < MJ; ++j)
          acc[i][j] = __builtin_amdgcn_mfma_f32_16x16x32_bf16(af[i], bfr[j], acc[i][j], 0, 0, 0);
    }
    __syncthreads();
  }

  const int lc = lane & 15;
  const int lrow = (lane >> 4) * 4;
  float bv[MJ];
#pragma unroll
  for (int j = 0; j < MJ; ++j) bv[j] = bias[col0 + wn + j * 16 + lc];
#pragma unroll
  for (int i = 0; i < 4; ++i) {
#pragma unroll
    for (int r = 0; r < 4; ++r) {
      int gr = row0 + wm + i * 16 + lrow + r;
      if (gr >= M) continue;
#pragma unroll
      for (int j = 0; j < MJ; ++j) {
        int gc = col0 + wn + j * 16 + lc;
        float v = acc[i][j][r] + bv[j];
        if (GELU) v = gelu_f(v);
        Cb[(size_t)gr * Nc + gc] = f2bf(v);
      }
    }
  }
}

// ---------------------------------------------------------------------------
// LayerNorm rows of 256: out = LN(xin + res) * g + b; res is bf16 (or null).
// Wave-per-row: lane holds float4 (64 lanes x 4 = 256), pure shfl_xor
// reductions — no LDS, no barriers. 4 rows/block, vectorized loads/stores.
// ---------------------------------------------------------------------------
__global__ __launch_bounds__(256) void ln_kernel(
    const float* __restrict__ xin, const u16* __restrict__ res,
    const float* __restrict__ g, const float* __restrict__ b,
    float* __restrict__ out, u16* __restrict__ outb, int N) {
  int row = blockIdx.x * 4 + (threadIdx.x >> 6);
  if (row >= N) return;
  int l = threadIdx.x & 63;
  size_t base = (size_t)row * 256 + l * 4;
  float4 r4 = *(const float4*)&xin[base];
  if (res) {
    ushort4 rb = *(const ushort4*)&res[base];
    r4.x += bf2f(rb.x); r4.y += bf2f(rb.y);
    r4.z += bf2f(rb.z); r4.w += bf2f(rb.w);
  }
  float s = r4.x + r4.y + r4.z + r4.w;
  for (int o = 32; o > 0; o >>= 1) s += __shfl_xor(s, o, 64);
  float m = s * (1.f / 256.f);
  float dx = r4.x - m, dy = r4.y - m, dz = r4.z - m, dw = r4.w - m;
  float s2 = dx * dx + dy * dy + dz * dz + dw * dw;
  for (int o = 32; o > 0; o >>= 1) s2 += __shfl_xor(s2, o, 64);
  float inv = rsqrtf(s2 * (1.f / 256.f) + 1e-5f);
  float4 g4 = *(const float4*)&g[l * 4];
  float4 b4 = *(const float4*)&b[l * 4];
  float4 o4 = { dx * inv * g4.x + b4.x, dy * inv * g4.y + b4.y,
                dz * inv * g4.z + b4.z, dw * inv * g4.w + b4.w };
  *(float4*)&out[base] = o4;
  if (outb) {
    ushort4 ob = { f2bf(o4.x), f2bf(o4.y), f2bf(o4.z), f2bf(o4.w) };
    *(ushort4*)&outb[base] = ob;
  }
}

// ---------------------------------------------------------------------------
extern "C" void kernel_launch(void* const* d_in, const int* in_sizes, int n_in,
                              void* d_out, int out_size, void* d_ws, size_t ws_size,
                              hipStream_t stream) {
  const float* x_in   = (const float*)d_in[0];
  const int*   ei     = (const int*)d_in[1];
  const int*   etype  = (const int*)d_in[2];
  const int*   ntype  = (const int*)d_in[3];
  const float* W_Q    = (const float*)d_in[4];
  const float* W_K    = (const float*)d_in[5];
  const float* W_V    = (const float*)d_in[6];
  const float* W_E    = (const float*)d_in[7];
  const float* mu     = (const float*)d_in[8];
  const float* Wo     = (const float*)d_in[9];
  const float* bo     = (const float*)d_in[10];
  const float* ln1g   = (const float*)d_in[11];
  const float* ln1b   = (const float*)d_in[12];
  const float* ln2g   = (const float*)d_in[13];
  const float* ln2b   = (const float*)d_in[14];
  const float* w1     = (const float*)d_in[15];
  const float* b1     = (const float*)d_in[16];
  const float* w2     = (const float*)d_in[17];
  const float* b2     = (const float*)d_in[18];
  const float* outg   = (const float*)d_in[19];
  const float* outb   = (const float*)d_in[20];

  const int N = in_sizes[0] / DMODEL;    // 20000
  const int E = in_sizes[1] / 2;         // 320000
  const int* src = ei;
  const int* dst = ei + E;

  const size_t NF = (size_t)N * DMODEL;
  const size_t EH = (size_t)E * NHEAD;

  // ---- workspace layout (scores slot retained but unused after fusion) ----
  float* f      = (float*)d_ws;
  float* xbuf   = f;                     // NF fp32 (residual master)
  float* scores = f + NF;                // EH fp32 (UNUSED after R6 fusion)
  u16*   fout   = (u16*)(f + NF + EH);   // NF bf16 (GEMM outputs)
  u16*   xb     = fout + NF;             // NF bf16
  u16*   Qeb    = xb + NF;               // 3NF bf16  } h1b aliases Qeb
  u16*   h1b    = Qeb;                   // alias (2NF used, FFN phase only)
  u16*   aggb   = Qeb + 3 * NF;          // NF bf16
  u8*    Kb8    = (u8*)(aggb + NF);      // NF bytes fp8
  u8*    Vb8    = Kb8 + NF;              // NF bytes fp8
  u16*   wqkvb  = (u16*)(Vb8 + NF);      // 96 * 5120
  u16*   Wot    = wqkvb + (size_t)NLAYER * NTYPE * NHEAD * 5120;
  u16*   w1t    = Wot + 3 * 65536;
  u16*   w2t    = w1t + 3 * 262144;
  int*   ip     = (int*)(w2t + 3 * 262144);
  int*   off    = ip;                    // N+1
  int*   csr_src= off + (N + 1);         // E
  int*   csr_dst= csr_src + E;           // E (slot retained, unused)
  int*   csr_et = csr_dst + E;           // E
  int*   cursor = csr_et + E;            // N
  int*   tidx   = cursor + N;            // N
  int*   toff   = tidx + N;              // NTYPE+1
  int*   tile_off = toff + (NTYPE + 1);  // NTYPE+1
  int*   tcnt   = tile_off + (NTYPE + 1);// NTYPE
  int*   tcur   = tcnt + NTYPE;          // NTYPE
  (void)scores; (void)csr_dst;

  // ---- CSR + type buckets (once) ----
  hipMemsetAsync(cursor, 0, (size_t)N * sizeof(int), stream);
  hipMemsetAsync(tcnt, 0, 2 * NTYPE * sizeof(int), stream);
  count_deg_kernel<<<(E + 255) / 256, 256, 0, stream>>>(dst, cursor, E);
  scan_kernel<<<1, 1024, 0, stream>>>(cursor, off, N);
  hipMemsetAsync(cursor, 0, (size_t)N * sizeof(int), stream);
  scatter_kernel<<<(E + 255) / 256, 256, 0, stream>>>(
      src, dst, etype, off, cursor, csr_src, csr_et, E);
  tcount_kernel<<<(N + 255) / 256, 256, 0, stream>>>(ntype, tcnt, N);
  tscan_kernel<<<1, 64, 0, stream>>>(tcnt, toff, tile_off);
  tscatter_kernel<<<(N + 255) / 256, 256, 0, stream>>>(ntype, toff, tcur, tidx, N);

  // ---- weight prep (once) ----
  wprep_kernel<<<NLAYER * NTYPE * NHEAD, 256, 0, stream>>>(W_Q, W_K, W_V, W_E, wqkvb);
  convT_kernel<<<dim3(DMODEL / 32, DMODEL / 32, NLAYER), 256, 0, stream>>>(
      Wo, Wot, DMODEL, DMODEL);
  convT_kernel<<<dim3(4 * DMODEL / 32, DMODEL / 32, NLAYER), 256, 0, stream>>>(
      w1, w1t, DMODEL, 4 * DMODEL);
  convT_kernel<<<dim3(DMODEL / 32, 4 * DMODEL / 32, NLAYER), 256, 0, stream>>>(
      w2, w2t, 4 * DMODEL, DMODEL);

  // ---- x working copies (fused copy + bf16 convert) ----
  xconv_kernel<<<(int)((NF / 4 + 255) / 256), 256, 0, stream>>>(
      x_in, xbuf, xb, (int)(NF / 4));

  const int gm = (N + 127) / 128;
  const int lng = (N + 3) / 4;
  const int qtiles = (N + 63) / 64 + NTYPE;
  for (int l = 0; l < NLAYER; ++l) {
    qkv_mfma<<<dim3(qtiles, NHEAD), 256, 0, stream>>>(
        xb, tidx, toff, tile_off,
        wqkvb + (size_t)l * NTYPE * NHEAD * 5120, Kb8, Vb8, Qeb);
    agg_kernel<<<N, 256, 0, stream>>>(off, csr_src, csr_et, Qeb, Kb8,
        mu + (size_t)l * NHEAD * ETYPE, Vb8, aggb);

    gemm_mfma<0, 128><<<dim3(DMODEL / 128, gm), 256, 0, stream>>>(
        aggb, Wot + (size_t)l * 65536, bo + (size_t)l * DMODEL,
        fout, N, DMODEL, DMODEL);
    ln_kernel<<<lng, 256, 0, stream>>>(xbuf, fout,
        ln1g + (size_t)l * DMODEL, ln1b + (size_t)l * DMODEL, xbuf, xb, N);
    gemm_mfma<1, 128><<<dim3(4 * DMODEL / 128, gm), 256, 0, stream>>>(
        xb, w1t + (size_t)l * 262144, b1 + (size_t)l * 4 * DMODEL,
        h1b, N, DMODEL, 4 * DMODEL);
    gemm_mfma<0, 128><<<dim3(DMODEL / 128, gm), 256, 0, stream>>>(
        h1b, w2t + (size_t)l * 262144, b2 + (size_t)l * DMODEL,
        fout, N, 4 * DMODEL, DMODEL);
    ln_kernel<<<lng, 256, 0, stream>>>(xbuf, fout,
        ln2g + (size_t)l * DMODEL, ln2b + (size_t)l * DMODEL, xbuf, xb, N);
  }

  ln_kernel<<<lng, 256, 0, stream>>>(xbuf, nullptr, outg, outb, (float*)d_out, nullptr, N);
}

// Round 7
// 700.365 us; speedup vs baseline: 1.2723x; 1.0086x over previous
//
#include <hip/hip_runtime.h>
#include <hip/hip_fp8.h>
#include <math.h>

#define HDIM 32
#define NHEAD 8
#define DMODEL 256
#define NTYPE 4
#define ETYPE 3
#define NLAYER 3

typedef unsigned short u16;
typedef unsigned char u8;
typedef __bf16 bf16x8 __attribute__((ext_vector_type(8)));
typedef float f32x4 __attribute__((ext_vector_type(4)));
typedef float f32x2 __attribute__((ext_vector_type(2)));

__device__ __forceinline__ u16 f2bf(float f) {
  union { float f; unsigned u; } v; v.f = f;
  unsigned r = v.u + 0x7FFF + ((v.u >> 16) & 1);
  return (u16)(r >> 16);
}
__device__ __forceinline__ float bf2f(u16 b) {
  union { unsigned u; float f; } v; v.u = (unsigned)b << 16; return v.f;
}
__device__ __forceinline__ u8 f2fp8(float v) {
  __hip_fp8_e4m3 t(v); return (u8)t.__x;
}
__device__ __forceinline__ float fp82f(unsigned b) {
  __hip_fp8_e4m3 t; t.__x = (__hip_fp8_storage_t)b; return (float)t;
}
// HW packed fp8(e4m3, OCP on gfx950) -> f32 decode: 4 bytes in 2 instructions.
__device__ __forceinline__ float4 fp8x4_f32(unsigned v) {
  f32x2 lo = __builtin_amdgcn_cvt_pk_f32_fp8((int)v, false);
  f32x2 hi = __builtin_amdgcn_cvt_pk_f32_fp8((int)v, true);
  return make_float4(lo[0], lo[1], hi[0], hi[1]);
}

// fast GELU (tanh form)
__device__ __forceinline__ float gelu_f(float v) {
  float u = 0.7978845608028654f * v * (1.f + 0.044715f * v * v);
  float e = __expf(-2.f * fabsf(u));
  float th = (1.f - e) / (1.f + e);
  th = copysignf(th, u);
  return 0.5f * v * (1.f + th);
}

#define GLDS16(g, l)                                              \
  __builtin_amdgcn_global_load_lds(                               \
      (const __attribute__((address_space(1))) void*)(g),         \
      (__attribute__((address_space(3))) void*)(l), 16, 0, 0)

// ---------------------------------------------------------------------------
// CSR build (dst-sorted edge VALUES in position order)
// ---------------------------------------------------------------------------
__global__ void count_deg_kernel(const int* __restrict__ dst, int* __restrict__ deg, int E) {
  int tid = blockIdx.x * 256 + threadIdx.x;
  if (tid < E) atomicAdd(&deg[dst[tid]], 1);
}

__global__ __launch_bounds__(1024) void scan_kernel(const int* __restrict__ deg,
                                                    int* __restrict__ off, int n) {
  __shared__ int part[1024];
  int t = threadIdx.x;
  int chunk = (n + 1023) >> 10;
  int base = t * chunk;
  int s = 0;
  for (int i = 0; i < chunk; ++i) {
    int idx = base + i;
    if (idx < n) s += deg[idx];
  }
  part[t] = s;
  __syncthreads();
  for (int o = 1; o < 1024; o <<= 1) {
    int v = (t >= o) ? part[t - o] : 0;
    __syncthreads();
    part[t] += v;
    __syncthreads();
  }
  int run = part[t] - s;
  for (int i = 0; i < chunk; ++i) {
    int idx = base + i;
    if (idx < n) { off[idx] = run; run += deg[idx]; }
  }
  if (t == 1023) off[n] = part[1023];
}

__global__ void scatter_kernel(const int* __restrict__ src, const int* __restrict__ dst,
                               const int* __restrict__ etype,
                               const int* __restrict__ off, int* __restrict__ cursor,
                               int* __restrict__ csr_src,
                               int* __restrict__ csr_et, int E) {
  int tid = blockIdx.x * 256 + threadIdx.x;
  if (tid < E) {
    int d = dst[tid];
    int p = atomicAdd(&cursor[d], 1);
    int pos = off[d] + p;
    csr_src[pos] = src[tid];
    csr_et[pos] = etype[tid];
  }
}

// ---------------------------------------------------------------------------
// Node-type buckets — hierarchical to avoid same-address atomic contention
// ---------------------------------------------------------------------------
__global__ void tcount_kernel(const int* __restrict__ nt, int* __restrict__ tcnt, int N) {
  __shared__ int h[NTYPE];
  int t = threadIdx.x;
  if (t < NTYPE) h[t] = 0;
  __syncthreads();
  int tid = blockIdx.x * 256 + t;
  if (tid < N) atomicAdd(&h[nt[tid]], 1);
  __syncthreads();
  if (t < NTYPE && h[t] > 0) atomicAdd(&tcnt[t], h[t]);
}

__global__ void tscan_kernel(const int* __restrict__ tcnt, int* __restrict__ toff,
                             int* __restrict__ tile_off) {
  if (threadIdx.x == 0 && blockIdx.x == 0) {
    int o = 0, to = 0;
    for (int t = 0; t < NTYPE; ++t) {
      toff[t] = o; tile_off[t] = to;
      o += tcnt[t]; to += (tcnt[t] + 63) >> 6;
    }
    toff[NTYPE] = o; tile_off[NTYPE] = to;
  }
}

__global__ void tscatter_kernel(const int* __restrict__ nt, const int* __restrict__ toff,
                                int* __restrict__ tcur, int* __restrict__ tidx, int N) {
  int tid = blockIdx.x * 256 + threadIdx.x;
  int lane = threadIdx.x & 63;
  int ty = (tid < N) ? nt[tid] : -1;
  unsigned long long lt_mask = (lane == 63) ? 0x7FFFFFFFFFFFFFFFull
                                            : ((1ull << lane) - 1);
#pragma unroll
  for (int t4 = 0; t4 < NTYPE; ++t4) {
    unsigned long long mask = __ballot(ty == t4);
    if (mask == 0) continue;
    int first = __builtin_ctzll(mask);
    int cnt = __popcll(mask);
    int base = 0;
    if (lane == first) base = atomicAdd(&tcur[t4], cnt);
    base = __shfl(base, first, 64);
    if (ty == t4) {
      int rank = __popcll(mask & lt_mask);
      tidx[toff[t4] + base + rank] = tid;
    }
  }
}

// ---------------------------------------------------------------------------
// x fp32 -> {fp32 residual master copy, bf16 mirror} in one pass
// ---------------------------------------------------------------------------
__global__ void xconv_kernel(const float* __restrict__ x, float* __restrict__ xbuf,
                             u16* __restrict__ xb, int n4) {
  int i = blockIdx.x * 256 + threadIdx.x;
  if (i < n4) {
    float4 v = ((const float4*)x)[i];
    ((float4*)xbuf)[i] = v;
    ushort4 o = { f2bf(v.x), f2bf(v.y), f2bf(v.z), f2bf(v.w) };
    ((ushort4*)xb)[i] = o;
  }
}

// ---------------------------------------------------------------------------
// Weight prep, per (l,type,head): bf16 B-operand mats ([col][k], k contig):
//   mat0 = WK^T, mat1 = WV^T,
//   mat2..4 = WQE[et] with Qe = x @ (WQ @ WE[et]^T)
// wq stored PADDED [32][33]: read wq[k*33+j] -> bank (k+j)&31, conflict-free.
// ---------------------------------------------------------------------------
__global__ __launch_bounds__(256) void wprep_kernel(
    const float* __restrict__ W_Q, const float* __restrict__ W_K,
    const float* __restrict__ W_V, const float* __restrict__ W_E,
    u16* __restrict__ wqkvb) {
  int b = blockIdx.x;
  int h = b & 7, tt = (b >> 3) & 3, l = b >> 5;
  __shared__ float wq[1056];         // 32 x 33 padded
  __shared__ float we[3][1024];
  int t = threadIdx.x;
  const float* WQp = W_Q + (((size_t)l * NTYPE + tt) * NHEAD + h) * 1024;
  for (int i = t; i < 1024; i += 256) wq[(i >> 5) * 33 + (i & 31)] = WQp[i];
  for (int et = 0; et < ETYPE; ++et) {
    const float* WEp = W_E + (((size_t)l * ETYPE + et) * NHEAD + h) * 1024;
    for (int i = t; i < 1024; i += 256) we[et][i] = WEp[i];
  }
  __syncthreads();
  const float* WKp = W_K + (((size_t)l * NTYPE + tt) * NHEAD + h) * 1024;
  const float* WVp = W_V + (((size_t)l * NTYPE + tt) * NHEAD + h) * 1024;
  u16* out = wqkvb + (size_t)b * 5120;
  for (int i = t; i < 1024; i += 256) {
    int col = i >> 5, k = i & 31;
    out[i] = f2bf(WKp[k * 32 + col]);
    out[1024 + i] = f2bf(WVp[k * 32 + col]);
#pragma unroll
    for (int et = 0; et < ETYPE; ++et) {
      float a = 0.f;
#pragma unroll
      for (int j = 0; j < 32; ++j) a += wq[k * 33 + j] * we[et][col * 32 + j];
      out[(2 + et) * 1024 + i] = f2bf(a);
    }
  }
}

// ---------------------------------------------------------------------------
// QKV via MFMA over type buckets: K,V stored fp8 e4m3, Qe[3] bf16.
// LDS layout for MFMA operands is [k-slot][row] per 16-row chunk so the
// b128 fragment reads are bank-conflict-free (reg-staged ds_write, so the
// scatter layout is free here).
// ---------------------------------------------------------------------------
__global__ __launch_bounds__(256) void qkv_mfma(
    const u16* __restrict__ xb, const int* __restrict__ tidx,
    const int* __restrict__ toff, const int* __restrict__ tile_off,
    const u16* __restrict__ wqkvb_l,
    u8* __restrict__ Kb8, u8* __restrict__ Vb8, u16* __restrict__ Qeb) {
  __shared__ u16 smem[10240];
  int bx = blockIdx.x, h = blockIdx.y;
  if (bx >= tile_off[NTYPE]) return;
  int ty = 0;
  while (bx >= tile_off[ty + 1]) ++ty;
  int lt = bx - tile_off[ty];
  int base = toff[ty] + lt * 64;
  int cnt = min(64, toff[ty + 1] - toff[ty] - lt * 64);
  int t = threadIdx.x;
  {
    // x tile 64 rows x 32 k, stored as [rgroup(4)][slot(4)][row16(16)] 16B units
    int row = ((t >> 6) << 4) | (t & 15);
    int q = (t >> 4) & 3;
    int node = tidx[base + min(row, cnt - 1)];
    *(uint4*)&smem[t * 8] =
        *(const uint4*)&xb[(size_t)node * 256 + h * 32 + q * 8];
  }
  // weights: 5 mats of 32 cols x 32 k; store as [mt][slot(4)][col(32)] 16B units
  const u16* wsrc = wqkvb_l + ((size_t)ty * NHEAD + h) * 5120;
  for (int dc = t; dc < 640; dc += 256) {
    int mt = dc >> 7, wi = dc & 127, slot = wi >> 5, colx = wi & 31;
    *(uint4*)&smem[2048 + dc * 8] = *(const uint4*)&wsrc[(mt * 128 + colx * 4 + slot) * 8];
  }
  __syncthreads();

  int lane = t & 63, w = t >> 6;
  int m = lane & 15, q = lane >> 4;
  bf16x8 af = *(const bf16x8*)&smem[w * 512 + q * 128 + m * 8];
  f32x4 acc[5][2];
#pragma unroll
  for (int mt = 0; mt < 5; ++mt)
#pragma unroll
    for (int c = 0; c < 2; ++c) {
      bf16x8 bf = *(const bf16x8*)&smem[2048 + mt * 1024 + q * 256 + (c * 16 + m) * 8];
      acc[mt][c] = __builtin_amdgcn_mfma_f32_16x16x32_bf16(af, bf, (f32x4){0.f, 0.f, 0.f, 0.f}, 0, 0, 0);
    }
  __syncthreads();
#pragma unroll
  for (int mt = 0; mt < 5; ++mt)
#pragma unroll
    for (int c = 0; c < 2; ++c)
#pragma unroll
      for (int r = 0; r < 4; ++r)
        smem[mt * 2048 + (w * 16 + q * 4 + r) * 32 + c * 16 + m] = f2bf(acc[mt][c][r]);
  __syncthreads();
  {
    int row = t >> 2, q4 = t & 3;
    if (row < cnt) {
      int node = tidx[base + row];
      {
        const u16* sp = &smem[row * 32 + q4 * 8];
        unsigned long long pk = 0;
#pragma unroll
        for (int j = 0; j < 8; ++j)
          pk |= (unsigned long long)f2fp8(bf2f(sp[j])) << (8 * j);
        *(unsigned long long*)&Kb8[(size_t)node * 256 + h * 32 + q4 * 8] = pk;
      }
      {
        const u16* sp = &smem[2048 + row * 32 + q4 * 8];
        unsigned long long pk = 0;
#pragma unroll
        for (int j = 0; j < 8; ++j)
          pk |= (unsigned long long)f2fp8(bf2f(sp[j])) << (8 * j);
        *(unsigned long long*)&Vb8[(size_t)node * 256 + h * 32 + q4 * 8] = pk;
      }
#pragma unroll
      for (int et = 0; et < ETYPE; ++et)
        *(uint4*)&Qeb[((size_t)node * ETYPE + et) * 256 + h * 32 + q4 * 8] =
            *(const uint4*)&smem[(2 + et) * 2048 + row * 32 + q4 * 8];
    }
  }
}

// ---------------------------------------------------------------------------
// FUSED score+softmax+aggregate, WAVE-PER-NODE (R7).
// R6 counters: VALUBusy 68%, HBM 21% -> VALU-bound. Two VALU cuts:
//  (1) HW packed fp8 decode (cvt_pk_f32_fp8): K+V decode 16 ops -> 4.
//      Decode is exact -> zero numerical risk.
//  (2) One wave owns a node: after the 8-lane dot reduce, e (and thus ssum)
//      is replicated per head's lanes -> NO cross-wave reduction needed.
//      Deletes sacc/sssum LDS, __syncthreads, final reduce, and the 4x
//      redundant Q preload. 20000 independent waves keep TLP ample.
// ---------------------------------------------------------------------------
__global__ __launch_bounds__(256) void agg_kernel(
    const int* __restrict__ off, const int* __restrict__ csr_src,
    const int* __restrict__ csr_et, const u16* __restrict__ Qeb,
    const u8* __restrict__ Kb8, const float* __restrict__ mu,
    const u8* __restrict__ Vb8, u16* __restrict__ aggb, int N) {
  int n = blockIdx.x * 4 + (threadIdx.x >> 6);
  if (n >= N) return;
  int l = threadIdx.x & 63;
  int d0 = l * 4;          // dims [d0, d0+4)
  int h = l >> 3;          // head of these dims

  // preload Q[dst=n] rows for the 3 edge types (bf16 -> f32), + scaled mu
  float4 q0, q1, q2;
  {
    const u16* qp = Qeb + (size_t)n * ETYPE * 256 + d0;
    ushort4 a = *(const ushort4*)(qp);
    ushort4 b = *(const ushort4*)(qp + 256);
    ushort4 c = *(const ushort4*)(qp + 512);
    q0 = make_float4(bf2f(a.x), bf2f(a.y), bf2f(a.z), bf2f(a.w));
    q1 = make_float4(bf2f(b.x), bf2f(b.y), bf2f(b.z), bf2f(b.w));
    q2 = make_float4(bf2f(c.x), bf2f(c.y), bf2f(c.z), bf2f(c.w));
  }
  const float sc = 0.17677669529663687f;
  float mu0 = sc * mu[h * ETYPE + 0];
  float mu1 = sc * mu[h * ETYPE + 1];
  float mu2 = sc * mu[h * ETYPE + 2];

  int s0 = off[n], s1 = off[n + 1];
  float a0 = 0.f, a1 = 0.f, a2 = 0.f, a3 = 0.f, ssum = 0.f;
  for (int k = s0; k < s1; ++k) {
    int sn = csr_src[k];
    int et = csr_et[k];
    unsigned k4 = *(const unsigned*)(Kb8 + (size_t)sn * 256 + d0);
    float4 kf = fp8x4_f32(k4);
    float4 qe = (et == 0) ? q0 : (et == 1) ? q1 : q2;   // wave-uniform select
    float mue = (et == 0) ? mu0 : (et == 1) ? mu1 : mu2;
    float p = kf.x * qe.x + kf.y * qe.y + kf.z * qe.z + kf.w * qe.w;
    p += __shfl_xor(p, 1, 64);
    p += __shfl_xor(p, 2, 64);
    p += __shfl_xor(p, 4, 64);   // full 32-dim dot, replicated in 8 head lanes
    float e = __expf(p * mue);
    unsigned v4 = *(const unsigned*)(Vb8 + (size_t)sn * 256 + d0);
    float4 vf = fp8x4_f32(v4);
    a0 += e * vf.x;
    a1 += e * vf.y;
    a2 += e * vf.z;
    a3 += e * vf.w;
    ssum += e;                   // identical across the head's 8 lanes
  }
  float inv = 1.f / (ssum + 1e-10f);
  ushort4 o = { f2bf(a0 * inv), f2bf(a1 * inv), f2bf(a2 * inv), f2bf(a3 * inv) };
  *(ushort4*)&aggb[(size_t)n * 256 + d0] = o;
}

// ---------------------------------------------------------------------------
// fp32 [K,Nc] -> bf16 transposed [Nc,K]
// ---------------------------------------------------------------------------
__global__ __launch_bounds__(256) void convT_kernel(const float* __restrict__ W,
                                                    u16* __restrict__ Wt, int K, int Nc) {
  __shared__ float tile[32][33];
  int bk = blockIdx.y * 32, bn = blockIdx.x * 32;
  const float* Wz = W + (size_t)blockIdx.z * K * Nc;
  u16* Wtz = Wt + (size_t)blockIdx.z * K * Nc;
  int tx = threadIdx.x & 31, ty = threadIdx.x >> 5;
  for (int r = ty; r < 32; r += 8)
    tile[r][tx] = Wz[(size_t)(bk + r) * Nc + bn + tx];
  __syncthreads();
  for (int r = ty; r < 32; r += 8)
    Wtz[(size_t)(bn + r) * K + bk + tx] = f2bf(tile[tx][r]);
}

// ---------------------------------------------------------------------------
// bf16 MFMA GEMM: C[M,Nc] = A[M,K] @ Bt[Nc,K]^T + bias -> bf16 out.
// BM=128, BN=128 for all gemms. GELU=1 adds fast-GELU to the epilogue.
// Proven structure (R0-R5): single-buffer lane-linear staging (both
// conflict-fix remaps measured slower; stage coalescing dominates), BK=64
// (half the vmcnt(0) drains), bijective XCD swizzle (L2 panel reuse).
// ---------------------------------------------------------------------------
template <int GELU, int BN>
__global__ __launch_bounds__(256) void gemm_mfma(
    const u16* __restrict__ A, const u16* __restrict__ Bt,
    const float* __restrict__ bias, u16* __restrict__ Cb,
    int M, int K, int Nc) {
  constexpr int MJ = BN / 32;
  __shared__ u16 As[128 * 64];       // 2 halves x 8 chunks x 64 lanes x 8 u16
  __shared__ u16 Bs[BN * 64];
  const int t = threadIdx.x;
  const int lane = t & 63;
  const int w = t >> 6;

  // bijective XCD-aware remap (8 XCDs, round-robin dispatch by linear id)
  const int nwg = gridDim.x * gridDim.y;
  const int lin = blockIdx.y * gridDim.x + blockIdx.x;
  const int qq = nwg >> 3, rr = nwg & 7;
  const int xcd = lin & 7, pos = lin >> 3;
  const int nl = (xcd < rr ? xcd * (qq + 1) : rr * (qq + 1) + (xcd - rr) * qq) + pos;
  const int row0 = (nl / gridDim.x) * 128;
  const int col0 = (nl % gridDim.x) * BN;

  const int wm = (w >> 1) * 64, wn = (w & 1) * (BN / 2);

  f32x4 acc[4][MJ] = {};
  const int sr = lane >> 2;        // stage row within 16-row chunk
  const int sk = (lane & 3) * 8;   // stage k-slot (lane-linear: coalesced)

  for (int k0 = 0; k0 < K; k0 += 64) {
#pragma unroll
    for (int half = 0; half < 2; ++half) {
#pragma unroll
      for (int c = 0; c < 2; ++c) {
        const int chunk = w * 2 + c;
        const int r = chunk * 16 + sr;
        int ra = row0 + r; if (ra >= M) ra = M - 1;
        GLDS16(A + (size_t)ra * K + k0 + half * 32 + sk,
               &As[((half * 8 + chunk) * 64 + lane) * 8]);
        if (BN == 128) {
          GLDS16(Bt + (size_t)(col0 + r) * K + k0 + half * 32 + sk,
                 &Bs[((half * 8 + chunk) * 64 + lane) * 8]);
        }
      }
      if (BN == 64) {
        const int r = w * 16 + sr;
        GLDS16(Bt + (size_t)(col0 + r) * K + k0 + half * 32 + sk,
               &Bs[((half * 4 + w) * 64 + lane) * 8]);
      }
    }
    __syncthreads();
    const int ko = (lane >> 4) * 8;
    const int lr = lane & 15;
#pragma unroll
    for (int half = 0; half < 2; ++half) {
      bf16x8 af[4], bfr[MJ];
      const int ab = half * 8 * 512;                       // A half offset (u16)
      const int bb = half * (BN == 128 ? 8 : 4) * 512;     // B half offset (u16)
#pragma unroll
      for (int i = 0; i < 4; ++i)
        af[i] = *(const bf16x8*)&As[ab + ((wm >> 4) + i) * 512 + lr * 32 + ko];
#pragma unroll
      for (int j = 0; j < MJ; ++j)
        bfr[j] = *(const bf16x8*)&Bs[bb + ((wn >> 4) + j) * 512 + lr * 32 + ko];
#pragma unroll
      for (int i = 0; i < 4; ++i)
#pragma unroll
        for (int j = 0; j < MJ; ++j)
          acc[i][j] = __builtin_amdgcn_mfma_f32_16x16x32_bf16(af[i], bfr[j], acc[i][j], 0, 0, 0);
    }
    __syncthreads();
  }

  const int lc = lane & 15;
  const int lrow = (lane >> 4) * 4;
  float bv[MJ];
#pragma unroll
  for (int j = 0; j < MJ; ++j) bv[j] = bias[col0 + wn + j * 16 + lc];
#pragma unroll
  for (int i = 0; i < 4; ++i) {
#pragma unroll
    for (int r = 0; r < 4; ++r) {
      int gr = row0 + wm + i * 16 + lrow + r;
      if (gr >= M) continue;
#pragma unroll
      for (int j = 0; j < MJ; ++j) {
        int gc = col0 + wn + j * 16 + lc;
        float v = acc[i][j][r] + bv[j];
        if (GELU) v = gelu_f(v);
        Cb[(size_t)gr * Nc + gc] = f2bf(v);
      }
    }
  }
}

// ---------------------------------------------------------------------------
// LayerNorm rows of 256: out = LN(xin + res) * g + b; res is bf16 (or null).
// Wave-per-row: lane holds float4 (64 lanes x 4 = 256), pure shfl_xor
// reductions — no LDS, no barriers. 4 rows/block, vectorized loads/stores.
// ---------------------------------------------------------------------------
__global__ __launch_bounds__(256) void ln_kernel(
    const float* __restrict__ xin, const u16* __restrict__ res,
    const float* __restrict__ g, const float* __restrict__ b,
    float* __restrict__ out, u16* __restrict__ outb, int N) {
  int row = blockIdx.x * 4 + (threadIdx.x >> 6);
  if (row >= N) return;
  int l = threadIdx.x & 63;
  size_t base = (size_t)row * 256 + l * 4;
  float4 r4 = *(const float4*)&xin[base];
  if (res) {
    ushort4 rb = *(const ushort4*)&res[base];
    r4.x += bf2f(rb.x); r4.y += bf2f(rb.y);
    r4.z += bf2f(rb.z); r4.w += bf2f(rb.w);
  }
  float s = r4.x + r4.y + r4.z + r4.w;
  for (int o = 32; o > 0; o >>= 1) s += __shfl_xor(s, o, 64);
  float m = s * (1.f / 256.f);
  float dx = r4.x - m, dy = r4.y - m, dz = r4.z - m, dw = r4.w - m;
  float s2 = dx * dx + dy * dy + dz * dz + dw * dw;
  for (int o = 32; o > 0; o >>= 1) s2 += __shfl_xor(s2, o, 64);
  float inv = rsqrtf(s2 * (1.f / 256.f) + 1e-5f);
  float4 g4 = *(const float4*)&g[l * 4];
  float4 b4 = *(const float4*)&b[l * 4];
  float4 o4 = { dx * inv * g4.x + b4.x, dy * inv * g4.y + b4.y,
                dz * inv * g4.z + b4.z, dw * inv * g4.w + b4.w };
  *(float4*)&out[base] = o4;
  if (outb) {
    ushort4 ob = { f2bf(o4.x), f2bf(o4.y), f2bf(o4.z), f2bf(o4.w) };
    *(ushort4*)&outb[base] = ob;
  }
}

// ---------------------------------------------------------------------------
extern "C" void kernel_launch(void* const* d_in, const int* in_sizes, int n_in,
                              void* d_out, int out_size, void* d_ws, size_t ws_size,
                              hipStream_t stream) {
  const float* x_in   = (const float*)d_in[0];
  const int*   ei     = (const int*)d_in[1];
  const int*   etype  = (const int*)d_in[2];
  const int*   ntype  = (const int*)d_in[3];
  const float* W_Q    = (const float*)d_in[4];
  const float* W_K    = (const float*)d_in[5];
  const float* W_V    = (const float*)d_in[6];
  const float* W_E    = (const float*)d_in[7];
  const float* mu     = (const float*)d_in[8];
  const float* Wo     = (const float*)d_in[9];
  const float* bo     = (const float*)d_in[10];
  const float* ln1g   = (const float*)d_in[11];
  const float* ln1b   = (const float*)d_in[12];
  const float* ln2g   = (const float*)d_in[13];
  const float* ln2b   = (const float*)d_in[14];
  const float* w1     = (const float*)d_in[15];
  const float* b1     = (const float*)d_in[16];
  const float* w2     = (const float*)d_in[17];
  const float* b2     = (const float*)d_in[18];
  const float* outg   = (const float*)d_in[19];
  const float* outb   = (const float*)d_in[20];

  const int N = in_sizes[0] / DMODEL;    // 20000
  const int E = in_sizes[1] / 2;         // 320000
  const int* src = ei;
  const int* dst = ei + E;

  const size_t NF = (size_t)N * DMODEL;
  const size_t EH = (size_t)E * NHEAD;

  // ---- workspace layout (scores slot retained but unused after fusion) ----
  float* f      = (float*)d_ws;
  float* xbuf   = f;                     // NF fp32 (residual master)
  float* scores = f + NF;                // EH fp32 (UNUSED after R6 fusion)
  u16*   fout   = (u16*)(f + NF + EH);   // NF bf16 (GEMM outputs)
  u16*   xb     = fout + NF;             // NF bf16
  u16*   Qeb    = xb + NF;               // 3NF bf16  } h1b aliases Qeb
  u16*   h1b    = Qeb;                   // alias (2NF used, FFN phase only)
  u16*   aggb   = Qeb + 3 * NF;          // NF bf16
  u8*    Kb8    = (u8*)(aggb + NF);      // NF bytes fp8
  u8*    Vb8    = Kb8 + NF;              // NF bytes fp8
  u16*   wqkvb  = (u16*)(Vb8 + NF);      // 96 * 5120
  u16*   Wot    = wqkvb + (size_t)NLAYER * NTYPE * NHEAD * 5120;
  u16*   w1t    = Wot + 3 * 65536;
  u16*   w2t    = w1t + 3 * 262144;
  int*   ip     = (int*)(w2t + 3 * 262144);
  int*   off    = ip;                    // N+1
  int*   csr_src= off + (N + 1);         // E
  int*   csr_dst= csr_src + E;           // E (slot retained, unused)
  int*   csr_et = csr_dst + E;           // E
  int*   cursor = csr_et + E;            // N
  int*   tidx   = cursor + N;            // N
  int*   toff   = tidx + N;              // NTYPE+1
  int*   tile_off = toff + (NTYPE + 1);  // NTYPE+1
  int*   tcnt   = tile_off + (NTYPE + 1);// NTYPE
  int*   tcur   = tcnt + NTYPE;          // NTYPE
  (void)scores; (void)csr_dst;

  // ---- CSR + type buckets (once) ----
  hipMemsetAsync(cursor, 0, (size_t)N * sizeof(int), stream);
  hipMemsetAsync(tcnt, 0, 2 * NTYPE * sizeof(int), stream);
  count_deg_kernel<<<(E + 255) / 256, 256, 0, stream>>>(dst, cursor, E);
  scan_kernel<<<1, 1024, 0, stream>>>(cursor, off, N);
  hipMemsetAsync(cursor, 0, (size_t)N * sizeof(int), stream);
  scatter_kernel<<<(E + 255) / 256, 256, 0, stream>>>(
      src, dst, etype, off, cursor, csr_src, csr_et, E);
  tcount_kernel<<<(N + 255) / 256, 256, 0, stream>>>(ntype, tcnt, N);
  tscan_kernel<<<1, 64, 0, stream>>>(tcnt, toff, tile_off);
  tscatter_kernel<<<(N + 255) / 256, 256, 0, stream>>>(ntype, toff, tcur, tidx, N);

  // ---- weight prep (once) ----
  wprep_kernel<<<NLAYER * NTYPE * NHEAD, 256, 0, stream>>>(W_Q, W_K, W_V, W_E, wqkvb);
  convT_kernel<<<dim3(DMODEL / 32, DMODEL / 32, NLAYER), 256, 0, stream>>>(
      Wo, Wot, DMODEL, DMODEL);
  convT_kernel<<<dim3(4 * DMODEL / 32, DMODEL / 32, NLAYER), 256, 0, stream>>>(
      w1, w1t, DMODEL, 4 * DMODEL);
  convT_kernel<<<dim3(DMODEL / 32, 4 * DMODEL / 32, NLAYER), 256, 0, stream>>>(
      w2, w2t, 4 * DMODEL, DMODEL);

  // ---- x working copies (fused copy + bf16 convert) ----
  xconv_kernel<<<(int)((NF / 4 + 255) / 256), 256, 0, stream>>>(
      x_in, xbuf, xb, (int)(NF / 4));

  const int gm = (N + 127) / 128;
  const int lng = (N + 3) / 4;
  const int qtiles = (N + 63) / 64 + NTYPE;
  for (int l = 0; l < NLAYER; ++l) {
    qkv_mfma<<<dim3(qtiles, NHEAD), 256, 0, stream>>>(
        xb, tidx, toff, tile_off,
        wqkvb + (size_t)l * NTYPE * NHEAD * 5120, Kb8, Vb8, Qeb);
    agg_kernel<<<lng, 256, 0, stream>>>(off, csr_src, csr_et, Qeb, Kb8,
        mu + (size_t)l * NHEAD * ETYPE, Vb8, aggb, N);

    gemm_mfma<0, 128><<<dim3(DMODEL / 128, gm), 256, 0, stream>>>(
        aggb, Wot + (size_t)l * 65536, bo + (size_t)l * DMODEL,
        fout, N, DMODEL, DMODEL);
    ln_kernel<<<lng, 256, 0, stream>>>(xbuf, fout,
        ln1g + (size_t)l * DMODEL, ln1b + (size_t)l * DMODEL, xbuf, xb, N);
    gemm_mfma<1, 128><<<dim3(4 * DMODEL / 128, gm), 256, 0, stream>>>(
        xb, w1t + (size_t)l * 262144, b1 + (size_t)l * 4 * DMODEL,
        h1b, N, DMODEL, 4 * DMODEL);
    gemm_mfma<0, 128><<<dim3(DMODEL / 128, gm), 256, 0, stream>>>(
        h1b, w2t + (size_t)l * 262144, b2 + (size_t)l * DMODEL,
        fout, N, 4 * DMODEL, DMODEL);
    ln_kernel<<<lng, 256, 0, stream>>>(xbuf, fout,
        ln2g + (size_t)l * DMODEL, ln2b + (size_t)l * DMODEL, xbuf, xb, N);
  }

  ln_kernel<<<lng, 256, 0, stream>>>(xbuf, nullptr, outg, outb, (float*)d_out, nullptr, N);
}

// Round 8
// 667.708 us; speedup vs baseline: 1.3345x; 1.0489x over previous
//
#include <hip/hip_runtime.h>
#include <hip/hip_fp8.h>
#include <math.h>

#define HDIM 32
#define NHEAD 8
#define DMODEL 256
#define NTYPE 4
#define ETYPE 3
#define NLAYER 3

typedef unsigned short u16;
typedef unsigned char u8;
typedef __bf16 bf16x8 __attribute__((ext_vector_type(8)));
typedef float f32x4 __attribute__((ext_vector_type(4)));
typedef float f32x2 __attribute__((ext_vector_type(2)));

__device__ __forceinline__ u16 f2bf(float f) {
  union { float f; unsigned u; } v; v.f = f;
  unsigned r = v.u + 0x7FFF + ((v.u >> 16) & 1);
  return (u16)(r >> 16);
}
__device__ __forceinline__ float bf2f(u16 b) {
  union { unsigned u; float f; } v; v.u = (unsigned)b << 16; return v.f;
}
__device__ __forceinline__ u8 f2fp8(float v) {
  __hip_fp8_e4m3 t(v); return (u8)t.__x;
}
__device__ __forceinline__ float fp82f(unsigned b) {
  __hip_fp8_e4m3 t; t.__x = (__hip_fp8_storage_t)b; return (float)t;
}
// HW packed fp8(e4m3, OCP on gfx950) -> f32 decode: 4 bytes in 2 instructions.
__device__ __forceinline__ float4 fp8x4_f32(unsigned v) {
  f32x2 lo = __builtin_amdgcn_cvt_pk_f32_fp8((int)v, false);
  f32x2 hi = __builtin_amdgcn_cvt_pk_f32_fp8((int)v, true);
  return make_float4(lo[0], lo[1], hi[0], hi[1]);
}

// fast GELU (tanh form)
__device__ __forceinline__ float gelu_f(float v) {
  float u = 0.7978845608028654f * v * (1.f + 0.044715f * v * v);
  float e = __expf(-2.f * fabsf(u));
  float th = (1.f - e) / (1.f + e);
  th = copysignf(th, u);
  return 0.5f * v * (1.f + th);
}

#define GLDS16(g, l)                                              \
  __builtin_amdgcn_global_load_lds(                               \
      (const __attribute__((address_space(1))) void*)(g),         \
      (__attribute__((address_space(3))) void*)(l), 16, 0, 0)

// ---------------------------------------------------------------------------
// CSR build (dst-sorted edge VALUES in position order)
// ---------------------------------------------------------------------------
__global__ void count_deg_kernel(const int* __restrict__ dst, int* __restrict__ deg, int E) {
  int tid = blockIdx.x * 256 + threadIdx.x;
  if (tid < E) atomicAdd(&deg[dst[tid]], 1);
}

__global__ __launch_bounds__(1024) void scan_kernel(const int* __restrict__ deg,
                                                    int* __restrict__ off, int n) {
  __shared__ int part[1024];
  int t = threadIdx.x;
  int chunk = (n + 1023) >> 10;
  int base = t * chunk;
  int s = 0;
  for (int i = 0; i < chunk; ++i) {
    int idx = base + i;
    if (idx < n) s += deg[idx];
  }
  part[t] = s;
  __syncthreads();
  for (int o = 1; o < 1024; o <<= 1) {
    int v = (t >= o) ? part[t - o] : 0;
    __syncthreads();
    part[t] += v;
    __syncthreads();
  }
  int run = part[t] - s;
  for (int i = 0; i < chunk; ++i) {
    int idx = base + i;
    if (idx < n) { off[idx] = run; run += deg[idx]; }
  }
  if (t == 1023) off[n] = part[1023];
}

__global__ void scatter_kernel(const int* __restrict__ src, const int* __restrict__ dst,
                               const int* __restrict__ etype,
                               const int* __restrict__ off, int* __restrict__ cursor,
                               int* __restrict__ csr_src,
                               int* __restrict__ csr_et, int E) {
  int tid = blockIdx.x * 256 + threadIdx.x;
  if (tid < E) {
    int d = dst[tid];
    int p = atomicAdd(&cursor[d], 1);
    int pos = off[d] + p;
    csr_src[pos] = src[tid];
    csr_et[pos] = etype[tid];
  }
}

// ---------------------------------------------------------------------------
// Node-type buckets — hierarchical to avoid same-address atomic contention
// ---------------------------------------------------------------------------
__global__ void tcount_kernel(const int* __restrict__ nt, int* __restrict__ tcnt, int N) {
  __shared__ int h[NTYPE];
  int t = threadIdx.x;
  if (t < NTYPE) h[t] = 0;
  __syncthreads();
  int tid = blockIdx.x * 256 + t;
  if (tid < N) atomicAdd(&h[nt[tid]], 1);
  __syncthreads();
  if (t < NTYPE && h[t] > 0) atomicAdd(&tcnt[t], h[t]);
}

__global__ void tscan_kernel(const int* __restrict__ tcnt, int* __restrict__ toff,
                             int* __restrict__ tile_off) {
  if (threadIdx.x == 0 && blockIdx.x == 0) {
    int o = 0, to = 0;
    for (int t = 0; t < NTYPE; ++t) {
      toff[t] = o; tile_off[t] = to;
      o += tcnt[t]; to += (tcnt[t] + 63) >> 6;
    }
    toff[NTYPE] = o; tile_off[NTYPE] = to;
  }
}

__global__ void tscatter_kernel(const int* __restrict__ nt, const int* __restrict__ toff,
                                int* __restrict__ tcur, int* __restrict__ tidx, int N) {
  int tid = blockIdx.x * 256 + threadIdx.x;
  int lane = threadIdx.x & 63;
  int ty = (tid < N) ? nt[tid] : -1;
  unsigned long long lt_mask = (lane == 63) ? 0x7FFFFFFFFFFFFFFFull
                                            : ((1ull << lane) - 1);
#pragma unroll
  for (int t4 = 0; t4 < NTYPE; ++t4) {
    unsigned long long mask = __ballot(ty == t4);
    if (mask == 0) continue;
    int first = __builtin_ctzll(mask);
    int cnt = __popcll(mask);
    int base = 0;
    if (lane == first) base = atomicAdd(&tcur[t4], cnt);
    base = __shfl(base, first, 64);
    if (ty == t4) {
      int rank = __popcll(mask & lt_mask);
      tidx[toff[t4] + base + rank] = tid;
    }
  }
}

// ---------------------------------------------------------------------------
// x fp32 -> {fp32 residual master copy, bf16 mirror} in one pass
// ---------------------------------------------------------------------------
__global__ void xconv_kernel(const float* __restrict__ x, float* __restrict__ xbuf,
                             u16* __restrict__ xb, int n4) {
  int i = blockIdx.x * 256 + threadIdx.x;
  if (i < n4) {
    float4 v = ((const float4*)x)[i];
    ((float4*)xbuf)[i] = v;
    ushort4 o = { f2bf(v.x), f2bf(v.y), f2bf(v.z), f2bf(v.w) };
    ((ushort4*)xb)[i] = o;
  }
}

// ---------------------------------------------------------------------------
// Weight prep, per (l,type,head): bf16 B-operand mats ([col][k], k contig):
//   mat0 = WK^T, mat1 = WV^T,
//   mat2..4 = WQE[et] with Qe = x @ (WQ @ WE[et]^T)
// wq stored PADDED [32][33]: read wq[k*33+j] -> bank (k+j)&31, conflict-free.
// ---------------------------------------------------------------------------
__global__ __launch_bounds__(256) void wprep_kernel(
    const float* __restrict__ W_Q, const float* __restrict__ W_K,
    const float* __restrict__ W_V, const float* __restrict__ W_E,
    u16* __restrict__ wqkvb) {
  int b = blockIdx.x;
  int h = b & 7, tt = (b >> 3) & 3, l = b >> 5;
  __shared__ float wq[1056];         // 32 x 33 padded
  __shared__ float we[3][1024];
  int t = threadIdx.x;
  const float* WQp = W_Q + (((size_t)l * NTYPE + tt) * NHEAD + h) * 1024;
  for (int i = t; i < 1024; i += 256) wq[(i >> 5) * 33 + (i & 31)] = WQp[i];
  for (int et = 0; et < ETYPE; ++et) {
    const float* WEp = W_E + (((size_t)l * ETYPE + et) * NHEAD + h) * 1024;
    for (int i = t; i < 1024; i += 256) we[et][i] = WEp[i];
  }
  __syncthreads();
  const float* WKp = W_K + (((size_t)l * NTYPE + tt) * NHEAD + h) * 1024;
  const float* WVp = W_V + (((size_t)l * NTYPE + tt) * NHEAD + h) * 1024;
  u16* out = wqkvb + (size_t)b * 5120;
  for (int i = t; i < 1024; i += 256) {
    int col = i >> 5, k = i & 31;
    out[i] = f2bf(WKp[k * 32 + col]);
    out[1024 + i] = f2bf(WVp[k * 32 + col]);
#pragma unroll
    for (int et = 0; et < ETYPE; ++et) {
      float a = 0.f;
#pragma unroll
      for (int j = 0; j < 32; ++j) a += wq[k * 33 + j] * we[et][col * 32 + j];
      out[(2 + et) * 1024 + i] = f2bf(a);
    }
  }
}

// ---------------------------------------------------------------------------
// QKV via MFMA over type buckets: K,V stored fp8 e4m3 INTERLEAVED in one
// [N][512] table (K bytes 0-255, V bytes 256-511) so agg's two per-edge
// gathers hit one node row. Qe[3] bf16.
// ---------------------------------------------------------------------------
__global__ __launch_bounds__(256) void qkv_mfma(
    const u16* __restrict__ xb, const int* __restrict__ tidx,
    const int* __restrict__ toff, const int* __restrict__ tile_off,
    const u16* __restrict__ wqkvb_l,
    u8* __restrict__ KVb8, u16* __restrict__ Qeb) {
  __shared__ u16 smem[10240];
  int bx = blockIdx.x, h = blockIdx.y;
  if (bx >= tile_off[NTYPE]) return;
  int ty = 0;
  while (bx >= tile_off[ty + 1]) ++ty;
  int lt = bx - tile_off[ty];
  int base = toff[ty] + lt * 64;
  int cnt = min(64, toff[ty + 1] - toff[ty] - lt * 64);
  int t = threadIdx.x;
  {
    // x tile 64 rows x 32 k, stored as [rgroup(4)][slot(4)][row16(16)] 16B units
    int row = ((t >> 6) << 4) | (t & 15);
    int q = (t >> 4) & 3;
    int node = tidx[base + min(row, cnt - 1)];
    *(uint4*)&smem[t * 8] =
        *(const uint4*)&xb[(size_t)node * 256 + h * 32 + q * 8];
  }
  // weights: 5 mats of 32 cols x 32 k; store as [mt][slot(4)][col(32)] 16B units
  const u16* wsrc = wqkvb_l + ((size_t)ty * NHEAD + h) * 5120;
  for (int dc = t; dc < 640; dc += 256) {
    int mt = dc >> 7, wi = dc & 127, slot = wi >> 5, colx = wi & 31;
    *(uint4*)&smem[2048 + dc * 8] = *(const uint4*)&wsrc[(mt * 128 + colx * 4 + slot) * 8];
  }
  __syncthreads();

  int lane = t & 63, w = t >> 6;
  int m = lane & 15, q = lane >> 4;
  bf16x8 af = *(const bf16x8*)&smem[w * 512 + q * 128 + m * 8];
  f32x4 acc[5][2];
#pragma unroll
  for (int mt = 0; mt < 5; ++mt)
#pragma unroll
    for (int c = 0; c < 2; ++c) {
      bf16x8 bf = *(const bf16x8*)&smem[2048 + mt * 1024 + q * 256 + (c * 16 + m) * 8];
      acc[mt][c] = __builtin_amdgcn_mfma_f32_16x16x32_bf16(af, bf, (f32x4){0.f, 0.f, 0.f, 0.f}, 0, 0, 0);
    }
  __syncthreads();
#pragma unroll
  for (int mt = 0; mt < 5; ++mt)
#pragma unroll
    for (int c = 0; c < 2; ++c)
#pragma unroll
      for (int r = 0; r < 4; ++r)
        smem[mt * 2048 + (w * 16 + q * 4 + r) * 32 + c * 16 + m] = f2bf(acc[mt][c][r]);
  __syncthreads();
  {
    int row = t >> 2, q4 = t & 3;
    if (row < cnt) {
      int node = tidx[base + row];
      {
        const u16* sp = &smem[row * 32 + q4 * 8];
        unsigned long long pk = 0;
#pragma unroll
        for (int j = 0; j < 8; ++j)
          pk |= (unsigned long long)f2fp8(bf2f(sp[j])) << (8 * j);
        *(unsigned long long*)&KVb8[(size_t)node * 512 + h * 32 + q4 * 8] = pk;
      }
      {
        const u16* sp = &smem[2048 + row * 32 + q4 * 8];
        unsigned long long pk = 0;
#pragma unroll
        for (int j = 0; j < 8; ++j)
          pk |= (unsigned long long)f2fp8(bf2f(sp[j])) << (8 * j);
        *(unsigned long long*)&KVb8[(size_t)node * 512 + 256 + h * 32 + q4 * 8] = pk;
      }
#pragma unroll
      for (int et = 0; et < ETYPE; ++et)
        *(uint4*)&Qeb[((size_t)node * ETYPE + et) * 256 + h * 32 + q4 * 8] =
            *(const uint4*)&smem[(2 + et) * 2048 + row * 32 + q4 * 8];
    }
  }
}

// ---------------------------------------------------------------------------
// FUSED score+softmax+aggregate, WAVE-PER-NODE, 4-WIDE EDGE BATCHES (R8).
// R7 counters (VALUBusy 68->44% but dur flat) proved the kernel is
// LATENCY-bound on the gather chain, not VALU-bound. Fix: issue all 8
// gathers (4 K + 4 V) of a 4-edge batch before any compute -> ~1 exposed
// gather latency per 4 edges instead of per edge. Tail edges: index clamped
// to a valid row, e masked to 0 (NOT mue=0 — exp(0)=1 would corrupt sums).
// K/V interleaved per node row (512B) for gather locality.
// ---------------------------------------------------------------------------
__global__ __launch_bounds__(256) void agg_kernel(
    const int* __restrict__ off, const int* __restrict__ csr_src,
    const int* __restrict__ csr_et, const u16* __restrict__ Qeb,
    const u8* __restrict__ KVb8, const float* __restrict__ mu,
    u16* __restrict__ aggb, int N) {
  int n = blockIdx.x * 4 + (threadIdx.x >> 6);
  if (n >= N) return;
  int l = threadIdx.x & 63;
  int d0 = l * 4;          // dims [d0, d0+4)
  int h = l >> 3;          // head of these dims

  // preload Q[dst=n] rows for the 3 edge types (bf16 -> f32), + scaled mu
  float4 q0, q1, q2;
  {
    const u16* qp = Qeb + (size_t)n * ETYPE * 256 + d0;
    ushort4 a = *(const ushort4*)(qp);
    ushort4 b = *(const ushort4*)(qp + 256);
    ushort4 c = *(const ushort4*)(qp + 512);
    q0 = make_float4(bf2f(a.x), bf2f(a.y), bf2f(a.z), bf2f(a.w));
    q1 = make_float4(bf2f(b.x), bf2f(b.y), bf2f(b.z), bf2f(b.w));
    q2 = make_float4(bf2f(c.x), bf2f(c.y), bf2f(c.z), bf2f(c.w));
  }
  const float sc = 0.17677669529663687f;
  float mu0 = sc * mu[h * ETYPE + 0];
  float mu1 = sc * mu[h * ETYPE + 1];
  float mu2 = sc * mu[h * ETYPE + 2];

  int s0 = off[n], s1 = off[n + 1];
  float a0 = 0.f, a1 = 0.f, a2 = 0.f, a3 = 0.f, ssum = 0.f;
  for (int k = s0; k < s1; k += 4) {
    unsigned ck[4], cv[4];
    float4 qq[4];
    float mm[4], msk[4];
    // ---- issue phase: 8 independent gathers in flight ----
#pragma unroll
    for (int i = 0; i < 4; ++i) {
      int idx = k + i;
      bool ok = idx < s1;
      int idc = ok ? idx : s1 - 1;       // s1 > s0 here, so valid
      int sn = csr_src[idc];
      int et = csr_et[idc];
      const u8* kvp = KVb8 + (size_t)sn * 512 + d0;
      ck[i] = *(const unsigned*)kvp;
      cv[i] = *(const unsigned*)(kvp + 256);
      qq[i] = (et == 0) ? q0 : (et == 1) ? q1 : q2;     // wave-uniform select
      mm[i] = (et == 0) ? mu0 : (et == 1) ? mu1 : mu2;
      msk[i] = ok ? 1.f : 0.f;
    }
    // ---- compute phase ----
#pragma unroll
    for (int i = 0; i < 4; ++i) {
      float4 kf = fp8x4_f32(ck[i]);
      float p = kf.x * qq[i].x + kf.y * qq[i].y + kf.z * qq[i].z + kf.w * qq[i].w;
      p += __shfl_xor(p, 1, 64);
      p += __shfl_xor(p, 2, 64);
      p += __shfl_xor(p, 4, 64);   // full 32-dim dot, replicated in 8 head lanes
      float e = msk[i] * __expf(p * mm[i]);
      float4 vf = fp8x4_f32(cv[i]);
      a0 += e * vf.x;
      a1 += e * vf.y;
      a2 += e * vf.z;
      a3 += e * vf.w;
      ssum += e;                   // identical across the head's 8 lanes
    }
  }
  float inv = 1.f / (ssum + 1e-10f);
  ushort4 o = { f2bf(a0 * inv), f2bf(a1 * inv), f2bf(a2 * inv), f2bf(a3 * inv) };
  *(ushort4*)&aggb[(size_t)n * 256 + d0] = o;
}

// ---------------------------------------------------------------------------
// fp32 [K,Nc] -> bf16 transposed [Nc,K]
// ---------------------------------------------------------------------------
__global__ __launch_bounds__(256) void convT_kernel(const float* __restrict__ W,
                                                    u16* __restrict__ Wt, int K, int Nc) {
  __shared__ float tile[32][33];
  int bk = blockIdx.y * 32, bn = blockIdx.x * 32;
  const float* Wz = W + (size_t)blockIdx.z * K * Nc;
  u16* Wtz = Wt + (size_t)blockIdx.z * K * Nc;
  int tx = threadIdx.x & 31, ty = threadIdx.x >> 5;
  for (int r = ty; r < 32; r += 8)
    tile[r][tx] = Wz[(size_t)(bk + r) * Nc + bn + tx];
  __syncthreads();
  for (int r = ty; r < 32; r += 8)
    Wtz[(size_t)(bn + r) * K + bk + tx] = f2bf(tile[tx][r]);
}

// ---------------------------------------------------------------------------
// bf16 MFMA GEMM: C[M,Nc] = A[M,K] @ Bt[Nc,K]^T + bias -> bf16 out.
// BM=128, BN=128 for all gemms. GELU=1 adds fast-GELU to the epilogue.
// Proven structure (R0-R5): single-buffer lane-linear staging, BK=64,
// bijective XCD swizzle (L2 panel reuse).
// ---------------------------------------------------------------------------
template <int GELU, int BN>
__global__ __launch_bounds__(256) void gemm_mfma(
    const u16* __restrict__ A, const u16* __restrict__ Bt,
    const float* __restrict__ bias, u16* __restrict__ Cb,
    int M, int K, int Nc) {
  constexpr int MJ = BN / 32;
  __shared__ u16 As[128 * 64];       // 2 halves x 8 chunks x 64 lanes x 8 u16
  __shared__ u16 Bs[BN * 64];
  const int t = threadIdx.x;
  const int lane = t & 63;
  const int w = t >> 6;

  // bijective XCD-aware remap (8 XCDs, round-robin dispatch by linear id)
  const int nwg = gridDim.x * gridDim.y;
  const int lin = blockIdx.y * gridDim.x + blockIdx.x;
  const int qq = nwg >> 3, rr = nwg & 7;
  const int xcd = lin & 7, pos = lin >> 3;
  const int nl = (xcd < rr ? xcd * (qq + 1) : rr * (qq + 1) + (xcd - rr) * qq) + pos;
  const int row0 = (nl / gridDim.x) * 128;
  const int col0 = (nl % gridDim.x) * BN;

  const int wm = (w >> 1) * 64, wn = (w & 1) * (BN / 2);

  f32x4 acc[4][MJ] = {};
  const int sr = lane >> 2;        // stage row within 16-row chunk
  const int sk = (lane & 3) * 8;   // stage k-slot (lane-linear: coalesced)

  for (int k0 = 0; k0 < K; k0 += 64) {
#pragma unroll
    for (int half = 0; half < 2; ++half) {
#pragma unroll
      for (int c = 0; c < 2; ++c) {
        const int chunk = w * 2 + c;
        const int r = chunk * 16 + sr;
        int ra = row0 + r; if (ra >= M) ra = M - 1;
        GLDS16(A + (size_t)ra * K + k0 + half * 32 + sk,
               &As[((half * 8 + chunk) * 64 + lane) * 8]);
        if (BN == 128) {
          GLDS16(Bt + (size_t)(col0 + r) * K + k0 + half * 32 + sk,
                 &Bs[((half * 8 + chunk) * 64 + lane) * 8]);
        }
      }
      if (BN == 64) {
        const int r = w * 16 + sr;
        GLDS16(Bt + (size_t)(col0 + r) * K + k0 + half * 32 + sk,
               &Bs[((half * 4 + w) * 64 + lane) * 8]);
      }
    }
    __syncthreads();
    const int ko = (lane >> 4) * 8;
    const int lr = lane & 15;
#pragma unroll
    for (int half = 0; half < 2; ++half) {
      bf16x8 af[4], bfr[MJ];
      const int ab = half * 8 * 512;                       // A half offset (u16)
      const int bb = half * (BN == 128 ? 8 : 4) * 512;     // B half offset (u16)
#pragma unroll
      for (int i = 0; i < 4; ++i)
        af[i] = *(const bf16x8*)&As[ab + ((wm >> 4) + i) * 512 + lr * 32 + ko];
#pragma unroll
      for (int j = 0; j < MJ; ++j)
        bfr[j] = *(const bf16x8*)&Bs[bb + ((wn >> 4) + j) * 512 + lr * 32 + ko];
#pragma unroll
      for (int i = 0; i < 4; ++i)
#pragma unroll
        for (int j = 0; j < MJ; ++j)
          acc[i][j] = __builtin_amdgcn_mfma_f32_16x16x32_bf16(af[i], bfr[j], acc[i][j], 0, 0, 0);
    }
    __syncthreads();
  }

  const int lc = lane & 15;
  const int lrow = (lane >> 4) * 4;
  float bv[MJ];
#pragma unroll
  for (int j = 0; j < MJ; ++j) bv[j] = bias[col0 + wn + j * 16 + lc];
#pragma unroll
  for (int i = 0; i < 4; ++i) {
#pragma unroll
    for (int r = 0; r < 4; ++r) {
      int gr = row0 + wm + i * 16 + lrow + r;
      if (gr >= M) continue;
#pragma unroll
      for (int j = 0; j < MJ; ++j) {
        int gc = col0 + wn + j * 16 + lc;
        float v = acc[i][j][r] + bv[j];
        if (GELU) v = gelu_f(v);
        Cb[(size_t)gr * Nc + gc] = f2bf(v);
      }
    }
  }
}

// ---------------------------------------------------------------------------
// LayerNorm rows of 256: out = LN(xin + res) * g + b; res is bf16 (or null).
// Wave-per-row: lane holds float4 (64 lanes x 4 = 256), pure shfl_xor
// reductions — no LDS, no barriers. 4 rows/block, vectorized loads/stores.
// ---------------------------------------------------------------------------
__global__ __launch_bounds__(256) void ln_kernel(
    const float* __restrict__ xin, const u16* __restrict__ res,
    const float* __restrict__ g, const float* __restrict__ b,
    float* __restrict__ out, u16* __restrict__ outb, int N) {
  int row = blockIdx.x * 4 + (threadIdx.x >> 6);
  if (row >= N) return;
  int l = threadIdx.x & 63;
  size_t base = (size_t)row * 256 + l * 4;
  float4 r4 = *(const float4*)&xin[base];
  if (res) {
    ushort4 rb = *(const ushort4*)&res[base];
    r4.x += bf2f(rb.x); r4.y += bf2f(rb.y);
    r4.z += bf2f(rb.z); r4.w += bf2f(rb.w);
  }
  float s = r4.x + r4.y + r4.z + r4.w;
  for (int o = 32; o > 0; o >>= 1) s += __shfl_xor(s, o, 64);
  float m = s * (1.f / 256.f);
  float dx = r4.x - m, dy = r4.y - m, dz = r4.z - m, dw = r4.w - m;
  float s2 = dx * dx + dy * dy + dz * dz + dw * dw;
  for (int o = 32; o > 0; o >>= 1) s2 += __shfl_xor(s2, o, 64);
  float inv = rsqrtf(s2 * (1.f / 256.f) + 1e-5f);
  float4 g4 = *(const float4*)&g[l * 4];
  float4 b4 = *(const float4*)&b[l * 4];
  float4 o4 = { dx * inv * g4.x + b4.x, dy * inv * g4.y + b4.y,
                dz * inv * g4.z + b4.z, dw * inv * g4.w + b4.w };
  *(float4*)&out[base] = o4;
  if (outb) {
    ushort4 ob = { f2bf(o4.x), f2bf(o4.y), f2bf(o4.z), f2bf(o4.w) };
    *(ushort4*)&outb[base] = ob;
  }
}

// ---------------------------------------------------------------------------
extern "C" void kernel_launch(void* const* d_in, const int* in_sizes, int n_in,
                              void* d_out, int out_size, void* d_ws, size_t ws_size,
                              hipStream_t stream) {
  const float* x_in   = (const float*)d_in[0];
  const int*   ei     = (const int*)d_in[1];
  const int*   etype  = (const int*)d_in[2];
  const int*   ntype  = (const int*)d_in[3];
  const float* W_Q    = (const float*)d_in[4];
  const float* W_K    = (const float*)d_in[5];
  const float* W_V    = (const float*)d_in[6];
  const float* W_E    = (const float*)d_in[7];
  const float* mu     = (const float*)d_in[8];
  const float* Wo     = (const float*)d_in[9];
  const float* bo     = (const float*)d_in[10];
  const float* ln1g   = (const float*)d_in[11];
  const float* ln1b   = (const float*)d_in[12];
  const float* ln2g   = (const float*)d_in[13];
  const float* ln2b   = (const float*)d_in[14];
  const float* w1     = (const float*)d_in[15];
  const float* b1     = (const float*)d_in[16];
  const float* w2     = (const float*)d_in[17];
  const float* b2     = (const float*)d_in[18];
  const float* outg   = (const float*)d_in[19];
  const float* outb   = (const float*)d_in[20];

  const int N = in_sizes[0] / DMODEL;    // 20000
  const int E = in_sizes[1] / 2;         // 320000
  const int* src = ei;
  const int* dst = ei + E;

  const size_t NF = (size_t)N * DMODEL;
  const size_t EH = (size_t)E * NHEAD;

  // ---- workspace layout ----
  float* f      = (float*)d_ws;
  float* xbuf   = f;                     // NF fp32 (residual master)
  float* scores = f + NF;                // EH fp32 (UNUSED after R6 fusion)
  u16*   fout   = (u16*)(f + NF + EH);   // NF bf16 (GEMM outputs)
  u16*   xb     = fout + NF;             // NF bf16
  u16*   Qeb    = xb + NF;               // 3NF bf16  } h1b aliases Qeb
  u16*   h1b    = Qeb;                   // alias (2NF used, FFN phase only)
  u16*   aggb   = Qeb + 3 * NF;          // NF bf16
  u8*    KVb8   = (u8*)(aggb + NF);      // 2NF bytes fp8 (K/V interleaved [N][512])
  u16*   wqkvb  = (u16*)(KVb8 + 2 * NF); // 96 * 5120
  u16*   Wot    = wqkvb + (size_t)NLAYER * NTYPE * NHEAD * 5120;
  u16*   w1t    = Wot + 3 * 65536;
  u16*   w2t    = w1t + 3 * 262144;
  int*   ip     = (int*)(w2t + 3 * 262144);
  int*   off    = ip;                    // N+1
  int*   csr_src= off + (N + 1);         // E
  int*   csr_dst= csr_src + E;           // E (slot retained, unused)
  int*   csr_et = csr_dst + E;           // E
  int*   cursor = csr_et + E;            // N
  int*   tidx   = cursor + N;            // N
  int*   toff   = tidx + N;              // NTYPE+1
  int*   tile_off = toff + (NTYPE + 1);  // NTYPE+1
  int*   tcnt   = tile_off + (NTYPE + 1);// NTYPE
  int*   tcur   = tcnt + NTYPE;          // NTYPE
  (void)scores; (void)csr_dst;

  // ---- CSR + type buckets (once) ----
  hipMemsetAsync(cursor, 0, (size_t)N * sizeof(int), stream);
  hipMemsetAsync(tcnt, 0, 2 * NTYPE * sizeof(int), stream);
  count_deg_kernel<<<(E + 255) / 256, 256, 0, stream>>>(dst, cursor, E);
  scan_kernel<<<1, 1024, 0, stream>>>(cursor, off, N);
  hipMemsetAsync(cursor, 0, (size_t)N * sizeof(int), stream);
  scatter_kernel<<<(E + 255) / 256, 256, 0, stream>>>(
      src, dst, etype, off, cursor, csr_src, csr_et, E);
  tcount_kernel<<<(N + 255) / 256, 256, 0, stream>>>(ntype, tcnt, N);
  tscan_kernel<<<1, 64, 0, stream>>>(tcnt, toff, tile_off);
  tscatter_kernel<<<(N + 255) / 256, 256, 0, stream>>>(ntype, toff, tcur, tidx, N);

  // ---- weight prep (once) ----
  wprep_kernel<<<NLAYER * NTYPE * NHEAD, 256, 0, stream>>>(W_Q, W_K, W_V, W_E, wqkvb);
  convT_kernel<<<dim3(DMODEL / 32, DMODEL / 32, NLAYER), 256, 0, stream>>>(
      Wo, Wot, DMODEL, DMODEL);
  convT_kernel<<<dim3(4 * DMODEL / 32, DMODEL / 32, NLAYER), 256, 0, stream>>>(
      w1, w1t, DMODEL, 4 * DMODEL);
  convT_kernel<<<dim3(DMODEL / 32, 4 * DMODEL / 32, NLAYER), 256, 0, stream>>>(
      w2, w2t, 4 * DMODEL, DMODEL);

  // ---- x working copies (fused copy + bf16 convert) ----
  xconv_kernel<<<(int)((NF / 4 + 255) / 256), 256, 0, stream>>>(
      x_in, xbuf, xb, (int)(NF / 4));

  const int gm = (N + 127) / 128;
  const int lng = (N + 3) / 4;
  const int qtiles = (N + 63) / 64 + NTYPE;
  for (int l = 0; l < NLAYER; ++l) {
    qkv_mfma<<<dim3(qtiles, NHEAD), 256, 0, stream>>>(
        xb, tidx, toff, tile_off,
        wqkvb + (size_t)l * NTYPE * NHEAD * 5120, KVb8, Qeb);
    agg_kernel<<<lng, 256, 0, stream>>>(off, csr_src, csr_et, Qeb, KVb8,
        mu + (size_t)l * NHEAD * ETYPE, aggb, N);

    gemm_mfma<0, 128><<<dim3(DMODEL / 128, gm), 256, 0, stream>>>(
        aggb, Wot + (size_t)l * 65536, bo + (size_t)l * DMODEL,
        fout, N, DMODEL, DMODEL);
    ln_kernel<<<lng, 256, 0, stream>>>(xbuf, fout,
        ln1g + (size_t)l * DMODEL, ln1b + (size_t)l * DMODEL, xbuf, xb, N);
    gemm_mfma<1, 128><<<dim3(4 * DMODEL / 128, gm), 256, 0, stream>>>(
        xb, w1t + (size_t)l * 262144, b1 + (size_t)l * 4 * DMODEL,
        h1b, N, DMODEL, 4 * DMODEL);
    gemm_mfma<0, 128><<<dim3(DMODEL / 128, gm), 256, 0, stream>>>(
        h1b, w2t + (size_t)l * 262144, b2 + (size_t)l * DMODEL,
        fout, N, 4 * DMODEL, DMODEL);
    ln_kernel<<<lng, 256, 0, stream>>>(xbuf, fout,
        ln2g + (size_t)l * DMODEL, ln2b + (size_t)l * DMODEL, xbuf, xb, N);
  }

  ln_kernel<<<lng, 256, 0, stream>>>(xbuf, nullptr, outg, outb, (float*)d_out, nullptr, N);
}